// Round 11
// baseline (205.509 us; speedup 1.0000x reference)
//
#include <hip/hip_runtime.h>
#include <hip/hip_bf16.h>

#define HEADS 8
#define HID 16
#define F1 128    // HEADS*HID
#define OUTD 64
#define XS_STRIDE 36   // padded LDS stride for 32-row tiles (36*4=144B, 16B-aligned)
#define BWL 7          // log2(bucket width)
#define BW 128         // dst-range per bucket
#define MAXBUK 512     // >= ceil(N/BW); N=50000 -> 391
#define CHUNK 4096     // edges per block in count/scatter (256 thr x 16)

typedef unsigned int uint;
typedef unsigned short ushort;

__device__ __forceinline__ ushort f2bf(float f) {
  __hip_bfloat16 b = __float2bfloat16(f);
  return *reinterpret_cast<ushort*>(&b);
}
__device__ __forceinline__ float bf2f_lo(uint w) {
  return __uint_as_float((w & 0xFFFFu) << 16);
}
__device__ __forceinline__ float bf2f_hi(uint w) {
  return __uint_as_float(w & 0xFFFF0000u);
}

// ---------------- CSR build (bucket radix, low write-amplification) ----------------
// pairs packed: src in bits [0,20), dst&(BW-1) in bits [20,27). Requires N < 2^20.

__global__ void k_z(int* __restrict__ a, int n) {
  int i = blockIdx.x * blockDim.x + threadIdx.x;
  if (i < n) a[i] = 0;
}

__global__ __launch_bounds__(256) void k_bukcount(const int* __restrict__ ei, int E, int N,
                                                  int* __restrict__ bukcnt) {
  __shared__ int hist[MAXBUK];
  int t = threadIdx.x;
  hist[t] = 0; hist[t + 256] = 0;
  __syncthreads();
  long long e0 = (long long)blockIdx.x * CHUNK;
  int ET = E + N;
#pragma unroll
  for (int i = 0; i < 16; ++i) {
    long long e = e0 + i * 256 + t;
    if (e < ET) {
      int d = e < E ? ei[E + e] : (int)(e - E);
      atomicAdd(&hist[d >> BWL], 1);
    }
  }
  __syncthreads();
  for (int b = t; b < MAXBUK; b += 256)
    if (hist[b]) atomicAdd(&bukcnt[b], hist[b]);
}

__global__ __launch_bounds__(512) void k_bukscan(const int* __restrict__ bukcnt,
                                                 int* __restrict__ bukbase,
                                                 int* __restrict__ bukcur,
                                                 int* __restrict__ off,
                                                 int NBUK, int N, int ET) {
  __shared__ int sm[512];
  int t = threadIdx.x;
  int v = t < NBUK ? bukcnt[t] : 0;
  sm[t] = v;
  __syncthreads();
  for (int o = 1; o < 512; o <<= 1) {
    int u = t >= o ? sm[t - o] : 0;
    __syncthreads();
    sm[t] += u;
    __syncthreads();
  }
  if (t < NBUK) {
    int base = sm[t] - v;   // exclusive
    bukbase[t] = base;
    bukcur[t] = base;
  }
  if (t == 0) { bukbase[NBUK] = ET; off[N] = ET; }
}

__global__ __launch_bounds__(256) void k_scatter(const int* __restrict__ ei, int E, int N,
                                                 int* __restrict__ bukcur,
                                                 int* __restrict__ pairs) {
  __shared__ int hist[MAXBUK];
  int t = threadIdx.x;
  hist[t] = 0; hist[t + 256] = 0;
  __syncthreads();
  long long e0 = (long long)blockIdx.x * CHUNK;
  int ET = E + N;
  int myP[16], myB[16];
#pragma unroll
  for (int i = 0; i < 16; ++i) {
    long long e = e0 + i * 256 + t;
    if (e < ET) {
      int s = e < E ? ei[e] : (int)(e - E);
      int d = e < E ? ei[E + e] : (int)(e - E);
      myP[i] = s | ((d & (BW - 1)) << 20);
      myB[i] = d >> BWL;
      atomicAdd(&hist[myB[i]], 1);
    } else {
      myB[i] = -1;
    }
  }
  __syncthreads();
  for (int b = t; b < MAXBUK; b += 256) {
    int c = hist[b];
    hist[b] = c ? atomicAdd(&bukcur[b], c) : 0;
  }
  __syncthreads();
#pragma unroll
  for (int i = 0; i < 16; ++i) {
    if (myB[i] >= 0) {
      int pos = atomicAdd(&hist[myB[i]], 1);
      pairs[pos] = myP[i];
    }
  }
}

__global__ __launch_bounds__(256) void k_csr(const int* __restrict__ pairs,
                                             const int* __restrict__ bukbase,
                                             int* __restrict__ off, int* __restrict__ csr,
                                             int N) {
  __shared__ int cnt[BW];
  __shared__ int cur[BW];
  int b = blockIdx.x, t = threadIdx.x;
  int beg = bukbase[b], end = bukbase[b + 1];
  if (t < BW) cnt[t] = 0;
  __syncthreads();
  for (int j = beg + t; j < end; j += 256)
    atomicAdd(&cnt[(pairs[j] >> 20) & (BW - 1)], 1);
  __syncthreads();
  int my = t < BW ? cnt[t] : 0;
  for (int o = 1; o < BW; o <<= 1) {
    int v = (t < BW && t >= o) ? cnt[t - o] : 0;
    __syncthreads();
    if (t < BW) cnt[t] += v;
    __syncthreads();
  }
  if (t < BW) {
    int start = beg + cnt[t] - my;   // exclusive within bucket
    cur[t] = start;
    int d0 = b * BW + t;
    if (d0 < N) off[d0] = start;
  }
  __syncthreads();
  for (int j = beg + t; j < end; j += 256) {
    int pr = pairs[j];
    int pos = atomicAdd(&cur[(pr >> 20) & (BW - 1)], 1);
    csr[pos] = pr & 0xFFFFF;
  }
}

// ---------------- layer 1 GEMM ----------------
// 32 rows x 128 cols per block; 256 threads; thread owns 4 rows x 4 cols.
// LDS 18.4KB -> 8 blocks/CU. h1 stored as two half-tables (heads 0-3 -> hA,
// heads 4-7 -> hB), 32 uints/row.
__global__ __launch_bounds__(256) void k_gemm1(
    const float* __restrict__ x, const float* __restrict__ W1,
    const float* __restrict__ as, const float* __restrict__ ad,
    uint* __restrict__ hA, uint* __restrict__ hB, float* __restrict__ a_src,
    float* __restrict__ a_dst, int N) {
  __shared__ float xs[F1 * XS_STRIDE];   // xs[k][row], 18.4 KB
  int tx = threadIdx.x;
  int cg = tx & 31;          // col group: cols 4cg..4cg+3
  int rg = tx >> 5;          // row group: rows 4rg..4rg+3 (rg in [0,8))
  int r0 = blockIdx.x * 32;

  {
    int row = tx & 31, kq0 = tx >> 5;   // kq0 in [0,8)
#pragma unroll
    for (int it = 0; it < 4; ++it) {
      int k4 = (it * 8 + kq0) * 4;
      float4 v = make_float4(0.f, 0.f, 0.f, 0.f);
      if (r0 + row < N) v = *reinterpret_cast<const float4*>(&x[(size_t)(r0 + row) * F1 + k4]);
      xs[(k4 + 0) * XS_STRIDE + row] = v.x;
      xs[(k4 + 1) * XS_STRIDE + row] = v.y;
      xs[(k4 + 2) * XS_STRIDE + row] = v.z;
      xs[(k4 + 3) * XS_STRIDE + row] = v.w;
    }
  }
  __syncthreads();

  float acc[4][4];
#pragma unroll
  for (int i = 0; i < 4; ++i)
#pragma unroll
    for (int j = 0; j < 4; ++j) acc[i][j] = 0.f;

#pragma unroll 4
  for (int k = 0; k < F1; ++k) {
    float4 w = *reinterpret_cast<const float4*>(&W1[k * F1 + 4 * cg]);
    float4 xa = *reinterpret_cast<const float4*>(&xs[k * XS_STRIDE + rg * 4]);
    const float xr[4] = {xa.x, xa.y, xa.z, xa.w};
#pragma unroll
    for (int i = 0; i < 4; ++i) {
      acc[i][0] = fmaf(xr[i], w.x, acc[i][0]);
      acc[i][1] = fmaf(xr[i], w.y, acc[i][1]);
      acc[i][2] = fmaf(xr[i], w.z, acc[i][2]);
      acc[i][3] = fmaf(xr[i], w.w, acc[i][3]);
    }
  }

  float4 as4 = *reinterpret_cast<const float4*>(&as[4 * cg]);
  float4 ad4 = *reinterpret_cast<const float4*>(&ad[4 * cg]);
  int h = cg >> 2;
  uint* hp = (cg < 16) ? hA : hB;
  int cgl = cg & 15;
#pragma unroll
  for (int i = 0; i < 4; ++i) {
    int row = r0 + rg * 4 + i;
    bool act = row < N;
    if (act) {
      uint2 pk;
      pk.x = (uint)f2bf(acc[i][0]) | ((uint)f2bf(acc[i][1]) << 16);
      pk.y = (uint)f2bf(acc[i][2]) | ((uint)f2bf(acc[i][3]) << 16);
      *reinterpret_cast<uint2*>(&hp[(size_t)row * 32 + 2 * cgl]) = pk;
    }
    float ps = acc[i][0] * as4.x + acc[i][1] * as4.y + acc[i][2] * as4.z + acc[i][3] * as4.w;
    float pd = acc[i][0] * ad4.x + acc[i][1] * ad4.y + acc[i][2] * ad4.z + acc[i][3] * ad4.w;
    ps += __shfl_xor(ps, 1); ps += __shfl_xor(ps, 2);
    pd += __shfl_xor(pd, 1); pd += __shfl_xor(pd, 2);
    if (act && (cg & 3) == 0) {
      a_src[row * HEADS + h] = ps;
      a_dst[row * HEADS + h] = pd;
    }
  }
}

// ---------------- layer 1 aggregate (channel-split half-table pass) ----------------
// 1 wave/dst; four 16-lane quarters process alternating edges; lane owns 4
// channels of the half-table via uint2 load (16x8B = 128B row); quarters
// combined with shfl_xor(16/32). hbase = 0 or 4 (head offset), obase = 0 or 64.
__global__ void k_agg1h(const int* __restrict__ off, const int* __restrict__ csr,
                        const uint2* __restrict__ htab, const float* __restrict__ a_src,
                        const float* __restrict__ a_dst, const float* __restrict__ b1,
                        float* __restrict__ out1, int N, int hbase, int obase) {
  int w = threadIdx.x >> 6, lane = threadIdx.x & 63;
  int q = lane >> 4, c2 = lane & 15;   // half-channels 4c2..4c2+3
  int h = hbase + (c2 >> 2);
  int d = blockIdx.x * 4 + w;
  if (d >= N) return;
  int beg = off[d], end = off[d + 1];
  float adl = a_dst[d * HEADS + h];
  float a0 = 0.f, a1 = 0.f, a2 = 0.f, a3 = 0.f, den = 0.f;
#pragma unroll 2
  for (int j = beg + q; j < end; j += 4) {
    int s = csr[j];
    float v = a_src[s * HEADS + h] + adl;
    v = v >= 0.f ? v : 0.2f * v;
    float p = __expf(v);
    uint2 wd = htab[(size_t)s * 16 + c2];
    a0 = fmaf(p, bf2f_lo(wd.x), a0);
    a1 = fmaf(p, bf2f_hi(wd.x), a1);
    a2 = fmaf(p, bf2f_lo(wd.y), a2);
    a3 = fmaf(p, bf2f_hi(wd.y), a3);
    den += p;
  }
  a0 += __shfl_xor(a0, 16); a0 += __shfl_xor(a0, 32);
  a1 += __shfl_xor(a1, 16); a1 += __shfl_xor(a1, 32);
  a2 += __shfl_xor(a2, 16); a2 += __shfl_xor(a2, 32);
  a3 += __shfl_xor(a3, 16); a3 += __shfl_xor(a3, 32);
  den += __shfl_xor(den, 16); den += __shfl_xor(den, 32);
  if (q == 0) {
    float inv = 1.f / den;   // self-loop guarantees den > 0
    float4 bb = *reinterpret_cast<const float4*>(&b1[obase + 4 * c2]);
    float4 o;
    o.x = a0 * inv + bb.x;
    o.y = a1 * inv + bb.y;
    o.z = a2 * inv + bb.z;
    o.w = a3 * inv + bb.w;
    *reinterpret_cast<float4*>(&out1[(size_t)d * F1 + obase + 4 * c2]) = o;
  }
}

// ---------------- layer 2 GEMM ----------------
// 32 rows x 64 cols per block; 256 threads; thread owns 2 rows x 4 cols.
__global__ __launch_bounds__(256) void k_gemm2(
    const float* __restrict__ out1, const float* __restrict__ W2,
    const float* __restrict__ as2, const float* __restrict__ ad2,
    uint* __restrict__ h2b, float* __restrict__ a_src2,
    float* __restrict__ a_dst2, int N) {
  __shared__ float xs[F1 * XS_STRIDE];   // xs[k][row]
  int tx = threadIdx.x;
  int cg = tx & 15;          // cols 4cg..4cg+3
  int rg = tx >> 4;          // rows 2rg..2rg+1 (rg in [0,16))
  int r0 = blockIdx.x * 32;

  {
    int row = tx & 31, kq0 = tx >> 5;
#pragma unroll
    for (int it = 0; it < 4; ++it) {
      int k4 = (it * 8 + kq0) * 4;
      float4 v = make_float4(0.f, 0.f, 0.f, 0.f);
      if (r0 + row < N) v = *reinterpret_cast<const float4*>(&out1[(size_t)(r0 + row) * F1 + k4]);
      v.x = v.x > 0.f ? v.x : __expf(v.x) - 1.f;
      v.y = v.y > 0.f ? v.y : __expf(v.y) - 1.f;
      v.z = v.z > 0.f ? v.z : __expf(v.z) - 1.f;
      v.w = v.w > 0.f ? v.w : __expf(v.w) - 1.f;
      xs[(k4 + 0) * XS_STRIDE + row] = v.x;
      xs[(k4 + 1) * XS_STRIDE + row] = v.y;
      xs[(k4 + 2) * XS_STRIDE + row] = v.z;
      xs[(k4 + 3) * XS_STRIDE + row] = v.w;
    }
  }
  __syncthreads();

  float acc[2][4];
#pragma unroll
  for (int i = 0; i < 2; ++i)
#pragma unroll
    for (int j = 0; j < 4; ++j) acc[i][j] = 0.f;

#pragma unroll 4
  for (int k = 0; k < F1; ++k) {
    float4 w = *reinterpret_cast<const float4*>(&W2[k * OUTD + 4 * cg]);
    float2 xv = *reinterpret_cast<const float2*>(&xs[k * XS_STRIDE + rg * 2]);
    acc[0][0] = fmaf(xv.x, w.x, acc[0][0]);
    acc[0][1] = fmaf(xv.x, w.y, acc[0][1]);
    acc[0][2] = fmaf(xv.x, w.z, acc[0][2]);
    acc[0][3] = fmaf(xv.x, w.w, acc[0][3]);
    acc[1][0] = fmaf(xv.y, w.x, acc[1][0]);
    acc[1][1] = fmaf(xv.y, w.y, acc[1][1]);
    acc[1][2] = fmaf(xv.y, w.z, acc[1][2]);
    acc[1][3] = fmaf(xv.y, w.w, acc[1][3]);
  }

  float4 as4 = *reinterpret_cast<const float4*>(&as2[4 * cg]);
  float4 ad4 = *reinterpret_cast<const float4*>(&ad2[4 * cg]);
#pragma unroll
  for (int i = 0; i < 2; ++i) {
    int row = r0 + rg * 2 + i;
    bool act = row < N;
    if (act) {
      uint2 pk;
      pk.x = (uint)f2bf(acc[i][0]) | ((uint)f2bf(acc[i][1]) << 16);
      pk.y = (uint)f2bf(acc[i][2]) | ((uint)f2bf(acc[i][3]) << 16);
      *reinterpret_cast<uint2*>(&h2b[(size_t)row * 32 + 2 * cg]) = pk;
    }
    float ps = acc[i][0] * as4.x + acc[i][1] * as4.y + acc[i][2] * as4.z + acc[i][3] * as4.w;
    float pd = acc[i][0] * ad4.x + acc[i][1] * ad4.y + acc[i][2] * ad4.z + acc[i][3] * ad4.w;
    ps += __shfl_xor(ps, 1); ps += __shfl_xor(ps, 2);
    ps += __shfl_xor(ps, 4); ps += __shfl_xor(ps, 8);
    pd += __shfl_xor(pd, 1); pd += __shfl_xor(pd, 2);
    pd += __shfl_xor(pd, 4); pd += __shfl_xor(pd, 8);
    if (act && cg == 0) {
      a_src2[row] = ps;
      a_dst2[row] = pd;
    }
  }
}

// ---------------- layer 2 aggregate ----------------
// 1 wave/dst; four 16-lane quarters process alternating edges; lane owns 4
// channels via uint2 loads; quarters combined with shfl_xor(16/32).
__global__ void k_agg2(const int* __restrict__ off, const int* __restrict__ csr,
                       const uint2* __restrict__ h2b2, const float* __restrict__ a_src2,
                       const float* __restrict__ a_dst2, const float* __restrict__ b2,
                       float* __restrict__ out, int N) {
  int w = threadIdx.x >> 6, lane = threadIdx.x & 63;
  int q = lane >> 4, c2 = lane & 15;   // channels 4c2..4c2+3
  int d = blockIdx.x * 4 + w;
  if (d >= N) return;
  int beg = off[d], end = off[d + 1];
  float adl = a_dst2[d];
  float a0 = 0.f, a1 = 0.f, a2 = 0.f, a3 = 0.f, den = 0.f;
#pragma unroll 2
  for (int j = beg + q; j < end; j += 4) {
    int s = csr[j];
    float v = a_src2[s] + adl;
    v = v >= 0.f ? v : 0.2f * v;
    float p = __expf(v);
    uint2 wd = h2b2[(size_t)s * 16 + c2];
    a0 = fmaf(p, bf2f_lo(wd.x), a0);
    a1 = fmaf(p, bf2f_hi(wd.x), a1);
    a2 = fmaf(p, bf2f_lo(wd.y), a2);
    a3 = fmaf(p, bf2f_hi(wd.y), a3);
    den += p;
  }
  a0 += __shfl_xor(a0, 16); a0 += __shfl_xor(a0, 32);
  a1 += __shfl_xor(a1, 16); a1 += __shfl_xor(a1, 32);
  a2 += __shfl_xor(a2, 16); a2 += __shfl_xor(a2, 32);
  a3 += __shfl_xor(a3, 16); a3 += __shfl_xor(a3, 32);
  den += __shfl_xor(den, 16); den += __shfl_xor(den, 32);
  if (q == 0) {
    float inv = 1.f / den;
    float4 bb = *reinterpret_cast<const float4*>(&b2[4 * c2]);
    float4 o;
    o.x = a0 * inv + bb.x;
    o.y = a1 * inv + bb.y;
    o.z = a2 * inv + bb.z;
    o.w = a3 * inv + bb.w;
    *reinterpret_cast<float4*>(&out[(size_t)d * OUTD + 4 * c2]) = o;
  }
}

extern "C" void kernel_launch(void* const* d_in, const int* in_sizes, int n_in,
                              void* d_out, int out_size, void* d_ws, size_t ws_size,
                              hipStream_t stream) {
  const float* x   = (const float*)d_in[0];
  const int*   ei  = (const int*)d_in[1];
  const float* W1  = (const float*)d_in[2];
  const float* as1 = (const float*)d_in[3];
  const float* ad1 = (const float*)d_in[4];
  const float* b1  = (const float*)d_in[5];
  const float* W2  = (const float*)d_in[6];
  const float* as2 = (const float*)d_in[7];
  const float* ad2 = (const float*)d_in[8];
  const float* b2  = (const float*)d_in[9];
  float* out = (float*)d_out;

  int N = in_sizes[0] / F1;
  int E = in_sizes[1] / 2;
  int ET = E + N;
  int NBUK = (N + BW - 1) / BW;       // 391 for N=50000 (<= MAXBUK)
  int NCH = (ET + CHUNK - 1) / CHUNK; // count/scatter blocks
  int NT = (N + 31) / 32;             // GEMM tiles (32 rows)

  // workspace layout (16B-aligned chunks)
  char* p = (char*)d_ws;
  auto alloc = [&](size_t bytes) {
    char* q = p;
    p += (bytes + 15) & ~(size_t)15;
    return q;
  };
  int* bukcnt  = (int*)alloc((size_t)NBUK * 4);
  int* bukbase = (int*)alloc((size_t)(NBUK + 1) * 4);
  int* bukcur  = (int*)alloc((size_t)NBUK * 4);
  int* off     = (int*)alloc((size_t)(N + 1) * 4);
  int* pairs   = (int*)alloc((size_t)ET * 4);
  int* csr     = (int*)alloc((size_t)ET * 4);
  uint* hA     = (uint*)alloc((size_t)N * 32 * 4);   // heads 0-3
  uint* hB     = (uint*)alloc((size_t)N * 32 * 4);   // heads 4-7
  uint* h2b    = (uint*)alloc((size_t)N * 32 * 4);
  float* out1  = (float*)alloc((size_t)N * F1 * 4);
  float* a_src1 = (float*)alloc((size_t)N * HEADS * 4);
  float* a_dst1 = (float*)alloc((size_t)N * HEADS * 4);
  float* a_src2 = (float*)alloc((size_t)N * 4);
  float* a_dst2 = (float*)alloc((size_t)N * 4);

  // CSR build (shared by both layers)
  hipLaunchKernelGGL(k_z, dim3((NBUK + 255) / 256), dim3(256), 0, stream, bukcnt, NBUK);
  hipLaunchKernelGGL(k_bukcount, dim3(NCH), dim3(256), 0, stream, ei, E, N, bukcnt);
  hipLaunchKernelGGL(k_bukscan, dim3(1), dim3(512), 0, stream,
                     bukcnt, bukbase, bukcur, off, NBUK, N, ET);
  hipLaunchKernelGGL(k_scatter, dim3(NCH), dim3(256), 0, stream, ei, E, N, bukcur, pairs);
  hipLaunchKernelGGL(k_csr, dim3(NBUK), dim3(256), 0, stream, pairs, bukbase, off, csr, N);

  // layer 1
  hipLaunchKernelGGL(k_gemm1, dim3(NT), dim3(256), 0, stream,
                     x, W1, as1, ad1, hA, hB, a_src1, a_dst1, N);
  hipLaunchKernelGGL(k_agg1h, dim3((N + 3) / 4), dim3(256), 0, stream,
                     off, csr, (const uint2*)hA, a_src1, a_dst1, b1, out1, N, 0, 0);
  hipLaunchKernelGGL(k_agg1h, dim3((N + 3) / 4), dim3(256), 0, stream,
                     off, csr, (const uint2*)hB, a_src1, a_dst1, b1, out1, N, 4, 64);

  // layer 2
  hipLaunchKernelGGL(k_gemm2, dim3(NT), dim3(256), 0, stream,
                     out1, W2, as2, ad2, h2b, a_src2, a_dst2, N);
  hipLaunchKernelGGL(k_agg2, dim3((N + 3) / 4), dim3(256), 0, stream,
                     off, csr, (const uint2*)h2b, a_src2, a_dst2, b2, out, N);
}

// Round 12
// 197.026 us; speedup vs baseline: 1.0431x; 1.0431x over previous
//
#include <hip/hip_runtime.h>
#include <hip/hip_bf16.h>

#define HEADS 8
#define HID 16
#define F1 128    // HEADS*HID
#define OUTD 64
#define GP 16          // GEMM k-panel size
#define BWL 7          // log2(bucket width)
#define BW 128         // dst-range per bucket
#define MAXBUK 512     // >= ceil(N/BW); N=50000 -> 391
#define CHUNK 4096     // edges per block in count/scatter (256 thr x 16)

typedef unsigned int uint;
typedef unsigned short ushort;

__device__ __forceinline__ ushort f2bf(float f) {
  __hip_bfloat16 b = __float2bfloat16(f);
  return *reinterpret_cast<ushort*>(&b);
}
__device__ __forceinline__ float bf2f_lo(uint w) {
  return __uint_as_float((w & 0xFFFFu) << 16);
}
__device__ __forceinline__ float bf2f_hi(uint w) {
  return __uint_as_float(w & 0xFFFF0000u);
}

// ---------------- CSR build (bucket radix, low write-amplification) ----------------
// pairs packed: src in bits [0,20), dst&(BW-1) in bits [20,27). Requires N < 2^20.

__global__ void k_z(int* __restrict__ a, int n) {
  int i = blockIdx.x * blockDim.x + threadIdx.x;
  if (i < n) a[i] = 0;
}

__global__ __launch_bounds__(256) void k_bukcount(const int* __restrict__ ei, int E, int N,
                                                  int* __restrict__ bukcnt) {
  __shared__ int hist[MAXBUK];
  int t = threadIdx.x;
  hist[t] = 0; hist[t + 256] = 0;
  __syncthreads();
  long long e0 = (long long)blockIdx.x * CHUNK;
  int ET = E + N;
#pragma unroll
  for (int i = 0; i < 16; ++i) {
    long long e = e0 + i * 256 + t;
    if (e < ET) {
      int d = e < E ? ei[E + e] : (int)(e - E);
      atomicAdd(&hist[d >> BWL], 1);
    }
  }
  __syncthreads();
  for (int b = t; b < MAXBUK; b += 256)
    if (hist[b]) atomicAdd(&bukcnt[b], hist[b]);
}

__global__ __launch_bounds__(512) void k_bukscan(const int* __restrict__ bukcnt,
                                                 int* __restrict__ bukbase,
                                                 int* __restrict__ bukcur,
                                                 int* __restrict__ off,
                                                 int NBUK, int N, int ET) {
  __shared__ int sm[512];
  int t = threadIdx.x;
  int v = t < NBUK ? bukcnt[t] : 0;
  sm[t] = v;
  __syncthreads();
  for (int o = 1; o < 512; o <<= 1) {
    int u = t >= o ? sm[t - o] : 0;
    __syncthreads();
    sm[t] += u;
    __syncthreads();
  }
  if (t < NBUK) {
    int base = sm[t] - v;   // exclusive
    bukbase[t] = base;
    bukcur[t] = base;
  }
  if (t == 0) { bukbase[NBUK] = ET; off[N] = ET; }
}

__global__ __launch_bounds__(256) void k_scatter(const int* __restrict__ ei, int E, int N,
                                                 int* __restrict__ bukcur,
                                                 int* __restrict__ pairs) {
  __shared__ int hist[MAXBUK];
  int t = threadIdx.x;
  hist[t] = 0; hist[t + 256] = 0;
  __syncthreads();
  long long e0 = (long long)blockIdx.x * CHUNK;
  int ET = E + N;
  int myP[16], myB[16];
#pragma unroll
  for (int i = 0; i < 16; ++i) {
    long long e = e0 + i * 256 + t;
    if (e < ET) {
      int s = e < E ? ei[e] : (int)(e - E);
      int d = e < E ? ei[E + e] : (int)(e - E);
      myP[i] = s | ((d & (BW - 1)) << 20);
      myB[i] = d >> BWL;
      atomicAdd(&hist[myB[i]], 1);
    } else {
      myB[i] = -1;
    }
  }
  __syncthreads();
  for (int b = t; b < MAXBUK; b += 256) {
    int c = hist[b];
    hist[b] = c ? atomicAdd(&bukcur[b], c) : 0;
  }
  __syncthreads();
#pragma unroll
  for (int i = 0; i < 16; ++i) {
    if (myB[i] >= 0) {
      int pos = atomicAdd(&hist[myB[i]], 1);
      pairs[pos] = myP[i];
    }
  }
}

__global__ __launch_bounds__(256) void k_csr(const int* __restrict__ pairs,
                                             const int* __restrict__ bukbase,
                                             int* __restrict__ off, int* __restrict__ csr,
                                             int N) {
  __shared__ int cnt[BW];
  __shared__ int cur[BW];
  int b = blockIdx.x, t = threadIdx.x;
  int beg = bukbase[b], end = bukbase[b + 1];
  if (t < BW) cnt[t] = 0;
  __syncthreads();
  for (int j = beg + t; j < end; j += 256)
    atomicAdd(&cnt[(pairs[j] >> 20) & (BW - 1)], 1);
  __syncthreads();
  int my = t < BW ? cnt[t] : 0;
  for (int o = 1; o < BW; o <<= 1) {
    int v = (t < BW && t >= o) ? cnt[t - o] : 0;
    __syncthreads();
    if (t < BW) cnt[t] += v;
    __syncthreads();
  }
  if (t < BW) {
    int start = beg + cnt[t] - my;   // exclusive within bucket
    cur[t] = start;
    int d0 = b * BW + t;
    if (d0 < N) off[d0] = start;
  }
  __syncthreads();
  for (int j = beg + t; j < end; j += 256) {
    int pr = pairs[j];
    int pos = atomicAdd(&cur[(pr >> 20) & (BW - 1)], 1);
    csr[pos] = pr & 0xFFFFF;
  }
}

// ---------------- layer 1 GEMM (k-panel, W in LDS) ----------------
// 64 rows x 128 cols per block; 256 threads; thread owns 8 rows x 4 cols.
// Per 16-k panel: xs[16][64] (4KB) + ws[16][128] (8KB) staged in LDS.
__global__ __launch_bounds__(256) void k_gemm1(
    const float* __restrict__ x, const float* __restrict__ W1,
    const float* __restrict__ as, const float* __restrict__ ad,
    uint* __restrict__ hA, uint* __restrict__ hB, float* __restrict__ a_src,
    float* __restrict__ a_dst, int N) {
  __shared__ float xs[GP][64];
  __shared__ float ws[GP][F1];
  int tx = threadIdx.x;
  int cg = tx & 31;          // col group: cols 4cg..4cg+3
  int rg = tx >> 5;          // row group: rows 8rg..8rg+7
  int r0 = blockIdx.x * 64;
  int rowL = tx & 63, kq = tx >> 6;   // x staging: kq in [0,4)
  int wc4 = tx & 31, wk = tx >> 5;    // W staging: wk in [0,8)
  bool xact = (r0 + rowL) < N;

  float acc[8][4];
#pragma unroll
  for (int i = 0; i < 8; ++i)
#pragma unroll
    for (int j = 0; j < 4; ++j) acc[i][j] = 0.f;

#pragma unroll
  for (int p = 0; p < F1 / GP; ++p) {
    int k0 = p * GP;
    // stage x panel
    float4 v = make_float4(0.f, 0.f, 0.f, 0.f);
    if (xact) v = *reinterpret_cast<const float4*>(&x[(size_t)(r0 + rowL) * F1 + k0 + kq * 4]);
    xs[kq * 4 + 0][rowL] = v.x;
    xs[kq * 4 + 1][rowL] = v.y;
    xs[kq * 4 + 2][rowL] = v.z;
    xs[kq * 4 + 3][rowL] = v.w;
    // stage W panel (rows wk and wk+8)
    *reinterpret_cast<float4*>(&ws[wk][wc4 * 4]) =
        *reinterpret_cast<const float4*>(&W1[(k0 + wk) * F1 + wc4 * 4]);
    *reinterpret_cast<float4*>(&ws[wk + 8][wc4 * 4]) =
        *reinterpret_cast<const float4*>(&W1[(k0 + wk + 8) * F1 + wc4 * 4]);
    __syncthreads();
#pragma unroll
    for (int k = 0; k < GP; ++k) {
      float4 w = *reinterpret_cast<const float4*>(&ws[k][cg * 4]);
      float4 xa = *reinterpret_cast<const float4*>(&xs[k][rg * 8]);
      float4 xb = *reinterpret_cast<const float4*>(&xs[k][rg * 8 + 4]);
      const float xr[8] = {xa.x, xa.y, xa.z, xa.w, xb.x, xb.y, xb.z, xb.w};
#pragma unroll
      for (int i = 0; i < 8; ++i) {
        acc[i][0] = fmaf(xr[i], w.x, acc[i][0]);
        acc[i][1] = fmaf(xr[i], w.y, acc[i][1]);
        acc[i][2] = fmaf(xr[i], w.z, acc[i][2]);
        acc[i][3] = fmaf(xr[i], w.w, acc[i][3]);
      }
    }
    __syncthreads();
  }

  float4 as4 = *reinterpret_cast<const float4*>(&as[4 * cg]);
  float4 ad4 = *reinterpret_cast<const float4*>(&ad[4 * cg]);
  int h = cg >> 2;
  uint* hp = (cg < 16) ? hA : hB;
  int cgl = cg & 15;
#pragma unroll
  for (int i = 0; i < 8; ++i) {
    int row = r0 + rg * 8 + i;
    bool act = row < N;
    if (act) {
      uint2 pk;
      pk.x = (uint)f2bf(acc[i][0]) | ((uint)f2bf(acc[i][1]) << 16);
      pk.y = (uint)f2bf(acc[i][2]) | ((uint)f2bf(acc[i][3]) << 16);
      *reinterpret_cast<uint2*>(&hp[(size_t)row * 32 + 2 * cgl]) = pk;
    }
    float ps = acc[i][0] * as4.x + acc[i][1] * as4.y + acc[i][2] * as4.z + acc[i][3] * as4.w;
    float pd = acc[i][0] * ad4.x + acc[i][1] * ad4.y + acc[i][2] * ad4.z + acc[i][3] * ad4.w;
    ps += __shfl_xor(ps, 1); ps += __shfl_xor(ps, 2);
    pd += __shfl_xor(pd, 1); pd += __shfl_xor(pd, 2);
    if (act && (cg & 3) == 0) {
      a_src[row * HEADS + h] = ps;
      a_dst[row * HEADS + h] = pd;
    }
  }
}

// ---------------- layer 1 aggregate (channel-split half-table pass) ----------------
// 1 wave/dst; four 16-lane quarters process alternating edges; lane owns 4
// channels of the half-table via uint2 load (16x8B = 128B row); quarters
// combined with shfl_xor(16/32). hbase = 0 or 4 (head offset), obase = 0 or 64.
__global__ void k_agg1h(const int* __restrict__ off, const int* __restrict__ csr,
                        const uint2* __restrict__ htab, const float* __restrict__ a_src,
                        const float* __restrict__ a_dst, const float* __restrict__ b1,
                        float* __restrict__ out1, int N, int hbase, int obase) {
  int w = threadIdx.x >> 6, lane = threadIdx.x & 63;
  int q = lane >> 4, c2 = lane & 15;   // half-channels 4c2..4c2+3
  int h = hbase + (c2 >> 2);
  int d = blockIdx.x * 4 + w;
  if (d >= N) return;
  int beg = off[d], end = off[d + 1];
  float adl = a_dst[d * HEADS + h];
  float a0 = 0.f, a1 = 0.f, a2 = 0.f, a3 = 0.f, den = 0.f;
#pragma unroll 2
  for (int j = beg + q; j < end; j += 4) {
    int s = csr[j];
    float v = a_src[s * HEADS + h] + adl;
    v = v >= 0.f ? v : 0.2f * v;
    float p = __expf(v);
    uint2 wd = htab[(size_t)s * 16 + c2];
    a0 = fmaf(p, bf2f_lo(wd.x), a0);
    a1 = fmaf(p, bf2f_hi(wd.x), a1);
    a2 = fmaf(p, bf2f_lo(wd.y), a2);
    a3 = fmaf(p, bf2f_hi(wd.y), a3);
    den += p;
  }
  a0 += __shfl_xor(a0, 16); a0 += __shfl_xor(a0, 32);
  a1 += __shfl_xor(a1, 16); a1 += __shfl_xor(a1, 32);
  a2 += __shfl_xor(a2, 16); a2 += __shfl_xor(a2, 32);
  a3 += __shfl_xor(a3, 16); a3 += __shfl_xor(a3, 32);
  den += __shfl_xor(den, 16); den += __shfl_xor(den, 32);
  if (q == 0) {
    float inv = 1.f / den;   // self-loop guarantees den > 0
    float4 bb = *reinterpret_cast<const float4*>(&b1[obase + 4 * c2]);
    float4 o;
    o.x = a0 * inv + bb.x;
    o.y = a1 * inv + bb.y;
    o.z = a2 * inv + bb.z;
    o.w = a3 * inv + bb.w;
    *reinterpret_cast<float4*>(&out1[(size_t)d * F1 + obase + 4 * c2]) = o;
  }
}

// ---------------- layer 2 GEMM (k-panel, W in LDS) ----------------
// 64 rows x 64 cols per block; 256 threads; thread owns 4 rows x 4 cols.
// Per 16-k panel: xs2[16][64] (ELU-fused) + ws2[16][64] staged in LDS (8KB).
__global__ __launch_bounds__(256) void k_gemm2(
    const float* __restrict__ out1, const float* __restrict__ W2,
    const float* __restrict__ as2, const float* __restrict__ ad2,
    uint* __restrict__ h2b, float* __restrict__ a_src2,
    float* __restrict__ a_dst2, int N) {
  __shared__ float xs2[GP][64];
  __shared__ float ws2[GP][OUTD];
  int tx = threadIdx.x;
  int cg = tx & 15;          // cols 4cg..4cg+3
  int rg = tx >> 4;          // rows 4rg..4rg+3 (rg in [0,16))
  int r0 = blockIdx.x * 64;
  int rowL = tx & 63, kq = tx >> 6;   // x staging
  int wc4 = tx & 15, wk = tx >> 4;    // W staging: wk in [0,16)
  bool xact = (r0 + rowL) < N;

  float acc[4][4];
#pragma unroll
  for (int i = 0; i < 4; ++i)
#pragma unroll
    for (int j = 0; j < 4; ++j) acc[i][j] = 0.f;

#pragma unroll
  for (int p = 0; p < F1 / GP; ++p) {
    int k0 = p * GP;
    float4 v = make_float4(0.f, 0.f, 0.f, 0.f);
    if (xact) v = *reinterpret_cast<const float4*>(&out1[(size_t)(r0 + rowL) * F1 + k0 + kq * 4]);
    v.x = v.x > 0.f ? v.x : __expf(v.x) - 1.f;
    v.y = v.y > 0.f ? v.y : __expf(v.y) - 1.f;
    v.z = v.z > 0.f ? v.z : __expf(v.z) - 1.f;
    v.w = v.w > 0.f ? v.w : __expf(v.w) - 1.f;
    xs2[kq * 4 + 0][rowL] = v.x;
    xs2[kq * 4 + 1][rowL] = v.y;
    xs2[kq * 4 + 2][rowL] = v.z;
    xs2[kq * 4 + 3][rowL] = v.w;
    *reinterpret_cast<float4*>(&ws2[wk][wc4 * 4]) =
        *reinterpret_cast<const float4*>(&W2[(k0 + wk) * OUTD + wc4 * 4]);
    __syncthreads();
#pragma unroll
    for (int k = 0; k < GP; ++k) {
      float4 w = *reinterpret_cast<const float4*>(&ws2[k][cg * 4]);
      float4 xv = *reinterpret_cast<const float4*>(&xs2[k][rg * 4]);
      const float xr[4] = {xv.x, xv.y, xv.z, xv.w};
#pragma unroll
      for (int i = 0; i < 4; ++i) {
        acc[i][0] = fmaf(xr[i], w.x, acc[i][0]);
        acc[i][1] = fmaf(xr[i], w.y, acc[i][1]);
        acc[i][2] = fmaf(xr[i], w.z, acc[i][2]);
        acc[i][3] = fmaf(xr[i], w.w, acc[i][3]);
      }
    }
    __syncthreads();
  }

  float4 as4 = *reinterpret_cast<const float4*>(&as2[4 * cg]);
  float4 ad4 = *reinterpret_cast<const float4*>(&ad2[4 * cg]);
#pragma unroll
  for (int i = 0; i < 4; ++i) {
    int row = r0 + rg * 4 + i;
    bool act = row < N;
    if (act) {
      uint2 pk;
      pk.x = (uint)f2bf(acc[i][0]) | ((uint)f2bf(acc[i][1]) << 16);
      pk.y = (uint)f2bf(acc[i][2]) | ((uint)f2bf(acc[i][3]) << 16);
      *reinterpret_cast<uint2*>(&h2b[(size_t)row * 32 + 2 * cg]) = pk;
    }
    float ps = acc[i][0] * as4.x + acc[i][1] * as4.y + acc[i][2] * as4.z + acc[i][3] * as4.w;
    float pd = acc[i][0] * ad4.x + acc[i][1] * ad4.y + acc[i][2] * ad4.z + acc[i][3] * ad4.w;
    ps += __shfl_xor(ps, 1); ps += __shfl_xor(ps, 2);
    ps += __shfl_xor(ps, 4); ps += __shfl_xor(ps, 8);
    pd += __shfl_xor(pd, 1); pd += __shfl_xor(pd, 2);
    pd += __shfl_xor(pd, 4); pd += __shfl_xor(pd, 8);
    if (act && cg == 0) {
      a_src2[row] = ps;
      a_dst2[row] = pd;
    }
  }
}

// ---------------- layer 2 aggregate ----------------
// 1 wave/dst; four 16-lane quarters process alternating edges; lane owns 4
// channels via uint2 loads; quarters combined with shfl_xor(16/32).
__global__ void k_agg2(const int* __restrict__ off, const int* __restrict__ csr,
                       const uint2* __restrict__ h2b2, const float* __restrict__ a_src2,
                       const float* __restrict__ a_dst2, const float* __restrict__ b2,
                       float* __restrict__ out, int N) {
  int w = threadIdx.x >> 6, lane = threadIdx.x & 63;
  int q = lane >> 4, c2 = lane & 15;   // channels 4c2..4c2+3
  int d = blockIdx.x * 4 + w;
  if (d >= N) return;
  int beg = off[d], end = off[d + 1];
  float adl = a_dst2[d];
  float a0 = 0.f, a1 = 0.f, a2 = 0.f, a3 = 0.f, den = 0.f;
#pragma unroll 2
  for (int j = beg + q; j < end; j += 4) {
    int s = csr[j];
    float v = a_src2[s] + adl;
    v = v >= 0.f ? v : 0.2f * v;
    float p = __expf(v);
    uint2 wd = h2b2[(size_t)s * 16 + c2];
    a0 = fmaf(p, bf2f_lo(wd.x), a0);
    a1 = fmaf(p, bf2f_hi(wd.x), a1);
    a2 = fmaf(p, bf2f_lo(wd.y), a2);
    a3 = fmaf(p, bf2f_hi(wd.y), a3);
    den += p;
  }
  a0 += __shfl_xor(a0, 16); a0 += __shfl_xor(a0, 32);
  a1 += __shfl_xor(a1, 16); a1 += __shfl_xor(a1, 32);
  a2 += __shfl_xor(a2, 16); a2 += __shfl_xor(a2, 32);
  a3 += __shfl_xor(a3, 16); a3 += __shfl_xor(a3, 32);
  den += __shfl_xor(den, 16); den += __shfl_xor(den, 32);
  if (q == 0) {
    float inv = 1.f / den;
    float4 bb = *reinterpret_cast<const float4*>(&b2[4 * c2]);
    float4 o;
    o.x = a0 * inv + bb.x;
    o.y = a1 * inv + bb.y;
    o.z = a2 * inv + bb.z;
    o.w = a3 * inv + bb.w;
    *reinterpret_cast<float4*>(&out[(size_t)d * OUTD + 4 * c2]) = o;
  }
}

extern "C" void kernel_launch(void* const* d_in, const int* in_sizes, int n_in,
                              void* d_out, int out_size, void* d_ws, size_t ws_size,
                              hipStream_t stream) {
  const float* x   = (const float*)d_in[0];
  const int*   ei  = (const int*)d_in[1];
  const float* W1  = (const float*)d_in[2];
  const float* as1 = (const float*)d_in[3];
  const float* ad1 = (const float*)d_in[4];
  const float* b1  = (const float*)d_in[5];
  const float* W2  = (const float*)d_in[6];
  const float* as2 = (const float*)d_in[7];
  const float* ad2 = (const float*)d_in[8];
  const float* b2  = (const float*)d_in[9];
  float* out = (float*)d_out;

  int N = in_sizes[0] / F1;
  int E = in_sizes[1] / 2;
  int ET = E + N;
  int NBUK = (N + BW - 1) / BW;       // 391 for N=50000 (<= MAXBUK)
  int NCH = (ET + CHUNK - 1) / CHUNK; // count/scatter blocks
  int NT = (N + 63) / 64;             // GEMM tiles (64 rows)

  // workspace layout (16B-aligned chunks)
  char* p = (char*)d_ws;
  auto alloc = [&](size_t bytes) {
    char* q = p;
    p += (bytes + 15) & ~(size_t)15;
    return q;
  };
  int* bukcnt  = (int*)alloc((size_t)NBUK * 4);
  int* bukbase = (int*)alloc((size_t)(NBUK + 1) * 4);
  int* bukcur  = (int*)alloc((size_t)NBUK * 4);
  int* off     = (int*)alloc((size_t)(N + 1) * 4);
  int* pairs   = (int*)alloc((size_t)ET * 4);
  int* csr     = (int*)alloc((size_t)ET * 4);
  uint* hA     = (uint*)alloc((size_t)N * 32 * 4);   // heads 0-3
  uint* hB     = (uint*)alloc((size_t)N * 32 * 4);   // heads 4-7
  uint* h2b    = (uint*)alloc((size_t)N * 32 * 4);
  float* out1  = (float*)alloc((size_t)N * F1 * 4);
  float* a_src1 = (float*)alloc((size_t)N * HEADS * 4);
  float* a_dst1 = (float*)alloc((size_t)N * HEADS * 4);
  float* a_src2 = (float*)alloc((size_t)N * 4);
  float* a_dst2 = (float*)alloc((size_t)N * 4);

  // CSR build (shared by both layers)
  hipLaunchKernelGGL(k_z, dim3((NBUK + 255) / 256), dim3(256), 0, stream, bukcnt, NBUK);
  hipLaunchKernelGGL(k_bukcount, dim3(NCH), dim3(256), 0, stream, ei, E, N, bukcnt);
  hipLaunchKernelGGL(k_bukscan, dim3(1), dim3(512), 0, stream,
                     bukcnt, bukbase, bukcur, off, NBUK, N, ET);
  hipLaunchKernelGGL(k_scatter, dim3(NCH), dim3(256), 0, stream, ei, E, N, bukcur, pairs);
  hipLaunchKernelGGL(k_csr, dim3(NBUK), dim3(256), 0, stream, pairs, bukbase, off, csr, N);

  // layer 1
  hipLaunchKernelGGL(k_gemm1, dim3(NT), dim3(256), 0, stream,
                     x, W1, as1, ad1, hA, hB, a_src1, a_dst1, N);
  hipLaunchKernelGGL(k_agg1h, dim3((N + 3) / 4), dim3(256), 0, stream,
                     off, csr, (const uint2*)hA, a_src1, a_dst1, b1, out1, N, 0, 0);
  hipLaunchKernelGGL(k_agg1h, dim3((N + 3) / 4), dim3(256), 0, stream,
                     off, csr, (const uint2*)hB, a_src1, a_dst1, b1, out1, N, 4, 64);

  // layer 2
  hipLaunchKernelGGL(k_gemm2, dim3(NT), dim3(256), 0, stream,
                     out1, W2, as2, ad2, h2b, a_src2, a_dst2, N);
  hipLaunchKernelGGL(k_agg2, dim3((N + 3) / 4), dim3(256), 0, stream,
                     off, csr, (const uint2*)h2b, a_src2, a_dst2, b2, out, N);
}

// Round 13
// 178.690 us; speedup vs baseline: 1.1501x; 1.1026x over previous
//
#include <hip/hip_runtime.h>
#include <hip/hip_bf16.h>

#define HEADS 8
#define HID 16
#define F1 128    // HEADS*HID
#define OUTD 64
#define GP 16          // gemm2 k-panel size
#define BWL 7          // log2(bucket width)
#define BW 128         // dst-range per bucket
#define MAXBUK 512     // >= ceil(N/BW); N=50000 -> 391
#define BCAP 3584      // fixed bucket capacity (mean 2176 + 31 sigma)
#define CHUNK 4096     // edges per block in scatter (256 thr x 16)

typedef unsigned int uint;
typedef unsigned short ushort;
typedef __attribute__((ext_vector_type(8))) short bfrag;   // 8 bf16 (4 VGPR)
typedef __attribute__((ext_vector_type(4))) float f32x4;

__device__ __forceinline__ ushort f2bf(float f) {
  __hip_bfloat16 b = __float2bfloat16(f);
  return *reinterpret_cast<ushort*>(&b);
}
__device__ __forceinline__ float bf2f_lo(uint w) {
  return __uint_as_float((w & 0xFFFFu) << 16);
}
__device__ __forceinline__ float bf2f_hi(uint w) {
  return __uint_as_float(w & 0xFFFF0000u);
}

// ---------------- CSR build (fixed-capacity bucket radix) ----------------
// pairs packed: src in bits [0,20), dst&(BW-1) in bits [20,27). N < 2^20.
// Buckets have fixed stride BCAP; no global scan needed.

__global__ void k_z(int* __restrict__ a, int n) {
  int i = blockIdx.x * blockDim.x + threadIdx.x;
  if (i < n) a[i] = 0;
}

__global__ __launch_bounds__(256) void k_scatter(const int* __restrict__ ei, int E, int N,
                                                 int* __restrict__ bukcur,
                                                 int* __restrict__ pairs) {
  __shared__ int hist[MAXBUK];
  int t = threadIdx.x;
  hist[t] = 0; hist[t + 256] = 0;
  __syncthreads();
  long long e0 = (long long)blockIdx.x * CHUNK;
  int ET = E + N;
  int myP[16], myB[16];
#pragma unroll
  for (int i = 0; i < 16; ++i) {
    long long e = e0 + i * 256 + t;
    if (e < ET) {
      int s = e < E ? ei[e] : (int)(e - E);
      int d = e < E ? ei[E + e] : (int)(e - E);
      myP[i] = s | ((d & (BW - 1)) << 20);
      myB[i] = d >> BWL;
      atomicAdd(&hist[myB[i]], 1);
    } else {
      myB[i] = -1;
    }
  }
  __syncthreads();
  // reserve a contiguous run inside the fixed-stride bucket
  for (int b = t; b < MAXBUK; b += 256) {
    int c = hist[b];
    hist[b] = c ? (b * BCAP + atomicAdd(&bukcur[b], c)) : 0;
  }
  __syncthreads();
#pragma unroll
  for (int i = 0; i < 16; ++i) {
    if (myB[i] >= 0) {
      int pos = atomicAdd(&hist[myB[i]], 1);
      pairs[pos] = myP[i];
    }
  }
}

// per-bucket fine CSR: per-dst [off, offe) within the bucket's fixed region.
__global__ __launch_bounds__(256) void k_csr(const int* __restrict__ pairs,
                                             const int* __restrict__ bukcur,
                                             int* __restrict__ off, int* __restrict__ offe,
                                             int* __restrict__ csr, int N) {
  __shared__ int cnt[BW];
  __shared__ int cur[BW];
  int b = blockIdx.x, t = threadIdx.x;
  int beg = b * BCAP, end = beg + bukcur[b];
  if (t < BW) cnt[t] = 0;
  __syncthreads();
  for (int j = beg + t; j < end; j += 256)
    atomicAdd(&cnt[(pairs[j] >> 20) & (BW - 1)], 1);
  __syncthreads();
  int my = t < BW ? cnt[t] : 0;
  for (int o = 1; o < BW; o <<= 1) {
    int v = (t < BW && t >= o) ? cnt[t - o] : 0;
    __syncthreads();
    if (t < BW) cnt[t] += v;
    __syncthreads();
  }
  if (t < BW) {
    int start = beg + cnt[t] - my;   // exclusive within bucket
    cur[t] = start;
    int d0 = b * BW + t;
    if (d0 < N) { off[d0] = start; offe[d0] = start + my; }
  }
  __syncthreads();
  for (int j = beg + t; j < end; j += 256) {
    int pr = pairs[j];
    int pos = atomicAdd(&cur[(pr >> 20) & (BW - 1)], 1);
    csr[pos] = pr & 0xFFFFF;
  }
}

// ---------------- W1 transpose+bf16 convert (once) ----------------
// W1t[c][k] bf16, row-major 128x128.
__global__ void k_wcvt(const float* __restrict__ W1, ushort* __restrict__ W1t) {
  int o = blockIdx.x * 256 + threadIdx.x;   // o = c*128 + k; grid 64 blocks
  int c = o >> 7, k = o & 127;
  W1t[o] = f2bf(W1[k * F1 + c]);
}

// ---------------- layer 1 GEMM (MFMA bf16) ----------------
// 64 rows/block, 4 waves x 16-row strips. x and W1t staged bf16 in LDS
// (padded stride 136). 8 col-tiles x 4 k-steps of mfma_f32_16x16x32_bf16.
// C/D layout: col=lane&15, row=(lane>>4)*4+reg. head = col-tile (n0).
__global__ __launch_bounds__(256) void k_gemm1(
    const float* __restrict__ x, const ushort* __restrict__ W1t,
    const float* __restrict__ as, const float* __restrict__ ad,
    uint* __restrict__ hA, uint* __restrict__ hB,
    float* __restrict__ a_src, float* __restrict__ a_dst, int N) {
  __shared__ __align__(16) ushort xl[64 * 136];    // 17.0 KB
  __shared__ __align__(16) ushort wl[128 * 136];   // 34.0 KB
  int tx = threadIdx.x;
  int r0 = blockIdx.x * 64;

  // stage W1t -> LDS (thread: c = tx>>1, k-half = (tx&1)*64)
  {
    int c = tx >> 1, k0 = (tx & 1) * 64;
    const uint4* g = reinterpret_cast<const uint4*>(W1t + c * F1 + k0);
#pragma unroll
    for (int j = 0; j < 8; ++j)
      *reinterpret_cast<uint4*>(&wl[c * 136 + k0 + j * 8]) = g[j];
  }
  // stage x tile (f32 -> bf16)
  {
    int row = tx & 63, kq = tx >> 6;
    bool act = (r0 + row) < N;
    const float4* xg = reinterpret_cast<const float4*>(x + (size_t)(r0 + row) * F1 + kq * 32);
#pragma unroll
    for (int j = 0; j < 4; ++j) {
      float4 va = act ? xg[2 * j]     : make_float4(0.f, 0.f, 0.f, 0.f);
      float4 vb = act ? xg[2 * j + 1] : make_float4(0.f, 0.f, 0.f, 0.f);
      uint4 pk;
      pk.x = (uint)f2bf(va.x) | ((uint)f2bf(va.y) << 16);
      pk.y = (uint)f2bf(va.z) | ((uint)f2bf(va.w) << 16);
      pk.z = (uint)f2bf(vb.x) | ((uint)f2bf(vb.y) << 16);
      pk.w = (uint)f2bf(vb.z) | ((uint)f2bf(vb.w) << 16);
      *reinterpret_cast<uint4*>(&xl[row * 136 + kq * 32 + j * 8]) = pk;
    }
  }
  __syncthreads();

  int w = tx >> 6, l = tx & 63;
  int lr = l & 15, lo = l >> 4;   // frag row/col index, k-octet

  bfrag af[4];
#pragma unroll
  for (int ks = 0; ks < 4; ++ks)
    af[ks] = *reinterpret_cast<const bfrag*>(&xl[(w * 16 + lr) * 136 + ks * 32 + lo * 8]);

  f32x4 acc[8];
#pragma unroll
  for (int n0 = 0; n0 < 8; ++n0) {
    acc[n0] = (f32x4){0.f, 0.f, 0.f, 0.f};
#pragma unroll
    for (int ks = 0; ks < 4; ++ks) {
      bfrag bf = *reinterpret_cast<const bfrag*>(&wl[(n0 * 16 + lr) * 136 + ks * 32 + lo * 8]);
      acc[n0] = __builtin_amdgcn_mfma_f32_16x16x32_bf16(af[ks], bf, acc[n0], 0, 0, 0);
    }
  }

  // epilogue: h-table stores (bf16) + per-head attention dots
#pragma unroll
  for (int n0 = 0; n0 < 8; ++n0) {
    float asv = as[n0 * 16 + lr];
    float adv = ad[n0 * 16 + lr];
    ushort* tp = reinterpret_cast<ushort*>(n0 < 4 ? hA : hB);
    int cbase = (n0 & 3) * 16 + lr;
#pragma unroll
    for (int r = 0; r < 4; ++r) {
      int row = r0 + w * 16 + lo * 4 + r;
      float hv = acc[n0][r];
      float ps = hv * asv, pd = hv * adv;
      ps += __shfl_xor(ps, 1); ps += __shfl_xor(ps, 2);
      ps += __shfl_xor(ps, 4); ps += __shfl_xor(ps, 8);
      pd += __shfl_xor(pd, 1); pd += __shfl_xor(pd, 2);
      pd += __shfl_xor(pd, 4); pd += __shfl_xor(pd, 8);
      if (row < N) {
        tp[(size_t)row * 64 + cbase] = f2bf(hv);
        if (lr == 0) {
          a_src[row * HEADS + n0] = ps;
          a_dst[row * HEADS + n0] = pd;
        }
      }
    }
  }
}

// ---------------- layer 1 aggregate (channel-split half-table pass) ----------------
__global__ void k_agg1h(const int* __restrict__ off, const int* __restrict__ offe,
                        const int* __restrict__ csr,
                        const uint2* __restrict__ htab, const float* __restrict__ a_src,
                        const float* __restrict__ a_dst, const float* __restrict__ b1,
                        float* __restrict__ out1, int N, int hbase, int obase) {
  int w = threadIdx.x >> 6, lane = threadIdx.x & 63;
  int q = lane >> 4, c2 = lane & 15;   // half-channels 4c2..4c2+3
  int h = hbase + (c2 >> 2);
  int d = blockIdx.x * 4 + w;
  if (d >= N) return;
  int beg = off[d], end = offe[d];
  float adl = a_dst[d * HEADS + h];
  float a0 = 0.f, a1 = 0.f, a2 = 0.f, a3 = 0.f, den = 0.f;
#pragma unroll 2
  for (int j = beg + q; j < end; j += 4) {
    int s = csr[j];
    float v = a_src[s * HEADS + h] + adl;
    v = v >= 0.f ? v : 0.2f * v;
    float p = __expf(v);
    uint2 wd = htab[(size_t)s * 16 + c2];
    a0 = fmaf(p, bf2f_lo(wd.x), a0);
    a1 = fmaf(p, bf2f_hi(wd.x), a1);
    a2 = fmaf(p, bf2f_lo(wd.y), a2);
    a3 = fmaf(p, bf2f_hi(wd.y), a3);
    den += p;
  }
  a0 += __shfl_xor(a0, 16); a0 += __shfl_xor(a0, 32);
  a1 += __shfl_xor(a1, 16); a1 += __shfl_xor(a1, 32);
  a2 += __shfl_xor(a2, 16); a2 += __shfl_xor(a2, 32);
  a3 += __shfl_xor(a3, 16); a3 += __shfl_xor(a3, 32);
  den += __shfl_xor(den, 16); den += __shfl_xor(den, 32);
  if (q == 0) {
    float inv = 1.f / den;   // self-loop guarantees den > 0
    float4 bb = *reinterpret_cast<const float4*>(&b1[obase + 4 * c2]);
    float4 o;
    o.x = a0 * inv + bb.x;
    o.y = a1 * inv + bb.y;
    o.z = a2 * inv + bb.z;
    o.w = a3 * inv + bb.w;
    *reinterpret_cast<float4*>(&out1[(size_t)d * F1 + obase + 4 * c2]) = o;
  }
}

// ---------------- layer 2 GEMM (k-panel, W in LDS) ----------------
__global__ __launch_bounds__(256) void k_gemm2(
    const float* __restrict__ out1, const float* __restrict__ W2,
    const float* __restrict__ as2, const float* __restrict__ ad2,
    uint* __restrict__ h2b, float* __restrict__ a_src2,
    float* __restrict__ a_dst2, int N) {
  __shared__ float xs2[GP][64];
  __shared__ float ws2[GP][OUTD];
  int tx = threadIdx.x;
  int cg = tx & 15;
  int rg = tx >> 4;
  int r0 = blockIdx.x * 64;
  int rowL = tx & 63, kq = tx >> 6;
  int wc4 = tx & 15, wk = tx >> 4;
  bool xact = (r0 + rowL) < N;

  float acc[4][4];
#pragma unroll
  for (int i = 0; i < 4; ++i)
#pragma unroll
    for (int j = 0; j < 4; ++j) acc[i][j] = 0.f;

#pragma unroll
  for (int p = 0; p < F1 / GP; ++p) {
    int k0 = p * GP;
    float4 v = make_float4(0.f, 0.f, 0.f, 0.f);
    if (xact) v = *reinterpret_cast<const float4*>(&out1[(size_t)(r0 + rowL) * F1 + k0 + kq * 4]);
    v.x = v.x > 0.f ? v.x : __expf(v.x) - 1.f;
    v.y = v.y > 0.f ? v.y : __expf(v.y) - 1.f;
    v.z = v.z > 0.f ? v.z : __expf(v.z) - 1.f;
    v.w = v.w > 0.f ? v.w : __expf(v.w) - 1.f;
    xs2[kq * 4 + 0][rowL] = v.x;
    xs2[kq * 4 + 1][rowL] = v.y;
    xs2[kq * 4 + 2][rowL] = v.z;
    xs2[kq * 4 + 3][rowL] = v.w;
    *reinterpret_cast<float4*>(&ws2[wk][wc4 * 4]) =
        *reinterpret_cast<const float4*>(&W2[(k0 + wk) * OUTD + wc4 * 4]);
    __syncthreads();
#pragma unroll
    for (int k = 0; k < GP; ++k) {
      float4 w = *reinterpret_cast<const float4*>(&ws2[k][cg * 4]);
      float4 xv = *reinterpret_cast<const float4*>(&xs2[k][rg * 4]);
      const float xr[4] = {xv.x, xv.y, xv.z, xv.w};
#pragma unroll
      for (int i = 0; i < 4; ++i) {
        acc[i][0] = fmaf(xr[i], w.x, acc[i][0]);
        acc[i][1] = fmaf(xr[i], w.y, acc[i][1]);
        acc[i][2] = fmaf(xr[i], w.z, acc[i][2]);
        acc[i][3] = fmaf(xr[i], w.w, acc[i][3]);
      }
    }
    __syncthreads();
  }

  float4 as4 = *reinterpret_cast<const float4*>(&as2[4 * cg]);
  float4 ad4 = *reinterpret_cast<const float4*>(&ad2[4 * cg]);
#pragma unroll
  for (int i = 0; i < 4; ++i) {
    int row = r0 + rg * 4 + i;
    bool act = row < N;
    if (act) {
      uint2 pk;
      pk.x = (uint)f2bf(acc[i][0]) | ((uint)f2bf(acc[i][1]) << 16);
      pk.y = (uint)f2bf(acc[i][2]) | ((uint)f2bf(acc[i][3]) << 16);
      *reinterpret_cast<uint2*>(&h2b[(size_t)row * 32 + 2 * cg]) = pk;
    }
    float ps = acc[i][0] * as4.x + acc[i][1] * as4.y + acc[i][2] * as4.z + acc[i][3] * as4.w;
    float pd = acc[i][0] * ad4.x + acc[i][1] * ad4.y + acc[i][2] * ad4.z + acc[i][3] * ad4.w;
    ps += __shfl_xor(ps, 1); ps += __shfl_xor(ps, 2);
    ps += __shfl_xor(ps, 4); ps += __shfl_xor(ps, 8);
    pd += __shfl_xor(pd, 1); pd += __shfl_xor(pd, 2);
    pd += __shfl_xor(pd, 4); pd += __shfl_xor(pd, 8);
    if (act && cg == 0) {
      a_src2[row] = ps;
      a_dst2[row] = pd;
    }
  }
}

// ---------------- layer 2 aggregate ----------------
__global__ void k_agg2(const int* __restrict__ off, const int* __restrict__ offe,
                       const int* __restrict__ csr,
                       const uint2* __restrict__ h2b2, const float* __restrict__ a_src2,
                       const float* __restrict__ a_dst2, const float* __restrict__ b2,
                       float* __restrict__ out, int N) {
  int w = threadIdx.x >> 6, lane = threadIdx.x & 63;
  int q = lane >> 4, c2 = lane & 15;
  int d = blockIdx.x * 4 + w;
  if (d >= N) return;
  int beg = off[d], end = offe[d];
  float adl = a_dst2[d];
  float a0 = 0.f, a1 = 0.f, a2 = 0.f, a3 = 0.f, den = 0.f;
#pragma unroll 2
  for (int j = beg + q; j < end; j += 4) {
    int s = csr[j];
    float v = a_src2[s] + adl;
    v = v >= 0.f ? v : 0.2f * v;
    float p = __expf(v);
    uint2 wd = h2b2[(size_t)s * 16 + c2];
    a0 = fmaf(p, bf2f_lo(wd.x), a0);
    a1 = fmaf(p, bf2f_hi(wd.x), a1);
    a2 = fmaf(p, bf2f_lo(wd.y), a2);
    a3 = fmaf(p, bf2f_hi(wd.y), a3);
    den += p;
  }
  a0 += __shfl_xor(a0, 16); a0 += __shfl_xor(a0, 32);
  a1 += __shfl_xor(a1, 16); a1 += __shfl_xor(a1, 32);
  a2 += __shfl_xor(a2, 16); a2 += __shfl_xor(a2, 32);
  a3 += __shfl_xor(a3, 16); a3 += __shfl_xor(a3, 32);
  den += __shfl_xor(den, 16); den += __shfl_xor(den, 32);
  if (q == 0) {
    float inv = 1.f / den;
    float4 bb = *reinterpret_cast<const float4*>(&b2[4 * c2]);
    float4 o;
    o.x = a0 * inv + bb.x;
    o.y = a1 * inv + bb.y;
    o.z = a2 * inv + bb.z;
    o.w = a3 * inv + bb.w;
    *reinterpret_cast<float4*>(&out[(size_t)d * OUTD + 4 * c2]) = o;
  }
}

extern "C" void kernel_launch(void* const* d_in, const int* in_sizes, int n_in,
                              void* d_out, int out_size, void* d_ws, size_t ws_size,
                              hipStream_t stream) {
  const float* x   = (const float*)d_in[0];
  const int*   ei  = (const int*)d_in[1];
  const float* W1  = (const float*)d_in[2];
  const float* as1 = (const float*)d_in[3];
  const float* ad1 = (const float*)d_in[4];
  const float* b1  = (const float*)d_in[5];
  const float* W2  = (const float*)d_in[6];
  const float* as2 = (const float*)d_in[7];
  const float* ad2 = (const float*)d_in[8];
  const float* b2  = (const float*)d_in[9];
  float* out = (float*)d_out;

  int N = in_sizes[0] / F1;
  int E = in_sizes[1] / 2;
  int ET = E + N;
  int NBUK = (N + BW - 1) / BW;       // 391 for N=50000 (<= MAXBUK)
  int NCH = (ET + CHUNK - 1) / CHUNK; // scatter blocks
  int NT = (N + 63) / 64;             // GEMM tiles (64 rows)

  // workspace layout (16B-aligned chunks)
  char* p = (char*)d_ws;
  auto alloc = [&](size_t bytes) {
    char* q = p;
    p += (bytes + 15) & ~(size_t)15;
    return q;
  };
  int* bukcur  = (int*)alloc((size_t)NBUK * 4);
  int* off     = (int*)alloc((size_t)N * 4);
  int* offe    = (int*)alloc((size_t)N * 4);
  int* pairs   = (int*)alloc((size_t)NBUK * BCAP * 4);
  int* csr     = (int*)alloc((size_t)NBUK * BCAP * 4);
  ushort* W1t  = (ushort*)alloc((size_t)F1 * F1 * 2);
  uint* hA     = (uint*)alloc((size_t)N * 32 * 4);   // heads 0-3
  uint* hB     = (uint*)alloc((size_t)N * 32 * 4);   // heads 4-7
  uint* h2b    = (uint*)alloc((size_t)N * 32 * 4);
  float* out1  = (float*)alloc((size_t)N * F1 * 4);
  float* a_src1 = (float*)alloc((size_t)N * HEADS * 4);
  float* a_dst1 = (float*)alloc((size_t)N * HEADS * 4);
  float* a_src2 = (float*)alloc((size_t)N * 4);
  float* a_dst2 = (float*)alloc((size_t)N * 4);

  // CSR build (no global scan: fixed-capacity buckets)
  hipLaunchKernelGGL(k_z, dim3((NBUK + 255) / 256), dim3(256), 0, stream, bukcur, NBUK);
  hipLaunchKernelGGL(k_scatter, dim3(NCH), dim3(256), 0, stream, ei, E, N, bukcur, pairs);
  hipLaunchKernelGGL(k_csr, dim3(NBUK), dim3(256), 0, stream,
                     pairs, bukcur, off, offe, csr, N);

  // W1 transpose/convert + layer-1 MFMA GEMM
  hipLaunchKernelGGL(k_wcvt, dim3(64), dim3(256), 0, stream, W1, W1t);
  hipLaunchKernelGGL(k_gemm1, dim3(NT), dim3(256), 0, stream,
                     x, W1t, as1, ad1, hA, hB, a_src1, a_dst1, N);
  hipLaunchKernelGGL(k_agg1h, dim3((N + 3) / 4), dim3(256), 0, stream,
                     off, offe, csr, (const uint2*)hA, a_src1, a_dst1, b1, out1, N, 0, 0);
  hipLaunchKernelGGL(k_agg1h, dim3((N + 3) / 4), dim3(256), 0, stream,
                     off, offe, csr, (const uint2*)hB, a_src1, a_dst1, b1, out1, N, 4, 64);

  // layer 2
  hipLaunchKernelGGL(k_gemm2, dim3(NT), dim3(256), 0, stream,
                     out1, W2, as2, ad2, h2b, a_src2, a_dst2, N);
  hipLaunchKernelGGL(k_agg2, dim3((N + 3) / 4), dim3(256), 0, stream,
                     off, offe, csr, (const uint2*)h2b, a_src2, a_dst2, b2, out, N);
}

// Round 14
// 171.045 us; speedup vs baseline: 1.2015x; 1.0447x over previous
//
#include <hip/hip_runtime.h>
#include <hip/hip_bf16.h>

#define HEADS 8
#define HID 16
#define F1 128    // HEADS*HID
#define OUTD 64
#define BWL 7          // log2(bucket width)
#define BW 128         // dst-range per bucket
#define MAXBUK 512     // >= ceil(N/BW); N=50000 -> 391
#define BCAP 3584      // fixed bucket capacity (mean 2176 + 31 sigma)
#define CHUNK 4096     // edges per block in scatter (256 thr x 16)

typedef unsigned int uint;
typedef unsigned short ushort;
typedef __attribute__((ext_vector_type(8))) short bfrag;   // 8 bf16 (4 VGPR)
typedef __attribute__((ext_vector_type(4))) float f32x4;

__device__ __forceinline__ ushort f2bf(float f) {
  __hip_bfloat16 b = __float2bfloat16(f);
  return *reinterpret_cast<ushort*>(&b);
}
__device__ __forceinline__ float bf2f_lo(uint w) {
  return __uint_as_float((w & 0xFFFFu) << 16);
}
__device__ __forceinline__ float bf2f_hi(uint w) {
  return __uint_as_float(w & 0xFFFF0000u);
}

// ---------------- CSR build (fixed-capacity bucket radix) ----------------
// pairs packed: src in bits [0,20), dst&(BW-1) in bits [20,27). N < 2^20.

__global__ void k_z(int* __restrict__ a, int n) {
  int i = blockIdx.x * blockDim.x + threadIdx.x;
  if (i < n) a[i] = 0;
}

__global__ __launch_bounds__(256) void k_scatter(const int* __restrict__ ei, int E, int N,
                                                 int* __restrict__ bukcur,
                                                 int* __restrict__ pairs) {
  __shared__ int hist[MAXBUK];
  int t = threadIdx.x;
  hist[t] = 0; hist[t + 256] = 0;
  __syncthreads();
  long long e0 = (long long)blockIdx.x * CHUNK;
  int ET = E + N;
  int myP[16], myB[16];
#pragma unroll
  for (int i = 0; i < 16; ++i) {
    long long e = e0 + i * 256 + t;
    if (e < ET) {
      int s = e < E ? ei[e] : (int)(e - E);
      int d = e < E ? ei[E + e] : (int)(e - E);
      myP[i] = s | ((d & (BW - 1)) << 20);
      myB[i] = d >> BWL;
      atomicAdd(&hist[myB[i]], 1);
    } else {
      myB[i] = -1;
    }
  }
  __syncthreads();
  for (int b = t; b < MAXBUK; b += 256) {
    int c = hist[b];
    hist[b] = c ? (b * BCAP + atomicAdd(&bukcur[b], c)) : 0;
  }
  __syncthreads();
#pragma unroll
  for (int i = 0; i < 16; ++i) {
    if (myB[i] >= 0) {
      int pos = atomicAdd(&hist[myB[i]], 1);
      pairs[pos] = myP[i];
    }
  }
}

__global__ __launch_bounds__(256) void k_csr(const int* __restrict__ pairs,
                                             const int* __restrict__ bukcur,
                                             int* __restrict__ off, int* __restrict__ offe,
                                             int* __restrict__ csr, int N) {
  __shared__ int cnt[BW];
  __shared__ int cur[BW];
  int b = blockIdx.x, t = threadIdx.x;
  int beg = b * BCAP, end = beg + bukcur[b];
  if (t < BW) cnt[t] = 0;
  __syncthreads();
  for (int j = beg + t; j < end; j += 256)
    atomicAdd(&cnt[(pairs[j] >> 20) & (BW - 1)], 1);
  __syncthreads();
  int my = t < BW ? cnt[t] : 0;
  for (int o = 1; o < BW; o <<= 1) {
    int v = (t < BW && t >= o) ? cnt[t - o] : 0;
    __syncthreads();
    if (t < BW) cnt[t] += v;
    __syncthreads();
  }
  if (t < BW) {
    int start = beg + cnt[t] - my;   // exclusive within bucket
    cur[t] = start;
    int d0 = b * BW + t;
    if (d0 < N) { off[d0] = start; offe[d0] = start + my; }
  }
  __syncthreads();
  for (int j = beg + t; j < end; j += 256) {
    int pr = pairs[j];
    int pos = atomicAdd(&cur[(pr >> 20) & (BW - 1)], 1);
    csr[pos] = pr & 0xFFFFF;
  }
}

// ---------------- W transpose+bf16 convert (once) ----------------
// W1t[c][k] bf16 128x128; W2t[c][k] bf16 64x128.
__global__ void k_wcvt(const float* __restrict__ W1, const float* __restrict__ W2,
                       ushort* __restrict__ W1t, ushort* __restrict__ W2t) {
  int o = blockIdx.x * 256 + threadIdx.x;
  if (o < F1 * F1) {
    int c = o >> 7, k = o & 127;
    W1t[o] = f2bf(W1[k * F1 + c]);
  } else if (o < F1 * F1 + OUTD * F1) {
    int i = o - F1 * F1;
    int c = i >> 7, k = i & 127;
    W2t[i] = f2bf(W2[k * OUTD + c]);
  }
}

// ---------------- layer 1 GEMM (MFMA bf16) ----------------
// 64 rows/block, 4 waves x 16-row strips; 8 col-tiles x 4 k-steps.
// C/D layout: col=lane&15, row=(lane>>4)*4+reg. head = col-tile (n0).
__global__ __launch_bounds__(256) void k_gemm1(
    const float* __restrict__ x, const ushort* __restrict__ W1t,
    const float* __restrict__ as, const float* __restrict__ ad,
    uint* __restrict__ hA, uint* __restrict__ hB,
    float* __restrict__ a_src, float* __restrict__ a_dst, int N) {
  __shared__ __align__(16) ushort xl[64 * 136];    // 17.0 KB
  __shared__ __align__(16) ushort wl[128 * 136];   // 34.0 KB
  int tx = threadIdx.x;
  int r0 = blockIdx.x * 64;

  {
    int c = tx >> 1, k0 = (tx & 1) * 64;
    const uint4* g = reinterpret_cast<const uint4*>(W1t + c * F1 + k0);
#pragma unroll
    for (int j = 0; j < 8; ++j)
      *reinterpret_cast<uint4*>(&wl[c * 136 + k0 + j * 8]) = g[j];
  }
  {
    int row = tx & 63, kq = tx >> 6;
    bool act = (r0 + row) < N;
    const float4* xg = reinterpret_cast<const float4*>(x + (size_t)(r0 + row) * F1 + kq * 32);
#pragma unroll
    for (int j = 0; j < 4; ++j) {
      float4 va = act ? xg[2 * j]     : make_float4(0.f, 0.f, 0.f, 0.f);
      float4 vb = act ? xg[2 * j + 1] : make_float4(0.f, 0.f, 0.f, 0.f);
      uint4 pk;
      pk.x = (uint)f2bf(va.x) | ((uint)f2bf(va.y) << 16);
      pk.y = (uint)f2bf(va.z) | ((uint)f2bf(va.w) << 16);
      pk.z = (uint)f2bf(vb.x) | ((uint)f2bf(vb.y) << 16);
      pk.w = (uint)f2bf(vb.z) | ((uint)f2bf(vb.w) << 16);
      *reinterpret_cast<uint4*>(&xl[row * 136 + kq * 32 + j * 8]) = pk;
    }
  }
  __syncthreads();

  int w = tx >> 6, l = tx & 63;
  int lr = l & 15, lo = l >> 4;

  bfrag af[4];
#pragma unroll
  for (int ks = 0; ks < 4; ++ks)
    af[ks] = *reinterpret_cast<const bfrag*>(&xl[(w * 16 + lr) * 136 + ks * 32 + lo * 8]);

  f32x4 acc[8];
#pragma unroll
  for (int n0 = 0; n0 < 8; ++n0) {
    acc[n0] = (f32x4){0.f, 0.f, 0.f, 0.f};
#pragma unroll
    for (int ks = 0; ks < 4; ++ks) {
      bfrag bf = *reinterpret_cast<const bfrag*>(&wl[(n0 * 16 + lr) * 136 + ks * 32 + lo * 8]);
      acc[n0] = __builtin_amdgcn_mfma_f32_16x16x32_bf16(af[ks], bf, acc[n0], 0, 0, 0);
    }
  }

#pragma unroll
  for (int n0 = 0; n0 < 8; ++n0) {
    float asv = as[n0 * 16 + lr];
    float adv = ad[n0 * 16 + lr];
    ushort* tp = reinterpret_cast<ushort*>(n0 < 4 ? hA : hB);
    int cbase = (n0 & 3) * 16 + lr;
#pragma unroll
    for (int r = 0; r < 4; ++r) {
      int row = r0 + w * 16 + lo * 4 + r;
      float hv = acc[n0][r];
      float ps = hv * asv, pd = hv * adv;
      ps += __shfl_xor(ps, 1); ps += __shfl_xor(ps, 2);
      ps += __shfl_xor(ps, 4); ps += __shfl_xor(ps, 8);
      pd += __shfl_xor(pd, 1); pd += __shfl_xor(pd, 2);
      pd += __shfl_xor(pd, 4); pd += __shfl_xor(pd, 8);
      if (row < N) {
        tp[(size_t)row * 64 + cbase] = f2bf(hv);
        if (lr == 0) {
          a_src[row * HEADS + n0] = ps;
          a_dst[row * HEADS + n0] = pd;
        }
      }
    }
  }
}

// ---------------- layer 1 aggregate (channel-split half-table pass) ----------------
__global__ void k_agg1h(const int* __restrict__ off, const int* __restrict__ offe,
                        const int* __restrict__ csr,
                        const uint2* __restrict__ htab, const float* __restrict__ a_src,
                        const float* __restrict__ a_dst, const float* __restrict__ b1,
                        float* __restrict__ out1, int N, int hbase, int obase) {
  int w = threadIdx.x >> 6, lane = threadIdx.x & 63;
  int q = lane >> 4, c2 = lane & 15;
  int h = hbase + (c2 >> 2);
  int d = blockIdx.x * 4 + w;
  if (d >= N) return;
  int beg = off[d], end = offe[d];
  float adl = a_dst[d * HEADS + h];
  float a0 = 0.f, a1 = 0.f, a2 = 0.f, a3 = 0.f, den = 0.f;
#pragma unroll 2
  for (int j = beg + q; j < end; j += 4) {
    int s = csr[j];
    float v = a_src[s * HEADS + h] + adl;
    v = v >= 0.f ? v : 0.2f * v;
    float p = __expf(v);
    uint2 wd = htab[(size_t)s * 16 + c2];
    a0 = fmaf(p, bf2f_lo(wd.x), a0);
    a1 = fmaf(p, bf2f_hi(wd.x), a1);
    a2 = fmaf(p, bf2f_lo(wd.y), a2);
    a3 = fmaf(p, bf2f_hi(wd.y), a3);
    den += p;
  }
  a0 += __shfl_xor(a0, 16); a0 += __shfl_xor(a0, 32);
  a1 += __shfl_xor(a1, 16); a1 += __shfl_xor(a1, 32);
  a2 += __shfl_xor(a2, 16); a2 += __shfl_xor(a2, 32);
  a3 += __shfl_xor(a3, 16); a3 += __shfl_xor(a3, 32);
  den += __shfl_xor(den, 16); den += __shfl_xor(den, 32);
  if (q == 0) {
    float inv = 1.f / den;   // self-loop guarantees den > 0
    float4 bb = *reinterpret_cast<const float4*>(&b1[obase + 4 * c2]);
    float4 o;
    o.x = a0 * inv + bb.x;
    o.y = a1 * inv + bb.y;
    o.z = a2 * inv + bb.z;
    o.w = a3 * inv + bb.w;
    *reinterpret_cast<float4*>(&out1[(size_t)d * F1 + obase + 4 * c2]) = o;
  }
}

// ---------------- layer 2 GEMM (MFMA bf16, ELU fused into staging) ----------------
// 64 rows/block, 4 waves x 16-row strips; 4 col-tiles x 4 k-steps.
__global__ __launch_bounds__(256) void k_gemm2(
    const float* __restrict__ out1, const ushort* __restrict__ W2t,
    const float* __restrict__ as2, const float* __restrict__ ad2,
    uint* __restrict__ h2b, float* __restrict__ a_src2,
    float* __restrict__ a_dst2, int N) {
  __shared__ __align__(16) ushort xl[64 * 136];   // 17.0 KB
  __shared__ __align__(16) ushort wl[64 * 136];   // 17.0 KB
  int tx = threadIdx.x;
  int r0 = blockIdx.x * 64;

  // stage W2t (64 c-rows x 128 k)
  {
    int c = tx & 63, k0 = (tx >> 6) * 32;
    const uint4* g = reinterpret_cast<const uint4*>(W2t + c * F1 + k0);
#pragma unroll
    for (int j = 0; j < 4; ++j)
      *reinterpret_cast<uint4*>(&wl[c * 136 + k0 + j * 8]) = g[j];
  }
  // stage elu(out1) tile (f32 -> bf16)
  {
    int row = tx & 63, kq = tx >> 6;
    bool act = (r0 + row) < N;
    const float4* xg = reinterpret_cast<const float4*>(out1 + (size_t)(r0 + row) * F1 + kq * 32);
#pragma unroll
    for (int j = 0; j < 4; ++j) {
      float4 va = act ? xg[2 * j]     : make_float4(0.f, 0.f, 0.f, 0.f);
      float4 vb = act ? xg[2 * j + 1] : make_float4(0.f, 0.f, 0.f, 0.f);
      va.x = va.x > 0.f ? va.x : __expf(va.x) - 1.f;
      va.y = va.y > 0.f ? va.y : __expf(va.y) - 1.f;
      va.z = va.z > 0.f ? va.z : __expf(va.z) - 1.f;
      va.w = va.w > 0.f ? va.w : __expf(va.w) - 1.f;
      vb.x = vb.x > 0.f ? vb.x : __expf(vb.x) - 1.f;
      vb.y = vb.y > 0.f ? vb.y : __expf(vb.y) - 1.f;
      vb.z = vb.z > 0.f ? vb.z : __expf(vb.z) - 1.f;
      vb.w = vb.w > 0.f ? vb.w : __expf(vb.w) - 1.f;
      uint4 pk;
      pk.x = (uint)f2bf(va.x) | ((uint)f2bf(va.y) << 16);
      pk.y = (uint)f2bf(va.z) | ((uint)f2bf(va.w) << 16);
      pk.z = (uint)f2bf(vb.x) | ((uint)f2bf(vb.y) << 16);
      pk.w = (uint)f2bf(vb.z) | ((uint)f2bf(vb.w) << 16);
      *reinterpret_cast<uint4*>(&xl[row * 136 + kq * 32 + j * 8]) = pk;
    }
  }
  __syncthreads();

  int w = tx >> 6, l = tx & 63;
  int lr = l & 15, lo = l >> 4;

  bfrag af[4];
#pragma unroll
  for (int ks = 0; ks < 4; ++ks)
    af[ks] = *reinterpret_cast<const bfrag*>(&xl[(w * 16 + lr) * 136 + ks * 32 + lo * 8]);

  f32x4 acc[4];
#pragma unroll
  for (int n0 = 0; n0 < 4; ++n0) {
    acc[n0] = (f32x4){0.f, 0.f, 0.f, 0.f};
#pragma unroll
    for (int ks = 0; ks < 4; ++ks) {
      bfrag bf = *reinterpret_cast<const bfrag*>(&wl[(n0 * 16 + lr) * 136 + ks * 32 + lo * 8]);
      acc[n0] = __builtin_amdgcn_mfma_f32_16x16x32_bf16(af[ks], bf, acc[n0], 0, 0, 0);
    }
  }

  // epilogue: bf16 stores + scalar attention dots (sum over all 64 cols)
  float asv[4], adv[4];
#pragma unroll
  for (int n0 = 0; n0 < 4; ++n0) {
    asv[n0] = as2[n0 * 16 + lr];
    adv[n0] = ad2[n0 * 16 + lr];
  }
  ushort* tp = reinterpret_cast<ushort*>(h2b);
#pragma unroll
  for (int r = 0; r < 4; ++r) {
    int row = r0 + w * 16 + lo * 4 + r;
    float ps = 0.f, pd = 0.f;
#pragma unroll
    for (int n0 = 0; n0 < 4; ++n0) {
      float hv = acc[n0][r];
      ps = fmaf(hv, asv[n0], ps);
      pd = fmaf(hv, adv[n0], pd);
    }
    ps += __shfl_xor(ps, 1); ps += __shfl_xor(ps, 2);
    ps += __shfl_xor(ps, 4); ps += __shfl_xor(ps, 8);
    pd += __shfl_xor(pd, 1); pd += __shfl_xor(pd, 2);
    pd += __shfl_xor(pd, 4); pd += __shfl_xor(pd, 8);
    if (row < N) {
#pragma unroll
      for (int n0 = 0; n0 < 4; ++n0)
        tp[(size_t)row * 64 + n0 * 16 + lr] = f2bf(acc[n0][r]);
      if (lr == 0) {
        a_src2[row] = ps;
        a_dst2[row] = pd;
      }
    }
  }
}

// ---------------- layer 2 aggregate ----------------
__global__ void k_agg2(const int* __restrict__ off, const int* __restrict__ offe,
                       const int* __restrict__ csr,
                       const uint2* __restrict__ h2b2, const float* __restrict__ a_src2,
                       const float* __restrict__ a_dst2, const float* __restrict__ b2,
                       float* __restrict__ out, int N) {
  int w = threadIdx.x >> 6, lane = threadIdx.x & 63;
  int q = lane >> 4, c2 = lane & 15;
  int d = blockIdx.x * 4 + w;
  if (d >= N) return;
  int beg = off[d], end = offe[d];
  float adl = a_dst2[d];
  float a0 = 0.f, a1 = 0.f, a2 = 0.f, a3 = 0.f, den = 0.f;
#pragma unroll 2
  for (int j = beg + q; j < end; j += 4) {
    int s = csr[j];
    float v = a_src2[s] + adl;
    v = v >= 0.f ? v : 0.2f * v;
    float p = __expf(v);
    uint2 wd = h2b2[(size_t)s * 16 + c2];
    a0 = fmaf(p, bf2f_lo(wd.x), a0);
    a1 = fmaf(p, bf2f_hi(wd.x), a1);
    a2 = fmaf(p, bf2f_lo(wd.y), a2);
    a3 = fmaf(p, bf2f_hi(wd.y), a3);
    den += p;
  }
  a0 += __shfl_xor(a0, 16); a0 += __shfl_xor(a0, 32);
  a1 += __shfl_xor(a1, 16); a1 += __shfl_xor(a1, 32);
  a2 += __shfl_xor(a2, 16); a2 += __shfl_xor(a2, 32);
  a3 += __shfl_xor(a3, 16); a3 += __shfl_xor(a3, 32);
  den += __shfl_xor(den, 16); den += __shfl_xor(den, 32);
  if (q == 0) {
    float inv = 1.f / den;
    float4 bb = *reinterpret_cast<const float4*>(&b2[4 * c2]);
    float4 o;
    o.x = a0 * inv + bb.x;
    o.y = a1 * inv + bb.y;
    o.z = a2 * inv + bb.z;
    o.w = a3 * inv + bb.w;
    *reinterpret_cast<float4*>(&out[(size_t)d * OUTD + 4 * c2]) = o;
  }
}

extern "C" void kernel_launch(void* const* d_in, const int* in_sizes, int n_in,
                              void* d_out, int out_size, void* d_ws, size_t ws_size,
                              hipStream_t stream) {
  const float* x   = (const float*)d_in[0];
  const int*   ei  = (const int*)d_in[1];
  const float* W1  = (const float*)d_in[2];
  const float* as1 = (const float*)d_in[3];
  const float* ad1 = (const float*)d_in[4];
  const float* b1  = (const float*)d_in[5];
  const float* W2  = (const float*)d_in[6];
  const float* as2 = (const float*)d_in[7];
  const float* ad2 = (const float*)d_in[8];
  const float* b2  = (const float*)d_in[9];
  float* out = (float*)d_out;

  int N = in_sizes[0] / F1;
  int E = in_sizes[1] / 2;
  int ET = E + N;
  int NBUK = (N + BW - 1) / BW;       // 391 for N=50000 (<= MAXBUK)
  int NCH = (ET + CHUNK - 1) / CHUNK; // scatter blocks
  int NT = (N + 63) / 64;             // GEMM tiles (64 rows)
  int NWC = (F1 * F1 + OUTD * F1 + 255) / 256;   // wcvt blocks

  // workspace layout (16B-aligned chunks)
  char* p = (char*)d_ws;
  auto alloc = [&](size_t bytes) {
    char* q = p;
    p += (bytes + 15) & ~(size_t)15;
    return q;
  };
  int* bukcur  = (int*)alloc((size_t)NBUK * 4);
  int* off     = (int*)alloc((size_t)N * 4);
  int* offe    = (int*)alloc((size_t)N * 4);
  int* pairs   = (int*)alloc((size_t)NBUK * BCAP * 4);
  int* csr     = (int*)alloc((size_t)NBUK * BCAP * 4);
  ushort* W1t  = (ushort*)alloc((size_t)F1 * F1 * 2);
  ushort* W2t  = (ushort*)alloc((size_t)OUTD * F1 * 2);
  uint* hA     = (uint*)alloc((size_t)N * 32 * 4);   // heads 0-3
  uint* hB     = (uint*)alloc((size_t)N * 32 * 4);   // heads 4-7
  uint* h2b    = (uint*)alloc((size_t)N * 32 * 4);
  float* out1  = (float*)alloc((size_t)N * F1 * 4);
  float* a_src1 = (float*)alloc((size_t)N * HEADS * 4);
  float* a_dst1 = (float*)alloc((size_t)N * HEADS * 4);
  float* a_src2 = (float*)alloc((size_t)N * 4);
  float* a_dst2 = (float*)alloc((size_t)N * 4);

  // CSR build (no global scan: fixed-capacity buckets)
  hipLaunchKernelGGL(k_z, dim3((NBUK + 255) / 256), dim3(256), 0, stream, bukcur, NBUK);
  hipLaunchKernelGGL(k_scatter, dim3(NCH), dim3(256), 0, stream, ei, E, N, bukcur, pairs);
  hipLaunchKernelGGL(k_csr, dim3(NBUK), dim3(256), 0, stream,
                     pairs, bukcur, off, offe, csr, N);

  // W transpose/convert + layer-1 MFMA GEMM
  hipLaunchKernelGGL(k_wcvt, dim3(NWC), dim3(256), 0, stream, W1, W2, W1t, W2t);
  hipLaunchKernelGGL(k_gemm1, dim3(NT), dim3(256), 0, stream,
                     x, W1t, as1, ad1, hA, hB, a_src1, a_dst1, N);
  hipLaunchKernelGGL(k_agg1h, dim3((N + 3) / 4), dim3(256), 0, stream,
                     off, offe, csr, (const uint2*)hA, a_src1, a_dst1, b1, out1, N, 0, 0);
  hipLaunchKernelGGL(k_agg1h, dim3((N + 3) / 4), dim3(256), 0, stream,
                     off, offe, csr, (const uint2*)hB, a_src1, a_dst1, b1, out1, N, 4, 64);

  // layer 2
  hipLaunchKernelGGL(k_gemm2, dim3(NT), dim3(256), 0, stream,
                     out1, W2t, as2, ad2, h2b, a_src2, a_dst2, N);
  hipLaunchKernelGGL(k_agg2, dim3((N + 3) / 4), dim3(256), 0, stream,
                     off, offe, csr, (const uint2*)h2b, a_src2, a_dst2, b2, out, N);
}

// Round 15
// 164.125 us; speedup vs baseline: 1.2522x; 1.0422x over previous
//
#include <hip/hip_runtime.h>
#include <hip/hip_bf16.h>

#define HEADS 8
#define HID 16
#define F1 128    // HEADS*HID
#define OUTD 64
#define BWL 7          // log2(bucket width)
#define BW 128         // dst-range per bucket
#define MAXBUK 512     // >= ceil(N/BW); N=50000 -> 391
#define BCAP 3584      // fixed bucket capacity (mean 2176 + 31 sigma)
#define CHUNK 2048     // edges per block in scatter (256 thr x 8)

typedef unsigned int uint;
typedef unsigned short ushort;
typedef __attribute__((ext_vector_type(8))) short bfrag;   // 8 bf16 (4 VGPR)
typedef __attribute__((ext_vector_type(4))) float f32x4;

__device__ __forceinline__ ushort f2bf(float f) {
  __hip_bfloat16 b = __float2bfloat16(f);
  return *reinterpret_cast<ushort*>(&b);
}
__device__ __forceinline__ float bf2f_lo(uint w) {
  return __uint_as_float((w & 0xFFFFu) << 16);
}
__device__ __forceinline__ float bf2f_hi(uint w) {
  return __uint_as_float(w & 0xFFFF0000u);
}
// ELU both bf16 halves of a packed uint
__device__ __forceinline__ uint elu2(uint u) {
  float lo = bf2f_lo(u), hi = bf2f_hi(u);
  lo = lo > 0.f ? lo : __expf(lo) - 1.f;
  hi = hi > 0.f ? hi : __expf(hi) - 1.f;
  return (uint)f2bf(lo) | ((uint)f2bf(hi) << 16);
}

// ---------------- setup: W transpose+bf16 convert + zero bucket cursors ----------------
// W1t[c][k] bf16 128x128; W2t[c][k] bf16 64x128.
__global__ void k_wcvt(const float* __restrict__ W1, const float* __restrict__ W2,
                       ushort* __restrict__ W1t, ushort* __restrict__ W2t,
                       int* __restrict__ bukcur, int NBUK) {
  int o = blockIdx.x * 256 + threadIdx.x;
  if (o < F1 * F1) {
    int c = o >> 7, k = o & 127;
    W1t[o] = f2bf(W1[k * F1 + c]);
  } else if (o < F1 * F1 + OUTD * F1) {
    int i = o - F1 * F1;
    int c = i >> 7, k = i & 127;
    W2t[i] = f2bf(W2[k * OUTD + c]);
  } else {
    int i = o - (F1 * F1 + OUTD * F1);
    if (i < NBUK) bukcur[i] = 0;
  }
}

// ---------------- CSR build (fixed-capacity bucket radix) ----------------
// pairs packed: src in bits [0,20), dst&(BW-1) in bits [20,27). N < 2^20.

__global__ __launch_bounds__(256) void k_scatter(const int* __restrict__ ei, int E, int N,
                                                 int* __restrict__ bukcur,
                                                 int* __restrict__ pairs) {
  __shared__ int hist[MAXBUK];
  int t = threadIdx.x;
  hist[t] = 0; hist[t + 256] = 0;
  __syncthreads();
  long long e0 = (long long)blockIdx.x * CHUNK;
  int ET = E + N;
  int myP[8], myB[8];
#pragma unroll
  for (int i = 0; i < 8; ++i) {
    long long e = e0 + i * 256 + t;
    if (e < ET) {
      int s = e < E ? ei[e] : (int)(e - E);
      int d = e < E ? ei[E + e] : (int)(e - E);
      myP[i] = s | ((d & (BW - 1)) << 20);
      myB[i] = d >> BWL;
      atomicAdd(&hist[myB[i]], 1);
    } else {
      myB[i] = -1;
    }
  }
  __syncthreads();
  for (int b = t; b < MAXBUK; b += 256) {
    int c = hist[b];
    hist[b] = c ? (b * BCAP + atomicAdd(&bukcur[b], c)) : 0;
  }
  __syncthreads();
#pragma unroll
  for (int i = 0; i < 8; ++i) {
    if (myB[i] >= 0) {
      int pos = atomicAdd(&hist[myB[i]], 1);
      pairs[pos] = myP[i];
    }
  }
}

__global__ __launch_bounds__(256) void k_csr(const int* __restrict__ pairs,
                                             const int* __restrict__ bukcur,
                                             int* __restrict__ off, int* __restrict__ offe,
                                             int* __restrict__ csr, int N) {
  __shared__ int cnt[BW];
  __shared__ int cur[BW];
  int b = blockIdx.x, t = threadIdx.x;
  int beg = b * BCAP, end = beg + bukcur[b];
  if (t < BW) cnt[t] = 0;
  __syncthreads();
  for (int j = beg + t; j < end; j += 256)
    atomicAdd(&cnt[(pairs[j] >> 20) & (BW - 1)], 1);
  __syncthreads();
  int my = t < BW ? cnt[t] : 0;
  for (int o = 1; o < BW; o <<= 1) {
    int v = (t < BW && t >= o) ? cnt[t - o] : 0;
    __syncthreads();
    if (t < BW) cnt[t] += v;
    __syncthreads();
  }
  if (t < BW) {
    int start = beg + cnt[t] - my;   // exclusive within bucket
    cur[t] = start;
    int d0 = b * BW + t;
    if (d0 < N) { off[d0] = start; offe[d0] = start + my; }
  }
  __syncthreads();
  for (int j = beg + t; j < end; j += 256) {
    int pr = pairs[j];
    int pos = atomicAdd(&cur[(pr >> 20) & (BW - 1)], 1);
    csr[pos] = pr & 0xFFFFF;
  }
}

// ---------------- layer 1 GEMM (MFMA bf16) ----------------
// 64 rows/block, 4 waves x 16-row strips; 8 col-tiles x 4 k-steps.
// C/D layout: col=lane&15, row=(lane>>4)*4+reg. head = col-tile (n0).
__global__ __launch_bounds__(256) void k_gemm1(
    const float* __restrict__ x, const ushort* __restrict__ W1t,
    const float* __restrict__ as, const float* __restrict__ ad,
    uint* __restrict__ hA, uint* __restrict__ hB,
    float* __restrict__ a_src, float* __restrict__ a_dst, int N) {
  __shared__ __align__(16) ushort xl[64 * 136];    // 17.0 KB
  __shared__ __align__(16) ushort wl[128 * 136];   // 34.0 KB
  int tx = threadIdx.x;
  int r0 = blockIdx.x * 64;

  {
    int c = tx >> 1, k0 = (tx & 1) * 64;
    const uint4* g = reinterpret_cast<const uint4*>(W1t + c * F1 + k0);
#pragma unroll
    for (int j = 0; j < 8; ++j)
      *reinterpret_cast<uint4*>(&wl[c * 136 + k0 + j * 8]) = g[j];
  }
  {
    int row = tx & 63, kq = tx >> 6;
    bool act = (r0 + row) < N;
    const float4* xg = reinterpret_cast<const float4*>(x + (size_t)(r0 + row) * F1 + kq * 32);
#pragma unroll
    for (int j = 0; j < 4; ++j) {
      float4 va = act ? xg[2 * j]     : make_float4(0.f, 0.f, 0.f, 0.f);
      float4 vb = act ? xg[2 * j + 1] : make_float4(0.f, 0.f, 0.f, 0.f);
      uint4 pk;
      pk.x = (uint)f2bf(va.x) | ((uint)f2bf(va.y) << 16);
      pk.y = (uint)f2bf(va.z) | ((uint)f2bf(va.w) << 16);
      pk.z = (uint)f2bf(vb.x) | ((uint)f2bf(vb.y) << 16);
      pk.w = (uint)f2bf(vb.z) | ((uint)f2bf(vb.w) << 16);
      *reinterpret_cast<uint4*>(&xl[row * 136 + kq * 32 + j * 8]) = pk;
    }
  }
  __syncthreads();

  int w = tx >> 6, l = tx & 63;
  int lr = l & 15, lo = l >> 4;

  bfrag af[4];
#pragma unroll
  for (int ks = 0; ks < 4; ++ks)
    af[ks] = *reinterpret_cast<const bfrag*>(&xl[(w * 16 + lr) * 136 + ks * 32 + lo * 8]);

  f32x4 acc[8];
#pragma unroll
  for (int n0 = 0; n0 < 8; ++n0) {
    acc[n0] = (f32x4){0.f, 0.f, 0.f, 0.f};
#pragma unroll
    for (int ks = 0; ks < 4; ++ks) {
      bfrag bf = *reinterpret_cast<const bfrag*>(&wl[(n0 * 16 + lr) * 136 + ks * 32 + lo * 8]);
      acc[n0] = __builtin_amdgcn_mfma_f32_16x16x32_bf16(af[ks], bf, acc[n0], 0, 0, 0);
    }
  }

#pragma unroll
  for (int n0 = 0; n0 < 8; ++n0) {
    float asv = as[n0 * 16 + lr];
    float adv = ad[n0 * 16 + lr];
    ushort* tp = reinterpret_cast<ushort*>(n0 < 4 ? hA : hB);
    int cbase = (n0 & 3) * 16 + lr;
#pragma unroll
    for (int r = 0; r < 4; ++r) {
      int row = r0 + w * 16 + lo * 4 + r;
      float hv = acc[n0][r];
      float ps = hv * asv, pd = hv * adv;
      ps += __shfl_xor(ps, 1); ps += __shfl_xor(ps, 2);
      ps += __shfl_xor(ps, 4); ps += __shfl_xor(ps, 8);
      pd += __shfl_xor(pd, 1); pd += __shfl_xor(pd, 2);
      pd += __shfl_xor(pd, 4); pd += __shfl_xor(pd, 8);
      if (row < N) {
        tp[(size_t)row * 64 + cbase] = f2bf(hv);
        if (lr == 0) {
          a_src[row * HEADS + n0] = ps;
          a_dst[row * HEADS + n0] = pd;
        }
      }
    }
  }
}

// ---------------- layer 1 aggregate (channel-split half-table pass) ----------------
// 1 wave/dst; four 16-lane quarters on alternating edges; lane owns 4 channels
// (uint2). Output packed bf16 into out1b (row = 64 uints = 128 ch).
// hbase = 0 or 4 (head offset), obase = 0 or 64 (channel offset).
__global__ void k_agg1h(const int* __restrict__ off, const int* __restrict__ offe,
                        const int* __restrict__ csr,
                        const uint2* __restrict__ htab, const float* __restrict__ a_src,
                        const float* __restrict__ a_dst, const float* __restrict__ b1,
                        uint* __restrict__ out1b, int N, int hbase, int obase) {
  int w = threadIdx.x >> 6, lane = threadIdx.x & 63;
  int q = lane >> 4, c2 = lane & 15;
  int h = hbase + (c2 >> 2);
  int d = blockIdx.x * 4 + w;
  if (d >= N) return;
  int beg = off[d], end = offe[d];
  float adl = a_dst[d * HEADS + h];
  float a0 = 0.f, a1 = 0.f, a2 = 0.f, a3 = 0.f, den = 0.f;
#pragma unroll 2
  for (int j = beg + q; j < end; j += 4) {
    int s = csr[j];
    float v = a_src[s * HEADS + h] + adl;
    v = v >= 0.f ? v : 0.2f * v;
    float p = __expf(v);
    uint2 wd = htab[(size_t)s * 16 + c2];
    a0 = fmaf(p, bf2f_lo(wd.x), a0);
    a1 = fmaf(p, bf2f_hi(wd.x), a1);
    a2 = fmaf(p, bf2f_lo(wd.y), a2);
    a3 = fmaf(p, bf2f_hi(wd.y), a3);
    den += p;
  }
  a0 += __shfl_xor(a0, 16); a0 += __shfl_xor(a0, 32);
  a1 += __shfl_xor(a1, 16); a1 += __shfl_xor(a1, 32);
  a2 += __shfl_xor(a2, 16); a2 += __shfl_xor(a2, 32);
  a3 += __shfl_xor(a3, 16); a3 += __shfl_xor(a3, 32);
  den += __shfl_xor(den, 16); den += __shfl_xor(den, 32);
  if (q == 0) {
    float inv = 1.f / den;   // self-loop guarantees den > 0
    float4 bb = *reinterpret_cast<const float4*>(&b1[obase + 4 * c2]);
    uint2 o;
    o.x = (uint)f2bf(a0 * inv + bb.x) | ((uint)f2bf(a1 * inv + bb.y) << 16);
    o.y = (uint)f2bf(a2 * inv + bb.z) | ((uint)f2bf(a3 * inv + bb.w) << 16);
    *reinterpret_cast<uint2*>(&out1b[(size_t)d * 64 + (obase >> 1) + 2 * c2]) = o;
  }
}

// ---------------- layer 2 GEMM (MFMA bf16, ELU fused into staging) ----------------
// 64 rows/block, 4 waves x 16-row strips; 4 col-tiles x 4 k-steps.
// Input out1b is packed bf16 (64 uints/row).
__global__ __launch_bounds__(256) void k_gemm2(
    const uint* __restrict__ out1b, const ushort* __restrict__ W2t,
    const float* __restrict__ as2, const float* __restrict__ ad2,
    uint* __restrict__ h2b, float* __restrict__ a_src2,
    float* __restrict__ a_dst2, int N) {
  __shared__ __align__(16) ushort xl[64 * 136];   // 17.0 KB
  __shared__ __align__(16) ushort wl[64 * 136];   // 17.0 KB
  int tx = threadIdx.x;
  int r0 = blockIdx.x * 64;

  {
    int c = tx & 63, k0 = (tx >> 6) * 32;
    const uint4* g = reinterpret_cast<const uint4*>(W2t + c * F1 + k0);
#pragma unroll
    for (int j = 0; j < 4; ++j)
      *reinterpret_cast<uint4*>(&wl[c * 136 + k0 + j * 8]) = g[j];
  }
  {
    int row = tx & 63, kq = tx >> 6;
    bool act = (r0 + row) < N;
    const uint4* xg = reinterpret_cast<const uint4*>(out1b + (size_t)(r0 + row) * 64 + kq * 16);
#pragma unroll
    for (int j = 0; j < 4; ++j) {
      uint4 v = act ? xg[j] : make_uint4(0, 0, 0, 0);
      uint4 pk;
      pk.x = elu2(v.x);
      pk.y = elu2(v.y);
      pk.z = elu2(v.z);
      pk.w = elu2(v.w);
      *reinterpret_cast<uint4*>(&xl[row * 136 + kq * 32 + j * 8]) = pk;
    }
  }
  __syncthreads();

  int w = tx >> 6, l = tx & 63;
  int lr = l & 15, lo = l >> 4;

  bfrag af[4];
#pragma unroll
  for (int ks = 0; ks < 4; ++ks)
    af[ks] = *reinterpret_cast<const bfrag*>(&xl[(w * 16 + lr) * 136 + ks * 32 + lo * 8]);

  f32x4 acc[4];
#pragma unroll
  for (int n0 = 0; n0 < 4; ++n0) {
    acc[n0] = (f32x4){0.f, 0.f, 0.f, 0.f};
#pragma unroll
    for (int ks = 0; ks < 4; ++ks) {
      bfrag bf = *reinterpret_cast<const bfrag*>(&wl[(n0 * 16 + lr) * 136 + ks * 32 + lo * 8]);
      acc[n0] = __builtin_amdgcn_mfma_f32_16x16x32_bf16(af[ks], bf, acc[n0], 0, 0, 0);
    }
  }

  float asv[4], adv[4];
#pragma unroll
  for (int n0 = 0; n0 < 4; ++n0) {
    asv[n0] = as2[n0 * 16 + lr];
    adv[n0] = ad2[n0 * 16 + lr];
  }
  ushort* tp = reinterpret_cast<ushort*>(h2b);
#pragma unroll
  for (int r = 0; r < 4; ++r) {
    int row = r0 + w * 16 + lo * 4 + r;
    float ps = 0.f, pd = 0.f;
#pragma unroll
    for (int n0 = 0; n0 < 4; ++n0) {
      float hv = acc[n0][r];
      ps = fmaf(hv, asv[n0], ps);
      pd = fmaf(hv, adv[n0], pd);
    }
    ps += __shfl_xor(ps, 1); ps += __shfl_xor(ps, 2);
    ps += __shfl_xor(ps, 4); ps += __shfl_xor(ps, 8);
    pd += __shfl_xor(pd, 1); pd += __shfl_xor(pd, 2);
    pd += __shfl_xor(pd, 4); pd += __shfl_xor(pd, 8);
    if (row < N) {
#pragma unroll
      for (int n0 = 0; n0 < 4; ++n0)
        tp[(size_t)row * 64 + n0 * 16 + lr] = f2bf(acc[n0][r]);
      if (lr == 0) {
        a_src2[row] = ps;
        a_dst2[row] = pd;
      }
    }
  }
}

// ---------------- layer 2 aggregate ----------------
// 1 wave/dst; eight 8-lane groups on alternating edges (8 rows in flight);
// lane owns 8 channels via uint4 (8x16B = 128B row); combine shfl_xor(8/16/32).
__global__ void k_agg2(const int* __restrict__ off, const int* __restrict__ offe,
                       const int* __restrict__ csr,
                       const uint4* __restrict__ h2b4, const float* __restrict__ a_src2,
                       const float* __restrict__ a_dst2, const float* __restrict__ b2,
                       float* __restrict__ out, int N) {
  int w = threadIdx.x >> 6, lane = threadIdx.x & 63;
  int g = lane >> 3, c4 = lane & 7;   // channels 8*c4..8*c4+7
  int d = blockIdx.x * 4 + w;
  if (d >= N) return;
  int beg = off[d], end = offe[d];
  float adl = a_dst2[d];
  float a[8] = {0.f, 0.f, 0.f, 0.f, 0.f, 0.f, 0.f, 0.f};
  float den = 0.f;
  for (int j = beg + g; j < end; j += 8) {
    int s = csr[j];
    float v = a_src2[s] + adl;
    v = v >= 0.f ? v : 0.2f * v;
    float p = __expf(v);
    uint4 wd = h2b4[(size_t)s * 8 + c4];
    a[0] = fmaf(p, bf2f_lo(wd.x), a[0]);
    a[1] = fmaf(p, bf2f_hi(wd.x), a[1]);
    a[2] = fmaf(p, bf2f_lo(wd.y), a[2]);
    a[3] = fmaf(p, bf2f_hi(wd.y), a[3]);
    a[4] = fmaf(p, bf2f_lo(wd.z), a[4]);
    a[5] = fmaf(p, bf2f_hi(wd.z), a[5]);
    a[6] = fmaf(p, bf2f_lo(wd.w), a[6]);
    a[7] = fmaf(p, bf2f_hi(wd.w), a[7]);
    den += p;
  }
#pragma unroll
  for (int i = 0; i < 8; ++i) {
    a[i] += __shfl_xor(a[i], 8);
    a[i] += __shfl_xor(a[i], 16);
    a[i] += __shfl_xor(a[i], 32);
  }
  den += __shfl_xor(den, 8); den += __shfl_xor(den, 16); den += __shfl_xor(den, 32);
  if (g == 0) {
    float inv = 1.f / den;
    float4 b0 = *reinterpret_cast<const float4*>(&b2[8 * c4]);
    float4 b1v = *reinterpret_cast<const float4*>(&b2[8 * c4 + 4]);
    float4 o0, o1;
    o0.x = a[0] * inv + b0.x;  o0.y = a[1] * inv + b0.y;
    o0.z = a[2] * inv + b0.z;  o0.w = a[3] * inv + b0.w;
    o1.x = a[4] * inv + b1v.x; o1.y = a[5] * inv + b1v.y;
    o1.z = a[6] * inv + b1v.z; o1.w = a[7] * inv + b1v.w;
    *reinterpret_cast<float4*>(&out[(size_t)d * OUTD + 8 * c4]) = o0;
    *reinterpret_cast<float4*>(&out[(size_t)d * OUTD + 8 * c4 + 4]) = o1;
  }
}

extern "C" void kernel_launch(void* const* d_in, const int* in_sizes, int n_in,
                              void* d_out, int out_size, void* d_ws, size_t ws_size,
                              hipStream_t stream) {
  const float* x   = (const float*)d_in[0];
  const int*   ei  = (const int*)d_in[1];
  const float* W1  = (const float*)d_in[2];
  const float* as1 = (const float*)d_in[3];
  const float* ad1 = (const float*)d_in[4];
  const float* b1  = (const float*)d_in[5];
  const float* W2  = (const float*)d_in[6];
  const float* as2 = (const float*)d_in[7];
  const float* ad2 = (const float*)d_in[8];
  const float* b2  = (const float*)d_in[9];
  float* out = (float*)d_out;

  int N = in_sizes[0] / F1;
  int E = in_sizes[1] / 2;
  int ET = E + N;
  int NBUK = (N + BW - 1) / BW;       // 391 for N=50000 (<= MAXBUK)
  int NCH = (ET + CHUNK - 1) / CHUNK; // scatter blocks
  int NT = (N + 63) / 64;             // GEMM tiles (64 rows)
  int NWC = (F1 * F1 + OUTD * F1 + MAXBUK + 255) / 256;   // wcvt+zero blocks

  // workspace layout (16B-aligned chunks)
  char* p = (char*)d_ws;
  auto alloc = [&](size_t bytes) {
    char* q = p;
    p += (bytes + 15) & ~(size_t)15;
    return q;
  };
  int* bukcur  = (int*)alloc((size_t)NBUK * 4);
  int* off     = (int*)alloc((size_t)N * 4);
  int* offe    = (int*)alloc((size_t)N * 4);
  int* pairs   = (int*)alloc((size_t)NBUK * BCAP * 4);
  int* csr     = (int*)alloc((size_t)NBUK * BCAP * 4);
  ushort* W1t  = (ushort*)alloc((size_t)F1 * F1 * 2);
  ushort* W2t  = (ushort*)alloc((size_t)OUTD * F1 * 2);
  uint* hA     = (uint*)alloc((size_t)N * 32 * 4);   // heads 0-3
  uint* hB     = (uint*)alloc((size_t)N * 32 * 4);   // heads 4-7
  uint* h2b    = (uint*)alloc((size_t)N * 32 * 4);
  uint* out1b  = (uint*)alloc((size_t)N * 64 * 4);   // bf16-packed out1
  float* a_src1 = (float*)alloc((size_t)N * HEADS * 4);
  float* a_dst1 = (float*)alloc((size_t)N * HEADS * 4);
  float* a_src2 = (float*)alloc((size_t)N * 4);
  float* a_dst2 = (float*)alloc((size_t)N * 4);

  // setup (W convert + bucket-cursor zero), then CSR build
  hipLaunchKernelGGL(k_wcvt, dim3(NWC), dim3(256), 0, stream, W1, W2, W1t, W2t, bukcur, NBUK);
  hipLaunchKernelGGL(k_scatter, dim3(NCH), dim3(256), 0, stream, ei, E, N, bukcur, pairs);
  hipLaunchKernelGGL(k_csr, dim3(NBUK), dim3(256), 0, stream,
                     pairs, bukcur, off, offe, csr, N);

  // layer 1
  hipLaunchKernelGGL(k_gemm1, dim3(NT), dim3(256), 0, stream,
                     x, W1t, as1, ad1, hA, hB, a_src1, a_dst1, N);
  hipLaunchKernelGGL(k_agg1h, dim3((N + 3) / 4), dim3(256), 0, stream,
                     off, offe, csr, (const uint2*)hA, a_src1, a_dst1, b1, out1b, N, 0, 0);
  hipLaunchKernelGGL(k_agg1h, dim3((N + 3) / 4), dim3(256), 0, stream,
                     off, offe, csr, (const uint2*)hB, a_src1, a_dst1, b1, out1b, N, 4, 64);

  // layer 2
  hipLaunchKernelGGL(k_gemm2, dim3(NT), dim3(256), 0, stream,
                     out1b, W2t, as2, ad2, h2b, a_src2, a_dst2, N);
  hipLaunchKernelGGL(k_agg2, dim3((N + 3) / 4), dim3(256), 0, stream,
                     off, offe, csr, (const uint4*)h2b, a_src2, a_dst2, b2, out, N);
}

// Round 16
// 154.538 us; speedup vs baseline: 1.3298x; 1.0620x over previous
//
#include <hip/hip_runtime.h>
#include <hip/hip_bf16.h>

#define HEADS 8
#define HID 16
#define F1 128    // HEADS*HID
#define OUTD 64
#define BWL 7          // log2(bucket width)
#define BW 128         // dst-range per bucket
#define MAXBUK 512     // >= ceil(N/BW); N=50000 -> 391
#define BCAP 3584      // fixed bucket capacity (mean 2176 + 31 sigma)
#define CHUNK 2048     // edges per block in scatter (256 thr x 8)

typedef unsigned int uint;
typedef unsigned short ushort;
typedef __attribute__((ext_vector_type(8))) short bfrag;   // 8 bf16 (4 VGPR)
typedef __attribute__((ext_vector_type(4))) float f32x4;

__device__ __forceinline__ ushort f2bf(float f) {
  __hip_bfloat16 b = __float2bfloat16(f);
  return *reinterpret_cast<ushort*>(&b);
}
__device__ __forceinline__ float bf2f_lo(uint w) {
  return __uint_as_float((w & 0xFFFFu) << 16);
}
__device__ __forceinline__ float bf2f_hi(uint w) {
  return __uint_as_float(w & 0xFFFF0000u);
}
// ELU both bf16 halves of a packed uint
__device__ __forceinline__ uint elu2(uint u) {
  float lo = bf2f_lo(u), hi = bf2f_hi(u);
  lo = lo > 0.f ? lo : __expf(lo) - 1.f;
  hi = hi > 0.f ? hi : __expf(hi) - 1.f;
  return (uint)f2bf(lo) | ((uint)f2bf(hi) << 16);
}

// ---------------- D1: W transpose+bf16 convert + zero bucket cursors ----------------
__global__ void k_wcvt(const float* __restrict__ W1, const float* __restrict__ W2,
                       ushort* __restrict__ W1t, ushort* __restrict__ W2t,
                       int* __restrict__ bukcur, int NBUK) {
  int o = blockIdx.x * 256 + threadIdx.x;
  if (o < F1 * F1) {
    int c = o >> 7, k = o & 127;
    W1t[o] = f2bf(W1[k * F1 + c]);
  } else if (o < F1 * F1 + OUTD * F1) {
    int i = o - F1 * F1;
    int c = i >> 7, k = i & 127;
    W2t[i] = f2bf(W2[k * OUTD + c]);
  } else {
    int i = o - (F1 * F1 + OUTD * F1);
    if (i < NBUK) bukcur[i] = 0;
  }
}

// ---------------- D2: fused scatter (blocks [0,NCH)) + layer-1 MFMA GEMM ----------------
// Scatter: pairs packed src|dstlow<<20 into fixed-capacity buckets.
// gemm1: 64 rows/block, 4 waves x 16-row strips; 8 col-tiles x 4 k-steps
// mfma_f32_16x16x32_bf16; C/D: col=lane&15, row=(lane>>4)*4+reg; head = col-tile.
// LDS union: scatter's 2KB hist aliases gemm1's 51KB tile buffer.
__global__ __launch_bounds__(256) void k_sg(
    const int* __restrict__ ei, int E, int N, int* __restrict__ bukcur,
    int* __restrict__ pairs,
    const float* __restrict__ x, const ushort* __restrict__ W1t,
    const float* __restrict__ as, const float* __restrict__ ad,
    uint* __restrict__ hA, uint* __restrict__ hB,
    float* __restrict__ a_src, float* __restrict__ a_dst, int NCH_) {
  __shared__ __align__(16) char smem[52224];   // 64*136*2 + 128*136*2 bytes
  int tx = threadIdx.x;

  if ((int)blockIdx.x < NCH_) {
    // ---------------- scatter ----------------
    int* hist = (int*)smem;
    hist[tx] = 0; hist[tx + 256] = 0;
    __syncthreads();
    long long e0 = (long long)blockIdx.x * CHUNK;
    int ET = E + N;
    int myP[8], myB[8];
#pragma unroll
    for (int i = 0; i < 8; ++i) {
      long long e = e0 + i * 256 + tx;
      if (e < ET) {
        int s = e < E ? ei[e] : (int)(e - E);
        int d = e < E ? ei[E + e] : (int)(e - E);
        myP[i] = s | ((d & (BW - 1)) << 20);
        myB[i] = d >> BWL;
        atomicAdd(&hist[myB[i]], 1);
      } else {
        myB[i] = -1;
      }
    }
    __syncthreads();
    for (int b = tx; b < MAXBUK; b += 256) {
      int c = hist[b];
      hist[b] = c ? (b * BCAP + atomicAdd(&bukcur[b], c)) : 0;
    }
    __syncthreads();
#pragma unroll
    for (int i = 0; i < 8; ++i) {
      if (myB[i] >= 0) {
        int pos = atomicAdd(&hist[myB[i]], 1);
        pairs[pos] = myP[i];
      }
    }
    return;
  }

  // ---------------- gemm1 ----------------
  ushort* xl = (ushort*)smem;          // [64*136]
  ushort* wl = xl + 64 * 136;          // [128*136]
  int r0 = ((int)blockIdx.x - NCH_) * 64;

  {
    int c = tx >> 1, k0 = (tx & 1) * 64;
    const uint4* g = reinterpret_cast<const uint4*>(W1t + c * F1 + k0);
#pragma unroll
    for (int j = 0; j < 8; ++j)
      *reinterpret_cast<uint4*>(&wl[c * 136 + k0 + j * 8]) = g[j];
  }
  {
    int row = tx & 63, kq = tx >> 6;
    bool act = (r0 + row) < N;
    const float4* xg = reinterpret_cast<const float4*>(x + (size_t)(r0 + row) * F1 + kq * 32);
#pragma unroll
    for (int j = 0; j < 4; ++j) {
      float4 va = act ? xg[2 * j]     : make_float4(0.f, 0.f, 0.f, 0.f);
      float4 vb = act ? xg[2 * j + 1] : make_float4(0.f, 0.f, 0.f, 0.f);
      uint4 pk;
      pk.x = (uint)f2bf(va.x) | ((uint)f2bf(va.y) << 16);
      pk.y = (uint)f2bf(va.z) | ((uint)f2bf(va.w) << 16);
      pk.z = (uint)f2bf(vb.x) | ((uint)f2bf(vb.y) << 16);
      pk.w = (uint)f2bf(vb.z) | ((uint)f2bf(vb.w) << 16);
      *reinterpret_cast<uint4*>(&xl[row * 136 + kq * 32 + j * 8]) = pk;
    }
  }
  __syncthreads();

  int w = tx >> 6, l = tx & 63;
  int lr = l & 15, lo = l >> 4;

  bfrag af[4];
#pragma unroll
  for (int ks = 0; ks < 4; ++ks)
    af[ks] = *reinterpret_cast<const bfrag*>(&xl[(w * 16 + lr) * 136 + ks * 32 + lo * 8]);

  f32x4 acc[8];
#pragma unroll
  for (int n0 = 0; n0 < 8; ++n0) {
    acc[n0] = (f32x4){0.f, 0.f, 0.f, 0.f};
#pragma unroll
    for (int ks = 0; ks < 4; ++ks) {
      bfrag bf = *reinterpret_cast<const bfrag*>(&wl[(n0 * 16 + lr) * 136 + ks * 32 + lo * 8]);
      acc[n0] = __builtin_amdgcn_mfma_f32_16x16x32_bf16(af[ks], bf, acc[n0], 0, 0, 0);
    }
  }

#pragma unroll
  for (int n0 = 0; n0 < 8; ++n0) {
    float asv = as[n0 * 16 + lr];
    float adv = ad[n0 * 16 + lr];
    ushort* tp = reinterpret_cast<ushort*>(n0 < 4 ? hA : hB);
    int cbase = (n0 & 3) * 16 + lr;
#pragma unroll
    for (int r = 0; r < 4; ++r) {
      int row = r0 + w * 16 + lo * 4 + r;
      float hv = acc[n0][r];
      float ps = hv * asv, pd = hv * adv;
      ps += __shfl_xor(ps, 1); ps += __shfl_xor(ps, 2);
      ps += __shfl_xor(ps, 4); ps += __shfl_xor(ps, 8);
      pd += __shfl_xor(pd, 1); pd += __shfl_xor(pd, 2);
      pd += __shfl_xor(pd, 4); pd += __shfl_xor(pd, 8);
      if (row < N) {
        tp[(size_t)row * 64 + cbase] = f2bf(hv);
        if (lr == 0) {
          a_src[row * HEADS + n0] = ps;
          a_dst[row * HEADS + n0] = pd;
        }
      }
    }
  }
}

// ---------------- D3: per-bucket fine CSR (512 threads) ----------------
__global__ __launch_bounds__(512) void k_csr(const int* __restrict__ pairs,
                                             const int* __restrict__ bukcur,
                                             int* __restrict__ off, int* __restrict__ offe,
                                             int* __restrict__ csr, int N) {
  __shared__ int cnt[BW];
  __shared__ int cur[BW];
  int b = blockIdx.x, t = threadIdx.x;
  int beg = b * BCAP, end = beg + bukcur[b];
  if (t < BW) cnt[t] = 0;
  __syncthreads();
  for (int j = beg + t; j < end; j += 512)
    atomicAdd(&cnt[(pairs[j] >> 20) & (BW - 1)], 1);
  __syncthreads();
  int my = t < BW ? cnt[t] : 0;
  for (int o = 1; o < BW; o <<= 1) {
    int v = (t < BW && t >= o) ? cnt[t - o] : 0;
    __syncthreads();
    if (t < BW) cnt[t] += v;
    __syncthreads();
  }
  if (t < BW) {
    int start = beg + cnt[t] - my;   // exclusive within bucket
    cur[t] = start;
    int d0 = b * BW + t;
    if (d0 < N) { off[d0] = start; offe[d0] = start + my; }
  }
  __syncthreads();
  for (int j = beg + t; j < end; j += 512) {
    int pr = pairs[j];
    int pos = atomicAdd(&cur[(pr >> 20) & (BW - 1)], 1);
    csr[pos] = pr & 0xFFFFF;
  }
}

// ---------------- layer 1 aggregate (channel-split half-table pass) ----------------
// 1 wave/dst; four 16-lane quarters on alternating edges; lane owns 4 channels
// (uint2). Output packed bf16 into out1b. hbase = 0/4, obase = 0/64.
__global__ void k_agg1h(const int* __restrict__ off, const int* __restrict__ offe,
                        const int* __restrict__ csr,
                        const uint2* __restrict__ htab, const float* __restrict__ a_src,
                        const float* __restrict__ a_dst, const float* __restrict__ b1,
                        uint* __restrict__ out1b, int N, int hbase, int obase) {
  int w = threadIdx.x >> 6, lane = threadIdx.x & 63;
  int q = lane >> 4, c2 = lane & 15;
  int h = hbase + (c2 >> 2);
  int d = blockIdx.x * 4 + w;
  if (d >= N) return;
  int beg = off[d], end = offe[d];
  float adl = a_dst[d * HEADS + h];
  float a0 = 0.f, a1 = 0.f, a2 = 0.f, a3 = 0.f, den = 0.f;
#pragma unroll 2
  for (int j = beg + q; j < end; j += 4) {
    int s = csr[j];
    float v = a_src[s * HEADS + h] + adl;
    v = v >= 0.f ? v : 0.2f * v;
    float p = __expf(v);
    uint2 wd = htab[(size_t)s * 16 + c2];
    a0 = fmaf(p, bf2f_lo(wd.x), a0);
    a1 = fmaf(p, bf2f_hi(wd.x), a1);
    a2 = fmaf(p, bf2f_lo(wd.y), a2);
    a3 = fmaf(p, bf2f_hi(wd.y), a3);
    den += p;
  }
  a0 += __shfl_xor(a0, 16); a0 += __shfl_xor(a0, 32);
  a1 += __shfl_xor(a1, 16); a1 += __shfl_xor(a1, 32);
  a2 += __shfl_xor(a2, 16); a2 += __shfl_xor(a2, 32);
  a3 += __shfl_xor(a3, 16); a3 += __shfl_xor(a3, 32);
  den += __shfl_xor(den, 16); den += __shfl_xor(den, 32);
  if (q == 0) {
    float inv = 1.f / den;   // self-loop guarantees den > 0
    float4 bb = *reinterpret_cast<const float4*>(&b1[obase + 4 * c2]);
    uint2 o;
    o.x = (uint)f2bf(a0 * inv + bb.x) | ((uint)f2bf(a1 * inv + bb.y) << 16);
    o.y = (uint)f2bf(a2 * inv + bb.z) | ((uint)f2bf(a3 * inv + bb.w) << 16);
    *reinterpret_cast<uint2*>(&out1b[(size_t)d * 64 + (obase >> 1) + 2 * c2]) = o;
  }
}

// ---------------- layer 2 GEMM (MFMA bf16, ELU fused into staging) ----------------
__global__ __launch_bounds__(256) void k_gemm2(
    const uint* __restrict__ out1b, const ushort* __restrict__ W2t,
    const float* __restrict__ as2, const float* __restrict__ ad2,
    uint* __restrict__ h2b, float* __restrict__ a_src2,
    float* __restrict__ a_dst2, int N) {
  __shared__ __align__(16) ushort xl[64 * 136];   // 17.0 KB
  __shared__ __align__(16) ushort wl[64 * 136];   // 17.0 KB
  int tx = threadIdx.x;
  int r0 = blockIdx.x * 64;

  {
    int c = tx & 63, k0 = (tx >> 6) * 32;
    const uint4* g = reinterpret_cast<const uint4*>(W2t + c * F1 + k0);
#pragma unroll
    for (int j = 0; j < 4; ++j)
      *reinterpret_cast<uint4*>(&wl[c * 136 + k0 + j * 8]) = g[j];
  }
  {
    int row = tx & 63, kq = tx >> 6;
    bool act = (r0 + row) < N;
    const uint4* xg = reinterpret_cast<const uint4*>(out1b + (size_t)(r0 + row) * 64 + kq * 16);
#pragma unroll
    for (int j = 0; j < 4; ++j) {
      uint4 v = act ? xg[j] : make_uint4(0, 0, 0, 0);
      uint4 pk;
      pk.x = elu2(v.x);
      pk.y = elu2(v.y);
      pk.z = elu2(v.z);
      pk.w = elu2(v.w);
      *reinterpret_cast<uint4*>(&xl[row * 136 + kq * 32 + j * 8]) = pk;
    }
  }
  __syncthreads();

  int w = tx >> 6, l = tx & 63;
  int lr = l & 15, lo = l >> 4;

  bfrag af[4];
#pragma unroll
  for (int ks = 0; ks < 4; ++ks)
    af[ks] = *reinterpret_cast<const bfrag*>(&xl[(w * 16 + lr) * 136 + ks * 32 + lo * 8]);

  f32x4 acc[4];
#pragma unroll
  for (int n0 = 0; n0 < 4; ++n0) {
    acc[n0] = (f32x4){0.f, 0.f, 0.f, 0.f};
#pragma unroll
    for (int ks = 0; ks < 4; ++ks) {
      bfrag bf = *reinterpret_cast<const bfrag*>(&wl[(n0 * 16 + lr) * 136 + ks * 32 + lo * 8]);
      acc[n0] = __builtin_amdgcn_mfma_f32_16x16x32_bf16(af[ks], bf, acc[n0], 0, 0, 0);
    }
  }

  float asv[4], adv[4];
#pragma unroll
  for (int n0 = 0; n0 < 4; ++n0) {
    asv[n0] = as2[n0 * 16 + lr];
    adv[n0] = ad2[n0 * 16 + lr];
  }
  ushort* tp = reinterpret_cast<ushort*>(h2b);
#pragma unroll
  for (int r = 0; r < 4; ++r) {
    int row = r0 + w * 16 + lo * 4 + r;
    float ps = 0.f, pd = 0.f;
#pragma unroll
    for (int n0 = 0; n0 < 4; ++n0) {
      float hv = acc[n0][r];
      ps = fmaf(hv, asv[n0], ps);
      pd = fmaf(hv, adv[n0], pd);
    }
    ps += __shfl_xor(ps, 1); ps += __shfl_xor(ps, 2);
    ps += __shfl_xor(ps, 4); ps += __shfl_xor(ps, 8);
    pd += __shfl_xor(pd, 1); pd += __shfl_xor(pd, 2);
    pd += __shfl_xor(pd, 4); pd += __shfl_xor(pd, 8);
    if (row < N) {
#pragma unroll
      for (int n0 = 0; n0 < 4; ++n0)
        tp[(size_t)row * 64 + n0 * 16 + lr] = f2bf(acc[n0][r]);
      if (lr == 0) {
        a_src2[row] = ps;
        a_dst2[row] = pd;
      }
    }
  }
}

// ---------------- layer 2 aggregate ----------------
// 1 wave/dst; eight 8-lane groups on alternating edges; lane owns 8 channels
// via uint4; combine shfl_xor(8/16/32).
__global__ void k_agg2(const int* __restrict__ off, const int* __restrict__ offe,
                       const int* __restrict__ csr,
                       const uint4* __restrict__ h2b4, const float* __restrict__ a_src2,
                       const float* __restrict__ a_dst2, const float* __restrict__ b2,
                       float* __restrict__ out, int N) {
  int w = threadIdx.x >> 6, lane = threadIdx.x & 63;
  int g = lane >> 3, c4 = lane & 7;   // channels 8*c4..8*c4+7
  int d = blockIdx.x * 4 + w;
  if (d >= N) return;
  int beg = off[d], end = offe[d];
  float adl = a_dst2[d];
  float a[8] = {0.f, 0.f, 0.f, 0.f, 0.f, 0.f, 0.f, 0.f};
  float den = 0.f;
  for (int j = beg + g; j < end; j += 8) {
    int s = csr[j];
    float v = a_src2[s] + adl;
    v = v >= 0.f ? v : 0.2f * v;
    float p = __expf(v);
    uint4 wd = h2b4[(size_t)s * 8 + c4];
    a[0] = fmaf(p, bf2f_lo(wd.x), a[0]);
    a[1] = fmaf(p, bf2f_hi(wd.x), a[1]);
    a[2] = fmaf(p, bf2f_lo(wd.y), a[2]);
    a[3] = fmaf(p, bf2f_hi(wd.y), a[3]);
    a[4] = fmaf(p, bf2f_lo(wd.z), a[4]);
    a[5] = fmaf(p, bf2f_hi(wd.z), a[5]);
    a[6] = fmaf(p, bf2f_lo(wd.w), a[6]);
    a[7] = fmaf(p, bf2f_hi(wd.w), a[7]);
    den += p;
  }
#pragma unroll
  for (int i = 0; i < 8; ++i) {
    a[i] += __shfl_xor(a[i], 8);
    a[i] += __shfl_xor(a[i], 16);
    a[i] += __shfl_xor(a[i], 32);
  }
  den += __shfl_xor(den, 8); den += __shfl_xor(den, 16); den += __shfl_xor(den, 32);
  if (g == 0) {
    float inv = 1.f / den;
    float4 b0 = *reinterpret_cast<const float4*>(&b2[8 * c4]);
    float4 b1v = *reinterpret_cast<const float4*>(&b2[8 * c4 + 4]);
    float4 o0, o1;
    o0.x = a[0] * inv + b0.x;  o0.y = a[1] * inv + b0.y;
    o0.z = a[2] * inv + b0.z;  o0.w = a[3] * inv + b0.w;
    o1.x = a[4] * inv + b1v.x; o1.y = a[5] * inv + b1v.y;
    o1.z = a[6] * inv + b1v.z; o1.w = a[7] * inv + b1v.w;
    *reinterpret_cast<float4*>(&out[(size_t)d * OUTD + 8 * c4]) = o0;
    *reinterpret_cast<float4*>(&out[(size_t)d * OUTD + 8 * c4 + 4]) = o1;
  }
}

extern "C" void kernel_launch(void* const* d_in, const int* in_sizes, int n_in,
                              void* d_out, int out_size, void* d_ws, size_t ws_size,
                              hipStream_t stream) {
  const float* x   = (const float*)d_in[0];
  const int*   ei  = (const int*)d_in[1];
  const float* W1  = (const float*)d_in[2];
  const float* as1 = (const float*)d_in[3];
  const float* ad1 = (const float*)d_in[4];
  const float* b1  = (const float*)d_in[5];
  const float* W2  = (const float*)d_in[6];
  const float* as2 = (const float*)d_in[7];
  const float* ad2 = (const float*)d_in[8];
  const float* b2  = (const float*)d_in[9];
  float* out = (float*)d_out;

  int N = in_sizes[0] / F1;
  int E = in_sizes[1] / 2;
  int ET = E + N;
  int NBUK = (N + BW - 1) / BW;       // 391 for N=50000 (<= MAXBUK)
  int NCH = (ET + CHUNK - 1) / CHUNK; // scatter blocks
  int NT = (N + 63) / 64;             // GEMM tiles (64 rows)
  int NWC = (F1 * F1 + OUTD * F1 + MAXBUK + 255) / 256;   // wcvt+zero blocks

  // workspace layout (16B-aligned chunks)
  char* p = (char*)d_ws;
  auto alloc = [&](size_t bytes) {
    char* q = p;
    p += (bytes + 15) & ~(size_t)15;
    return q;
  };
  int* bukcur  = (int*)alloc((size_t)NBUK * 4);
  int* off     = (int*)alloc((size_t)N * 4);
  int* offe    = (int*)alloc((size_t)N * 4);
  int* pairs   = (int*)alloc((size_t)NBUK * BCAP * 4);
  int* csr     = (int*)alloc((size_t)NBUK * BCAP * 4);
  ushort* W1t  = (ushort*)alloc((size_t)F1 * F1 * 2);
  ushort* W2t  = (ushort*)alloc((size_t)OUTD * F1 * 2);
  uint* hA     = (uint*)alloc((size_t)N * 32 * 4);   // heads 0-3
  uint* hB     = (uint*)alloc((size_t)N * 32 * 4);   // heads 4-7
  uint* h2b    = (uint*)alloc((size_t)N * 32 * 4);
  uint* out1b  = (uint*)alloc((size_t)N * 64 * 4);   // bf16-packed out1
  float* a_src1 = (float*)alloc((size_t)N * HEADS * 4);
  float* a_dst1 = (float*)alloc((size_t)N * HEADS * 4);
  float* a_src2 = (float*)alloc((size_t)N * 4);
  float* a_dst2 = (float*)alloc((size_t)N * 4);

  // D1: setup (W convert + bucket-cursor zero)
  hipLaunchKernelGGL(k_wcvt, dim3(NWC), dim3(256), 0, stream, W1, W2, W1t, W2t, bukcur, NBUK);
  // D2: scatter || gemm1 (block-range fused; both depend only on D1)
  hipLaunchKernelGGL(k_sg, dim3(NCH + NT), dim3(256), 0, stream,
                     ei, E, N, bukcur, pairs,
                     x, W1t, as1, ad1, hA, hB, a_src1, a_dst1, NCH);
  // D3: fine CSR
  hipLaunchKernelGGL(k_csr, dim3(NBUK), dim3(512), 0, stream,
                     pairs, bukcur, off, offe, csr, N);

  // D4/D5: layer-1 aggregate (two half-table passes, serial for L2 locality)
  hipLaunchKernelGGL(k_agg1h, dim3((N + 3) / 4), dim3(256), 0, stream,
                     off, offe, csr, (const uint2*)hA, a_src1, a_dst1, b1, out1b, N, 0, 0);
  hipLaunchKernelGGL(k_agg1h, dim3((N + 3) / 4), dim3(256), 0, stream,
                     off, offe, csr, (const uint2*)hB, a_src1, a_dst1, b1, out1b, N, 4, 64);

  // D6/D7: layer 2
  hipLaunchKernelGGL(k_gemm2, dim3(NT), dim3(256), 0, stream,
                     out1b, W2t, as2, ad2, h2b, a_src2, a_dst2, N);
  hipLaunchKernelGGL(k_agg2, dim3((N + 3) / 4), dim3(256), 0, stream,
                     off, offe, csr, (const uint4*)h2b, a_src2, a_dst2, b2, out, N);
}

// Round 17
// 147.934 us; speedup vs baseline: 1.3892x; 1.0446x over previous
//
#include <hip/hip_runtime.h>
#include <hip/hip_bf16.h>

#define HEADS 8
#define HID 16
#define F1 128    // HEADS*HID
#define OUTD 64
#define BWL 7          // log2(bucket width)
#define BW 128         // dst-range per bucket
#define MAXBUK 512     // >= ceil(N/BW); N=50000 -> 391
#define BCAP 3584      // fixed bucket capacity (mean 2176 + 31 sigma)
#define CHUNK 2048     // edges per block in scatter (256 thr x 8)

typedef unsigned int uint;
typedef unsigned short ushort;
typedef __attribute__((ext_vector_type(8))) short bfrag;   // 8 bf16 (4 VGPR)
typedef __attribute__((ext_vector_type(4))) float f32x4;

__device__ __forceinline__ ushort f2bf(float f) {
  __hip_bfloat16 b = __float2bfloat16(f);
  return *reinterpret_cast<ushort*>(&b);
}
__device__ __forceinline__ float bf2f_lo(uint w) {
  return __uint_as_float((w & 0xFFFFu) << 16);
}
__device__ __forceinline__ float bf2f_hi(uint w) {
  return __uint_as_float(w & 0xFFFF0000u);
}
// ELU both bf16 halves of a packed uint
__device__ __forceinline__ uint elu2(uint u) {
  float lo = bf2f_lo(u), hi = bf2f_hi(u);
  lo = lo > 0.f ? lo : __expf(lo) - 1.f;
  hi = hi > 0.f ? hi : __expf(hi) - 1.f;
  return (uint)f2bf(lo) | ((uint)f2bf(hi) << 16);
}

// ---------------- D1: setup ----------------
// W1t[c][k] bf16 128x128; W2t[c][k] bf16 64x128.
// Wdt[j][k] 16x128: cols j<8 = as1-folded W1, j>=8 = ad1-folded (head j&7).
// Wd2t[j][k] 16x128: j=0 as2-folded W2, j=1 ad2-folded, j>=2 zero.
__global__ void k_wcvt(const float* __restrict__ W1, const float* __restrict__ W2,
                       const float* __restrict__ as1, const float* __restrict__ ad1,
                       const float* __restrict__ as2, const float* __restrict__ ad2,
                       ushort* __restrict__ W1t, ushort* __restrict__ W2t,
                       ushort* __restrict__ Wdt, ushort* __restrict__ Wd2t,
                       int* __restrict__ bukcur, int NBUK) {
  int o = blockIdx.x * 256 + threadIdx.x;
  if (o < F1 * F1) {
    int c = o >> 7, k = o & 127;
    W1t[o] = f2bf(W1[k * F1 + c]);
  } else if (o < F1 * F1 + OUTD * F1) {
    int i = o - F1 * F1;
    int c = i >> 7, k = i & 127;
    W2t[i] = f2bf(W2[k * OUTD + c]);
  } else if (o < F1 * F1 + OUTD * F1 + 2048) {
    int i = o - (F1 * F1 + OUTD * F1);
    int j = i >> 7, k = i & 127;
    const float* av = j < 8 ? as1 : ad1;
    int h = j & 7;
    float s = 0.f;
#pragma unroll
    for (int t = 0; t < HID; ++t)
      s = fmaf(W1[k * F1 + h * HID + t], av[h * HID + t], s);
    Wdt[i] = f2bf(s);
  } else if (o < F1 * F1 + OUTD * F1 + 4096) {
    int i = o - (F1 * F1 + OUTD * F1 + 2048);
    int j = i >> 7, k = i & 127;
    float s = 0.f;
    if (j < 2) {
      const float* av = j == 0 ? as2 : ad2;
      for (int c = 0; c < OUTD; ++c) s = fmaf(W2[k * OUTD + c], av[c], s);
    }
    Wd2t[i] = f2bf(s);
  } else {
    int i = o - (F1 * F1 + OUTD * F1 + 4096);
    if (i < NBUK) bukcur[i] = 0;
  }
}

// ---------------- D2: fused scatter (blocks [0,NCH)) + layer-1 MFMA GEMM ----------------
__global__ __launch_bounds__(256) void k_sg(
    const int* __restrict__ ei, int E, int N, int* __restrict__ bukcur,
    int* __restrict__ pairs,
    const float* __restrict__ x, const ushort* __restrict__ W1t,
    const ushort* __restrict__ Wdt,
    uint* __restrict__ hA, uint* __restrict__ hB,
    float* __restrict__ a_src, float* __restrict__ a_dst, int NCH_) {
  __shared__ __align__(16) char smem[52224];   // 64*136*2 + 128*136*2 bytes
  int tx = threadIdx.x;

  if ((int)blockIdx.x < NCH_) {
    // ---------------- scatter ----------------
    int* hist = (int*)smem;
    hist[tx] = 0; hist[tx + 256] = 0;
    __syncthreads();
    long long e0 = (long long)blockIdx.x * CHUNK;
    int ET = E + N;
    int myP[8], myB[8];
#pragma unroll
    for (int i = 0; i < 8; ++i) {
      long long e = e0 + i * 256 + tx;
      if (e < ET) {
        int s = e < E ? ei[e] : (int)(e - E);
        int d = e < E ? ei[E + e] : (int)(e - E);
        myP[i] = s | ((d & (BW - 1)) << 20);
        myB[i] = d >> BWL;
        atomicAdd(&hist[myB[i]], 1);
      } else {
        myB[i] = -1;
      }
    }
    __syncthreads();
    for (int b = tx; b < MAXBUK; b += 256) {
      int c = hist[b];
      hist[b] = c ? (b * BCAP + atomicAdd(&bukcur[b], c)) : 0;
    }
    __syncthreads();
#pragma unroll
    for (int i = 0; i < 8; ++i) {
      if (myB[i] >= 0) {
        int pos = atomicAdd(&hist[myB[i]], 1);
        pairs[pos] = myP[i];
      }
    }
    return;
  }

  // ---------------- gemm1 ----------------
  ushort* xl = (ushort*)smem;          // [64*136]
  ushort* wl = xl + 64 * 136;          // [128*136]
  int r0 = ((int)blockIdx.x - NCH_) * 64;

  {
    int c = tx >> 1, k0 = (tx & 1) * 64;
    const uint4* g = reinterpret_cast<const uint4*>(W1t + c * F1 + k0);
#pragma unroll
    for (int j = 0; j < 8; ++j)
      *reinterpret_cast<uint4*>(&wl[c * 136 + k0 + j * 8]) = g[j];
  }
  {
    int row = tx & 63, kq = tx >> 6;
    bool act = (r0 + row) < N;
    const float4* xg = reinterpret_cast<const float4*>(x + (size_t)(r0 + row) * F1 + kq * 32);
#pragma unroll
    for (int j = 0; j < 4; ++j) {
      float4 va = act ? xg[2 * j]     : make_float4(0.f, 0.f, 0.f, 0.f);
      float4 vb = act ? xg[2 * j + 1] : make_float4(0.f, 0.f, 0.f, 0.f);
      uint4 pk;
      pk.x = (uint)f2bf(va.x) | ((uint)f2bf(va.y) << 16);
      pk.y = (uint)f2bf(va.z) | ((uint)f2bf(va.w) << 16);
      pk.z = (uint)f2bf(vb.x) | ((uint)f2bf(vb.y) << 16);
      pk.w = (uint)f2bf(vb.z) | ((uint)f2bf(vb.w) << 16);
      *reinterpret_cast<uint4*>(&xl[row * 136 + kq * 32 + j * 8]) = pk;
    }
  }
  __syncthreads();

  int w = tx >> 6, l = tx & 63;
  int lr = l & 15, lo = l >> 4;

  bfrag af[4];
#pragma unroll
  for (int ks = 0; ks < 4; ++ks)
    af[ks] = *reinterpret_cast<const bfrag*>(&xl[(w * 16 + lr) * 136 + ks * 32 + lo * 8]);

  f32x4 acc[8];
#pragma unroll
  for (int n0 = 0; n0 < 8; ++n0) {
    acc[n0] = (f32x4){0.f, 0.f, 0.f, 0.f};
#pragma unroll
    for (int ks = 0; ks < 4; ++ks) {
      bfrag bf = *reinterpret_cast<const bfrag*>(&wl[(n0 * 16 + lr) * 136 + ks * 32 + lo * 8]);
      acc[n0] = __builtin_amdgcn_mfma_f32_16x16x32_bf16(af[ks], bf, acc[n0], 0, 0, 0);
    }
  }
  // attention dots via folded-weight MFMA tile (B from global Wdt, L2-hot)
  f32x4 dacc = (f32x4){0.f, 0.f, 0.f, 0.f};
#pragma unroll
  for (int ks = 0; ks < 4; ++ks) {
    bfrag bd = *reinterpret_cast<const bfrag*>(Wdt + lr * F1 + ks * 32 + lo * 8);
    dacc = __builtin_amdgcn_mfma_f32_16x16x32_bf16(af[ks], bd, dacc, 0, 0, 0);
  }

#pragma unroll
  for (int n0 = 0; n0 < 8; ++n0) {
    ushort* tp = reinterpret_cast<ushort*>(n0 < 4 ? hA : hB);
    int cbase = (n0 & 3) * 16 + lr;
#pragma unroll
    for (int r = 0; r < 4; ++r) {
      int row = r0 + w * 16 + lo * 4 + r;
      if (row < N) tp[(size_t)row * 64 + cbase] = f2bf(acc[n0][r]);
    }
  }
#pragma unroll
  for (int r = 0; r < 4; ++r) {
    int row = r0 + w * 16 + lo * 4 + r;
    if (row < N) {
      if (lr < 8) a_src[row * HEADS + lr] = dacc[r];
      else        a_dst[row * HEADS + (lr - 8)] = dacc[r];
    }
  }
}

// ---------------- D3: per-bucket fine CSR (512 threads) ----------------
__global__ __launch_bounds__(512) void k_csr(const int* __restrict__ pairs,
                                             const int* __restrict__ bukcur,
                                             int* __restrict__ off, int* __restrict__ offe,
                                             int* __restrict__ csr, int N) {
  __shared__ int cnt[BW];
  __shared__ int cur[BW];
  int b = blockIdx.x, t = threadIdx.x;
  int beg = b * BCAP, end = beg + bukcur[b];
  if (t < BW) cnt[t] = 0;
  __syncthreads();
  for (int j = beg + t; j < end; j += 512)
    atomicAdd(&cnt[(pairs[j] >> 20) & (BW - 1)], 1);
  __syncthreads();
  int my = t < BW ? cnt[t] : 0;
  for (int o = 1; o < BW; o <<= 1) {
    int v = (t < BW && t >= o) ? cnt[t - o] : 0;
    __syncthreads();
    if (t < BW) cnt[t] += v;
    __syncthreads();
  }
  if (t < BW) {
    int start = beg + cnt[t] - my;   // exclusive within bucket
    cur[t] = start;
    int d0 = b * BW + t;
    if (d0 < N) { off[d0] = start; offe[d0] = start + my; }
  }
  __syncthreads();
  for (int j = beg + t; j < end; j += 512) {
    int pr = pairs[j];
    int pos = atomicAdd(&cur[(pr >> 20) & (BW - 1)], 1);
    csr[pos] = pr & 0xFFFFF;
  }
}

// ---------------- layer 1 aggregate (channel-split half-table pass) ----------------
__global__ void k_agg1h(const int* __restrict__ off, const int* __restrict__ offe,
                        const int* __restrict__ csr,
                        const uint2* __restrict__ htab, const float* __restrict__ a_src,
                        const float* __restrict__ a_dst, const float* __restrict__ b1,
                        uint* __restrict__ out1b, int N, int hbase, int obase) {
  int w = threadIdx.x >> 6, lane = threadIdx.x & 63;
  int q = lane >> 4, c2 = lane & 15;
  int h = hbase + (c2 >> 2);
  int d = blockIdx.x * 4 + w;
  if (d >= N) return;
  int beg = off[d], end = offe[d];
  float adl = a_dst[d * HEADS + h];
  float a0 = 0.f, a1 = 0.f, a2 = 0.f, a3 = 0.f, den = 0.f;
#pragma unroll 2
  for (int j = beg + q; j < end; j += 4) {
    int s = csr[j];
    float v = a_src[s * HEADS + h] + adl;
    v = v >= 0.f ? v : 0.2f * v;
    float p = __expf(v);
    uint2 wd = htab[(size_t)s * 16 + c2];
    a0 = fmaf(p, bf2f_lo(wd.x), a0);
    a1 = fmaf(p, bf2f_hi(wd.x), a1);
    a2 = fmaf(p, bf2f_lo(wd.y), a2);
    a3 = fmaf(p, bf2f_hi(wd.y), a3);
    den += p;
  }
  a0 += __shfl_xor(a0, 16); a0 += __shfl_xor(a0, 32);
  a1 += __shfl_xor(a1, 16); a1 += __shfl_xor(a1, 32);
  a2 += __shfl_xor(a2, 16); a2 += __shfl_xor(a2, 32);
  a3 += __shfl_xor(a3, 16); a3 += __shfl_xor(a3, 32);
  den += __shfl_xor(den, 16); den += __shfl_xor(den, 32);
  if (q == 0) {
    float inv = 1.f / den;   // self-loop guarantees den > 0
    float4 bb = *reinterpret_cast<const float4*>(&b1[obase + 4 * c2]);
    uint2 o;
    o.x = (uint)f2bf(a0 * inv + bb.x) | ((uint)f2bf(a1 * inv + bb.y) << 16);
    o.y = (uint)f2bf(a2 * inv + bb.z) | ((uint)f2bf(a3 * inv + bb.w) << 16);
    *reinterpret_cast<uint2*>(&out1b[(size_t)d * 64 + (obase >> 1) + 2 * c2]) = o;
  }
}

// ---------------- layer 2 GEMM (MFMA bf16, ELU fused into staging) ----------------
__global__ __launch_bounds__(256) void k_gemm2(
    const uint* __restrict__ out1b, const ushort* __restrict__ W2t,
    const ushort* __restrict__ Wd2t,
    uint* __restrict__ h2b, float* __restrict__ a_src2,
    float* __restrict__ a_dst2, int N) {
  __shared__ __align__(16) ushort xl[64 * 136];   // 17.0 KB
  __shared__ __align__(16) ushort wl[64 * 136];   // 17.0 KB
  int tx = threadIdx.x;
  int r0 = blockIdx.x * 64;

  {
    int c = tx & 63, k0 = (tx >> 6) * 32;
    const uint4* g = reinterpret_cast<const uint4*>(W2t + c * F1 + k0);
#pragma unroll
    for (int j = 0; j < 4; ++j)
      *reinterpret_cast<uint4*>(&wl[c * 136 + k0 + j * 8]) = g[j];
  }
  {
    int row = tx & 63, kq = tx >> 6;
    bool act = (r0 + row) < N;
    const uint4* xg = reinterpret_cast<const uint4*>(out1b + (size_t)(r0 + row) * 64 + kq * 16);
#pragma unroll
    for (int j = 0; j < 4; ++j) {
      uint4 v = act ? xg[j] : make_uint4(0, 0, 0, 0);
      uint4 pk;
      pk.x = elu2(v.x);
      pk.y = elu2(v.y);
      pk.z = elu2(v.z);
      pk.w = elu2(v.w);
      *reinterpret_cast<uint4*>(&xl[row * 136 + kq * 32 + j * 8]) = pk;
    }
  }
  __syncthreads();

  int w = tx >> 6, l = tx & 63;
  int lr = l & 15, lo = l >> 4;

  bfrag af[4];
#pragma unroll
  for (int ks = 0; ks < 4; ++ks)
    af[ks] = *reinterpret_cast<const bfrag*>(&xl[(w * 16 + lr) * 136 + ks * 32 + lo * 8]);

  f32x4 acc[4];
#pragma unroll
  for (int n0 = 0; n0 < 4; ++n0) {
    acc[n0] = (f32x4){0.f, 0.f, 0.f, 0.f};
#pragma unroll
    for (int ks = 0; ks < 4; ++ks) {
      bfrag bf = *reinterpret_cast<const bfrag*>(&wl[(n0 * 16 + lr) * 136 + ks * 32 + lo * 8]);
      acc[n0] = __builtin_amdgcn_mfma_f32_16x16x32_bf16(af[ks], bf, acc[n0], 0, 0, 0);
    }
  }
  f32x4 dacc = (f32x4){0.f, 0.f, 0.f, 0.f};
#pragma unroll
  for (int ks = 0; ks < 4; ++ks) {
    bfrag bd = *reinterpret_cast<const bfrag*>(Wd2t + lr * F1 + ks * 32 + lo * 8);
    dacc = __builtin_amdgcn_mfma_f32_16x16x32_bf16(af[ks], bd, dacc, 0, 0, 0);
  }

  ushort* tp = reinterpret_cast<ushort*>(h2b);
#pragma unroll
  for (int r = 0; r < 4; ++r) {
    int row = r0 + w * 16 + lo * 4 + r;
    if (row < N) {
#pragma unroll
      for (int n0 = 0; n0 < 4; ++n0)
        tp[(size_t)row * 64 + n0 * 16 + lr] = f2bf(acc[n0][r]);
      if (lr == 0) a_src2[row] = dacc[r];
      if (lr == 1) a_dst2[row] = dacc[r];
    }
  }
}

// ---------------- layer 2 aggregate ----------------
__global__ void k_agg2(const int* __restrict__ off, const int* __restrict__ offe,
                       const int* __restrict__ csr,
                       const uint4* __restrict__ h2b4, const float* __restrict__ a_src2,
                       const float* __restrict__ a_dst2, const float* __restrict__ b2,
                       float* __restrict__ out, int N) {
  int w = threadIdx.x >> 6, lane = threadIdx.x & 63;
  int g = lane >> 3, c4 = lane & 7;   // channels 8*c4..8*c4+7
  int d = blockIdx.x * 4 + w;
  if (d >= N) return;
  int beg = off[d], end = offe[d];
  float adl = a_dst2[d];
  float a[8] = {0.f, 0.f, 0.f, 0.f, 0.f, 0.f, 0.f, 0.f};
  float den = 0.f;
  for (int j = beg + g; j < end; j += 8) {
    int s = csr[j];
    float v = a_src2[s] + adl;
    v = v >= 0.f ? v : 0.2f * v;
    float p = __expf(v);
    uint4 wd = h2b4[(size_t)s * 8 + c4];
    a[0] = fmaf(p, bf2f_lo(wd.x), a[0]);
    a[1] = fmaf(p, bf2f_hi(wd.x), a[1]);
    a[2] = fmaf(p, bf2f_lo(wd.y), a[2]);
    a[3] = fmaf(p, bf2f_hi(wd.y), a[3]);
    a[4] = fmaf(p, bf2f_lo(wd.z), a[4]);
    a[5] = fmaf(p, bf2f_hi(wd.z), a[5]);
    a[6] = fmaf(p, bf2f_lo(wd.w), a[6]);
    a[7] = fmaf(p, bf2f_hi(wd.w), a[7]);
    den += p;
  }
#pragma unroll
  for (int i = 0; i < 8; ++i) {
    a[i] += __shfl_xor(a[i], 8);
    a[i] += __shfl_xor(a[i], 16);
    a[i] += __shfl_xor(a[i], 32);
  }
  den += __shfl_xor(den, 8); den += __shfl_xor(den, 16); den += __shfl_xor(den, 32);
  if (g == 0) {
    float inv = 1.f / den;
    float4 b0 = *reinterpret_cast<const float4*>(&b2[8 * c4]);
    float4 b1v = *reinterpret_cast<const float4*>(&b2[8 * c4 + 4]);
    float4 o0, o1;
    o0.x = a[0] * inv + b0.x;  o0.y = a[1] * inv + b0.y;
    o0.z = a[2] * inv + b0.z;  o0.w = a[3] * inv + b0.w;
    o1.x = a[4] * inv + b1v.x; o1.y = a[5] * inv + b1v.y;
    o1.z = a[6] * inv + b1v.z; o1.w = a[7] * inv + b1v.w;
    *reinterpret_cast<float4*>(&out[(size_t)d * OUTD + 8 * c4]) = o0;
    *reinterpret_cast<float4*>(&out[(size_t)d * OUTD + 8 * c4 + 4]) = o1;
  }
}

extern "C" void kernel_launch(void* const* d_in, const int* in_sizes, int n_in,
                              void* d_out, int out_size, void* d_ws, size_t ws_size,
                              hipStream_t stream) {
  const float* x   = (const float*)d_in[0];
  const int*   ei  = (const int*)d_in[1];
  const float* W1  = (const float*)d_in[2];
  const float* as1 = (const float*)d_in[3];
  const float* ad1 = (const float*)d_in[4];
  const float* b1  = (const float*)d_in[5];
  const float* W2  = (const float*)d_in[6];
  const float* as2 = (const float*)d_in[7];
  const float* ad2 = (const float*)d_in[8];
  const float* b2  = (const float*)d_in[9];
  float* out = (float*)d_out;

  int N = in_sizes[0] / F1;
  int E = in_sizes[1] / 2;
  int ET = E + N;
  int NBUK = (N + BW - 1) / BW;       // 391 for N=50000 (<= MAXBUK)
  int NCH = (ET + CHUNK - 1) / CHUNK; // scatter blocks
  int NT = (N + 63) / 64;             // GEMM tiles (64 rows)
  int NWC = (F1 * F1 + OUTD * F1 + 4096 + MAXBUK + 255) / 256;

  // workspace layout (16B-aligned chunks)
  char* p = (char*)d_ws;
  auto alloc = [&](size_t bytes) {
    char* q = p;
    p += (bytes + 15) & ~(size_t)15;
    return q;
  };
  int* bukcur  = (int*)alloc((size_t)NBUK * 4);
  int* off     = (int*)alloc((size_t)N * 4);
  int* offe    = (int*)alloc((size_t)N * 4);
  int* pairs   = (int*)alloc((size_t)NBUK * BCAP * 4);
  int* csr     = (int*)alloc((size_t)NBUK * BCAP * 4);
  ushort* W1t  = (ushort*)alloc((size_t)F1 * F1 * 2);
  ushort* W2t  = (ushort*)alloc((size_t)OUTD * F1 * 2);
  ushort* Wdt  = (ushort*)alloc((size_t)16 * F1 * 2);
  ushort* Wd2t = (ushort*)alloc((size_t)16 * F1 * 2);
  uint* hA     = (uint*)alloc((size_t)N * 32 * 4);   // heads 0-3
  uint* hB     = (uint*)alloc((size_t)N * 32 * 4);   // heads 4-7
  uint* h2b    = (uint*)alloc((size_t)N * 32 * 4);
  uint* out1b  = (uint*)alloc((size_t)N * 64 * 4);   // bf16-packed out1
  float* a_src1 = (float*)alloc((size_t)N * HEADS * 4);
  float* a_dst1 = (float*)alloc((size_t)N * HEADS * 4);
  float* a_src2 = (float*)alloc((size_t)N * 4);
  float* a_dst2 = (float*)alloc((size_t)N * 4);

  // D1: setup (W convert + folded dot-weights + bucket-cursor zero)
  hipLaunchKernelGGL(k_wcvt, dim3(NWC), dim3(256), 0, stream,
                     W1, W2, as1, ad1, as2, ad2, W1t, W2t, Wdt, Wd2t, bukcur, NBUK);
  // D2: scatter || gemm1 (block-range fused)
  hipLaunchKernelGGL(k_sg, dim3(NCH + NT), dim3(256), 0, stream,
                     ei, E, N, bukcur, pairs,
                     x, W1t, Wdt, hA, hB, a_src1, a_dst1, NCH);
  // D3: fine CSR
  hipLaunchKernelGGL(k_csr, dim3(NBUK), dim3(512), 0, stream,
                     pairs, bukcur, off, offe, csr, N);

  // D4/D5: layer-1 aggregate (two half-table passes)
  hipLaunchKernelGGL(k_agg1h, dim3((N + 3) / 4), dim3(256), 0, stream,
                     off, offe, csr, (const uint2*)hA, a_src1, a_dst1, b1, out1b, N, 0, 0);
  hipLaunchKernelGGL(k_agg1h, dim3((N + 3) / 4), dim3(256), 0, stream,
                     off, offe, csr, (const uint2*)hB, a_src1, a_dst1, b1, out1b, N, 4, 64);

  // D6/D7: layer 2
  hipLaunchKernelGGL(k_gemm2, dim3(NT), dim3(256), 0, stream,
                     out1b, W2t, Wd2t, h2b, a_src2, a_dst2, N);
  hipLaunchKernelGGL(k_agg2, dim3((N + 3) / 4), dim3(256), 0, stream,
                     off, offe, csr, (const uint4*)h2b, a_src2, a_dst2, b2, out, N);
}

// Round 18
// 146.065 us; speedup vs baseline: 1.4070x; 1.0128x over previous
//
#include <hip/hip_runtime.h>
#include <hip/hip_bf16.h>

#define HEADS 8
#define HID 16
#define F1 128    // HEADS*HID
#define OUTD 64
#define BWL 7          // log2(bucket width)
#define BW 128         // dst-range per bucket
#define MAXBUK 512     // >= ceil(N/BW); N=50000 -> 391
#define BCAP 3584      // fixed bucket capacity (mean 2176 + 31 sigma)
#define CHUNK 2048     // edges per block in scatter (256 thr x 8)

typedef unsigned int uint;
typedef unsigned short ushort;
typedef __attribute__((ext_vector_type(8))) short bfrag;   // 8 bf16 (4 VGPR)
typedef __attribute__((ext_vector_type(4))) float f32x4;

__device__ __forceinline__ ushort f2bf(float f) {
  __hip_bfloat16 b = __float2bfloat16(f);
  return *reinterpret_cast<ushort*>(&b);
}
__device__ __forceinline__ float bf2f_lo(uint w) {
  return __uint_as_float((w & 0xFFFFu) << 16);
}
__device__ __forceinline__ float bf2f_hi(uint w) {
  return __uint_as_float(w & 0xFFFF0000u);
}
// ELU both bf16 halves of a packed uint
__device__ __forceinline__ uint elu2(uint u) {
  float lo = bf2f_lo(u), hi = bf2f_hi(u);
  lo = lo > 0.f ? lo : __expf(lo) - 1.f;
  hi = hi > 0.f ? hi : __expf(hi) - 1.f;
  return (uint)f2bf(lo) | ((uint)f2bf(hi) << 16);
}

// ---------------- D1: setup ----------------
// W1t[c][k] bf16 128x128; W2t[c][k] bf16 64x128.
// Wdt[j][k] 16x128: cols j<8 = as1-folded W1, j>=8 = ad1-folded (head j&7).
// Wd2t[j][k] 16x128: j=0 as2-folded W2, j=1 ad2-folded, j>=2 zero.
__global__ void k_wcvt(const float* __restrict__ W1, const float* __restrict__ W2,
                       const float* __restrict__ as1, const float* __restrict__ ad1,
                       const float* __restrict__ as2, const float* __restrict__ ad2,
                       ushort* __restrict__ W1t, ushort* __restrict__ W2t,
                       ushort* __restrict__ Wdt, ushort* __restrict__ Wd2t,
                       int* __restrict__ bukcur, int NBUK) {
  int o = blockIdx.x * 256 + threadIdx.x;
  if (o < F1 * F1) {
    int c = o >> 7, k = o & 127;
    W1t[o] = f2bf(W1[k * F1 + c]);
  } else if (o < F1 * F1 + OUTD * F1) {
    int i = o - F1 * F1;
    int c = i >> 7, k = i & 127;
    W2t[i] = f2bf(W2[k * OUTD + c]);
  } else if (o < F1 * F1 + OUTD * F1 + 2048) {
    int i = o - (F1 * F1 + OUTD * F1);
    int j = i >> 7, k = i & 127;
    const float* av = j < 8 ? as1 : ad1;
    int h = j & 7;
    float s = 0.f;
#pragma unroll
    for (int t = 0; t < HID; ++t)
      s = fmaf(W1[k * F1 + h * HID + t], av[h * HID + t], s);
    Wdt[i] = f2bf(s);
  } else if (o < F1 * F1 + OUTD * F1 + 4096) {
    int i = o - (F1 * F1 + OUTD * F1 + 2048);
    int j = i >> 7, k = i & 127;
    float s = 0.f;
    if (j < 2) {
      const float* av = j == 0 ? as2 : ad2;
      for (int c = 0; c < OUTD; ++c) s = fmaf(W2[k * OUTD + c], av[c], s);
    }
    Wd2t[i] = f2bf(s);
  } else {
    int i = o - (F1 * F1 + OUTD * F1 + 4096);
    if (i < NBUK) bukcur[i] = 0;
  }
}

// ---------------- D2: fused scatter (blocks [0,NCH)) + layer-1 MFMA GEMM ----------------
__global__ __launch_bounds__(256) void k_sg(
    const int* __restrict__ ei, int E, int N, int* __restrict__ bukcur,
    int* __restrict__ pairs,
    const float* __restrict__ x, const ushort* __restrict__ W1t,
    const ushort* __restrict__ Wdt,
    uint* __restrict__ hA, uint* __restrict__ hB,
    float* __restrict__ a_src, float* __restrict__ a_dst, int NCH_) {
  __shared__ __align__(16) char smem[52224];   // 64*136*2 + 128*136*2 bytes
  int tx = threadIdx.x;

  if ((int)blockIdx.x < NCH_) {
    // ---------------- scatter ----------------
    int* hist = (int*)smem;
    hist[tx] = 0; hist[tx + 256] = 0;
    __syncthreads();
    long long e0 = (long long)blockIdx.x * CHUNK;
    int ET = E + N;
    int myP[8], myB[8];
#pragma unroll
    for (int i = 0; i < 8; ++i) {
      long long e = e0 + i * 256 + tx;
      if (e < ET) {
        int s = e < E ? ei[e] : (int)(e - E);
        int d = e < E ? ei[E + e] : (int)(e - E);
        myP[i] = s | ((d & (BW - 1)) << 20);
        myB[i] = d >> BWL;
        atomicAdd(&hist[myB[i]], 1);
      } else {
        myB[i] = -1;
      }
    }
    __syncthreads();
    for (int b = tx; b < MAXBUK; b += 256) {
      int c = hist[b];
      hist[b] = c ? (b * BCAP + atomicAdd(&bukcur[b], c)) : 0;
    }
    __syncthreads();
#pragma unroll
    for (int i = 0; i < 8; ++i) {
      if (myB[i] >= 0) {
        int pos = atomicAdd(&hist[myB[i]], 1);
        pairs[pos] = myP[i];
      }
    }
    return;
  }

  // ---------------- gemm1 ----------------
  ushort* xl = (ushort*)smem;          // [64*136]
  ushort* wl = xl + 64 * 136;          // [128*136]
  int r0 = ((int)blockIdx.x - NCH_) * 64;

  {
    int c = tx >> 1, k0 = (tx & 1) * 64;
    const uint4* g = reinterpret_cast<const uint4*>(W1t + c * F1 + k0);
#pragma unroll
    for (int j = 0; j < 8; ++j)
      *reinterpret_cast<uint4*>(&wl[c * 136 + k0 + j * 8]) = g[j];
  }
  {
    int row = tx & 63, kq = tx >> 6;
    bool act = (r0 + row) < N;
    const float4* xg = reinterpret_cast<const float4*>(x + (size_t)(r0 + row) * F1 + kq * 32);
#pragma unroll
    for (int j = 0; j < 4; ++j) {
      float4 va = act ? xg[2 * j]     : make_float4(0.f, 0.f, 0.f, 0.f);
      float4 vb = act ? xg[2 * j + 1] : make_float4(0.f, 0.f, 0.f, 0.f);
      uint4 pk;
      pk.x = (uint)f2bf(va.x) | ((uint)f2bf(va.y) << 16);
      pk.y = (uint)f2bf(va.z) | ((uint)f2bf(va.w) << 16);
      pk.z = (uint)f2bf(vb.x) | ((uint)f2bf(vb.y) << 16);
      pk.w = (uint)f2bf(vb.z) | ((uint)f2bf(vb.w) << 16);
      *reinterpret_cast<uint4*>(&xl[row * 136 + kq * 32 + j * 8]) = pk;
    }
  }
  __syncthreads();

  int w = tx >> 6, l = tx & 63;
  int lr = l & 15, lo = l >> 4;

  bfrag af[4];
#pragma unroll
  for (int ks = 0; ks < 4; ++ks)
    af[ks] = *reinterpret_cast<const bfrag*>(&xl[(w * 16 + lr) * 136 + ks * 32 + lo * 8]);

  f32x4 acc[8];
#pragma unroll
  for (int n0 = 0; n0 < 8; ++n0) {
    acc[n0] = (f32x4){0.f, 0.f, 0.f, 0.f};
#pragma unroll
    for (int ks = 0; ks < 4; ++ks) {
      bfrag bf = *reinterpret_cast<const bfrag*>(&wl[(n0 * 16 + lr) * 136 + ks * 32 + lo * 8]);
      acc[n0] = __builtin_amdgcn_mfma_f32_16x16x32_bf16(af[ks], bf, acc[n0], 0, 0, 0);
    }
  }
  // attention dots via folded-weight MFMA tile (B from global Wdt, L2-hot)
  f32x4 dacc = (f32x4){0.f, 0.f, 0.f, 0.f};
#pragma unroll
  for (int ks = 0; ks < 4; ++ks) {
    bfrag bd = *reinterpret_cast<const bfrag*>(Wdt + lr * F1 + ks * 32 + lo * 8);
    dacc = __builtin_amdgcn_mfma_f32_16x16x32_bf16(af[ks], bd, dacc, 0, 0, 0);
  }

#pragma unroll
  for (int n0 = 0; n0 < 8; ++n0) {
    ushort* tp = reinterpret_cast<ushort*>(n0 < 4 ? hA : hB);
    int cbase = (n0 & 3) * 16 + lr;
#pragma unroll
    for (int r = 0; r < 4; ++r) {
      int row = r0 + w * 16 + lo * 4 + r;
      if (row < N) tp[(size_t)row * 64 + cbase] = f2bf(acc[n0][r]);
    }
  }
#pragma unroll
  for (int r = 0; r < 4; ++r) {
    int row = r0 + w * 16 + lo * 4 + r;
    if (row < N) {
      if (lr < 8) a_src[row * HEADS + lr] = dacc[r];
      else        a_dst[row * HEADS + (lr - 8)] = dacc[r];
    }
  }
}

// ---------------- D3: per-bucket fine CSR (512 threads) ----------------
__global__ __launch_bounds__(512) void k_csr(const int* __restrict__ pairs,
                                             const int* __restrict__ bukcur,
                                             int* __restrict__ off, int* __restrict__ offe,
                                             int* __restrict__ csr, int N) {
  __shared__ int cnt[BW];
  __shared__ int cur[BW];
  int b = blockIdx.x, t = threadIdx.x;
  int beg = b * BCAP, end = beg + bukcur[b];
  if (t < BW) cnt[t] = 0;
  __syncthreads();
  for (int j = beg + t; j < end; j += 512)
    atomicAdd(&cnt[(pairs[j] >> 20) & (BW - 1)], 1);
  __syncthreads();
  int my = t < BW ? cnt[t] : 0;
  for (int o = 1; o < BW; o <<= 1) {
    int v = (t < BW && t >= o) ? cnt[t - o] : 0;
    __syncthreads();
    if (t < BW) cnt[t] += v;
    __syncthreads();
  }
  if (t < BW) {
    int start = beg + cnt[t] - my;   // exclusive within bucket
    cur[t] = start;
    int d0 = b * BW + t;
    if (d0 < N) { off[d0] = start; offe[d0] = start + my; }
  }
  __syncthreads();
  for (int j = beg + t; j < end; j += 512) {
    int pr = pairs[j];
    int pos = atomicAdd(&cur[(pr >> 20) & (BW - 1)], 1);
    csr[pos] = pr & 0xFFFFF;
  }
}

// ---------------- layer 1 aggregate (channel-split half-table pass) ----------------
// 1 wave/dst; eight 8-lane groups on alternating edges (8 rows in flight);
// lane owns 8 half-table channels via uint4 (8x16B = 128B row); head = c4>>1;
// combine shfl_xor(8/16/32). hbase = 0/4, obase = 0/64.
__global__ void k_agg1h(const int* __restrict__ off, const int* __restrict__ offe,
                        const int* __restrict__ csr,
                        const uint4* __restrict__ htab4, const float* __restrict__ a_src,
                        const float* __restrict__ a_dst, const float* __restrict__ b1,
                        uint* __restrict__ out1b, int N, int hbase, int obase) {
  int w = threadIdx.x >> 6, lane = threadIdx.x & 63;
  int g = lane >> 3, c4 = lane & 7;   // half-channels 8*c4..8*c4+7
  int h = hbase + (c4 >> 1);
  int d = blockIdx.x * 4 + w;
  if (d >= N) return;
  int beg = off[d], end = offe[d];
  float adl = a_dst[d * HEADS + h];
  float a[8] = {0.f, 0.f, 0.f, 0.f, 0.f, 0.f, 0.f, 0.f};
  float den = 0.f;
  for (int j = beg + g; j < end; j += 8) {
    int s = csr[j];
    float v = a_src[s * HEADS + h] + adl;
    v = v >= 0.f ? v : 0.2f * v;
    float p = __expf(v);
    uint4 wd = htab4[(size_t)s * 8 + c4];
    a[0] = fmaf(p, bf2f_lo(wd.x), a[0]);
    a[1] = fmaf(p, bf2f_hi(wd.x), a[1]);
    a[2] = fmaf(p, bf2f_lo(wd.y), a[2]);
    a[3] = fmaf(p, bf2f_hi(wd.y), a[3]);
    a[4] = fmaf(p, bf2f_lo(wd.z), a[4]);
    a[5] = fmaf(p, bf2f_hi(wd.z), a[5]);
    a[6] = fmaf(p, bf2f_lo(wd.w), a[6]);
    a[7] = fmaf(p, bf2f_hi(wd.w), a[7]);
    den += p;
  }
#pragma unroll
  for (int i = 0; i < 8; ++i) {
    a[i] += __shfl_xor(a[i], 8);
    a[i] += __shfl_xor(a[i], 16);
    a[i] += __shfl_xor(a[i], 32);
  }
  den += __shfl_xor(den, 8); den += __shfl_xor(den, 16); den += __shfl_xor(den, 32);
  if (g == 0) {
    float inv = 1.f / den;   // self-loop guarantees den > 0
    float4 b0 = *reinterpret_cast<const float4*>(&b1[obase + 8 * c4]);
    float4 b1v = *reinterpret_cast<const float4*>(&b1[obase + 8 * c4 + 4]);
    uint4 o;
    o.x = (uint)f2bf(a[0] * inv + b0.x)  | ((uint)f2bf(a[1] * inv + b0.y) << 16);
    o.y = (uint)f2bf(a[2] * inv + b0.z)  | ((uint)f2bf(a[3] * inv + b0.w) << 16);
    o.z = (uint)f2bf(a[4] * inv + b1v.x) | ((uint)f2bf(a[5] * inv + b1v.y) << 16);
    o.w = (uint)f2bf(a[6] * inv + b1v.z) | ((uint)f2bf(a[7] * inv + b1v.w) << 16);
    *reinterpret_cast<uint4*>(&out1b[(size_t)d * 64 + (obase >> 1) + 4 * c4]) = o;
  }
}

// ---------------- layer 2 GEMM (MFMA bf16, ELU fused into staging) ----------------
__global__ __launch_bounds__(256) void k_gemm2(
    const uint* __restrict__ out1b, const ushort* __restrict__ W2t,
    const ushort* __restrict__ Wd2t,
    uint* __restrict__ h2b, float* __restrict__ a_src2,
    float* __restrict__ a_dst2, int N) {
  __shared__ __align__(16) ushort xl[64 * 136];   // 17.0 KB
  __shared__ __align__(16) ushort wl[64 * 136];   // 17.0 KB
  int tx = threadIdx.x;
  int r0 = blockIdx.x * 64;

  {
    int c = tx & 63, k0 = (tx >> 6) * 32;
    const uint4* g = reinterpret_cast<const uint4*>(W2t + c * F1 + k0);
#pragma unroll
    for (int j = 0; j < 4; ++j)
      *reinterpret_cast<uint4*>(&wl[c * 136 + k0 + j * 8]) = g[j];
  }
  {
    int row = tx & 63, kq = tx >> 6;
    bool act = (r0 + row) < N;
    const uint4* xg = reinterpret_cast<const uint4*>(out1b + (size_t)(r0 + row) * 64 + kq * 16);
#pragma unroll
    for (int j = 0; j < 4; ++j) {
      uint4 v = act ? xg[j] : make_uint4(0, 0, 0, 0);
      uint4 pk;
      pk.x = elu2(v.x);
      pk.y = elu2(v.y);
      pk.z = elu2(v.z);
      pk.w = elu2(v.w);
      *reinterpret_cast<uint4*>(&xl[row * 136 + kq * 32 + j * 8]) = pk;
    }
  }
  __syncthreads();

  int w = tx >> 6, l = tx & 63;
  int lr = l & 15, lo = l >> 4;

  bfrag af[4];
#pragma unroll
  for (int ks = 0; ks < 4; ++ks)
    af[ks] = *reinterpret_cast<const bfrag*>(&xl[(w * 16 + lr) * 136 + ks * 32 + lo * 8]);

  f32x4 acc[4];
#pragma unroll
  for (int n0 = 0; n0 < 4; ++n0) {
    acc[n0] = (f32x4){0.f, 0.f, 0.f, 0.f};
#pragma unroll
    for (int ks = 0; ks < 4; ++ks) {
      bfrag bf = *reinterpret_cast<const bfrag*>(&wl[(n0 * 16 + lr) * 136 + ks * 32 + lo * 8]);
      acc[n0] = __builtin_amdgcn_mfma_f32_16x16x32_bf16(af[ks], bf, acc[n0], 0, 0, 0);
    }
  }
  f32x4 dacc = (f32x4){0.f, 0.f, 0.f, 0.f};
#pragma unroll
  for (int ks = 0; ks < 4; ++ks) {
    bfrag bd = *reinterpret_cast<const bfrag*>(Wd2t + lr * F1 + ks * 32 + lo * 8);
    dacc = __builtin_amdgcn_mfma_f32_16x16x32_bf16(af[ks], bd, dacc, 0, 0, 0);
  }

  ushort* tp = reinterpret_cast<ushort*>(h2b);
#pragma unroll
  for (int r = 0; r < 4; ++r) {
    int row = r0 + w * 16 + lo * 4 + r;
    if (row < N) {
#pragma unroll
      for (int n0 = 0; n0 < 4; ++n0)
        tp[(size_t)row * 64 + n0 * 16 + lr] = f2bf(acc[n0][r]);
      if (lr == 0) a_src2[row] = dacc[r];
      if (lr == 1) a_dst2[row] = dacc[r];
    }
  }
}

// ---------------- layer 2 aggregate ----------------
__global__ void k_agg2(const int* __restrict__ off, const int* __restrict__ offe,
                       const int* __restrict__ csr,
                       const uint4* __restrict__ h2b4, const float* __restrict__ a_src2,
                       const float* __restrict__ a_dst2, const float* __restrict__ b2,
                       float* __restrict__ out, int N) {
  int w = threadIdx.x >> 6, lane = threadIdx.x & 63;
  int g = lane >> 3, c4 = lane & 7;   // channels 8*c4..8*c4+7
  int d = blockIdx.x * 4 + w;
  if (d >= N) return;
  int beg = off[d], end = offe[d];
  float adl = a_dst2[d];
  float a[8] = {0.f, 0.f, 0.f, 0.f, 0.f, 0.f, 0.f, 0.f};
  float den = 0.f;
  for (int j = beg + g; j < end; j += 8) {
    int s = csr[j];
    float v = a_src2[s] + adl;
    v = v >= 0.f ? v : 0.2f * v;
    float p = __expf(v);
    uint4 wd = h2b4[(size_t)s * 8 + c4];
    a[0] = fmaf(p, bf2f_lo(wd.x), a[0]);
    a[1] = fmaf(p, bf2f_hi(wd.x), a[1]);
    a[2] = fmaf(p, bf2f_lo(wd.y), a[2]);
    a[3] = fmaf(p, bf2f_hi(wd.y), a[3]);
    a[4] = fmaf(p, bf2f_lo(wd.z), a[4]);
    a[5] = fmaf(p, bf2f_hi(wd.z), a[5]);
    a[6] = fmaf(p, bf2f_lo(wd.w), a[6]);
    a[7] = fmaf(p, bf2f_hi(wd.w), a[7]);
    den += p;
  }
#pragma unroll
  for (int i = 0; i < 8; ++i) {
    a[i] += __shfl_xor(a[i], 8);
    a[i] += __shfl_xor(a[i], 16);
    a[i] += __shfl_xor(a[i], 32);
  }
  den += __shfl_xor(den, 8); den += __shfl_xor(den, 16); den += __shfl_xor(den, 32);
  if (g == 0) {
    float inv = 1.f / den;
    float4 b0 = *reinterpret_cast<const float4*>(&b2[8 * c4]);
    float4 b1v = *reinterpret_cast<const float4*>(&b2[8 * c4 + 4]);
    float4 o0, o1;
    o0.x = a[0] * inv + b0.x;  o0.y = a[1] * inv + b0.y;
    o0.z = a[2] * inv + b0.z;  o0.w = a[3] * inv + b0.w;
    o1.x = a[4] * inv + b1v.x; o1.y = a[5] * inv + b1v.y;
    o1.z = a[6] * inv + b1v.z; o1.w = a[7] * inv + b1v.w;
    *reinterpret_cast<float4*>(&out[(size_t)d * OUTD + 8 * c4]) = o0;
    *reinterpret_cast<float4*>(&out[(size_t)d * OUTD + 8 * c4 + 4]) = o1;
  }
}

extern "C" void kernel_launch(void* const* d_in, const int* in_sizes, int n_in,
                              void* d_out, int out_size, void* d_ws, size_t ws_size,
                              hipStream_t stream) {
  const float* x   = (const float*)d_in[0];
  const int*   ei  = (const int*)d_in[1];
  const float* W1  = (const float*)d_in[2];
  const float* as1 = (const float*)d_in[3];
  const float* ad1 = (const float*)d_in[4];
  const float* b1  = (const float*)d_in[5];
  const float* W2  = (const float*)d_in[6];
  const float* as2 = (const float*)d_in[7];
  const float* ad2 = (const float*)d_in[8];
  const float* b2  = (const float*)d_in[9];
  float* out = (float*)d_out;

  int N = in_sizes[0] / F1;
  int E = in_sizes[1] / 2;
  int ET = E + N;
  int NBUK = (N + BW - 1) / BW;       // 391 for N=50000 (<= MAXBUK)
  int NCH = (ET + CHUNK - 1) / CHUNK; // scatter blocks
  int NT = (N + 63) / 64;             // GEMM tiles (64 rows)
  int NWC = (F1 * F1 + OUTD * F1 + 4096 + MAXBUK + 255) / 256;

  // workspace layout (16B-aligned chunks)
  char* p = (char*)d_ws;
  auto alloc = [&](size_t bytes) {
    char* q = p;
    p += (bytes + 15) & ~(size_t)15;
    return q;
  };
  int* bukcur  = (int*)alloc((size_t)NBUK * 4);
  int* off     = (int*)alloc((size_t)N * 4);
  int* offe    = (int*)alloc((size_t)N * 4);
  int* pairs   = (int*)alloc((size_t)NBUK * BCAP * 4);
  int* csr     = (int*)alloc((size_t)NBUK * BCAP * 4);
  ushort* W1t  = (ushort*)alloc((size_t)F1 * F1 * 2);
  ushort* W2t  = (ushort*)alloc((size_t)OUTD * F1 * 2);
  ushort* Wdt  = (ushort*)alloc((size_t)16 * F1 * 2);
  ushort* Wd2t = (ushort*)alloc((size_t)16 * F1 * 2);
  uint* hA     = (uint*)alloc((size_t)N * 32 * 4);   // heads 0-3
  uint* hB     = (uint*)alloc((size_t)N * 32 * 4);   // heads 4-7
  uint* h2b    = (uint*)alloc((size_t)N * 32 * 4);
  uint* out1b  = (uint*)alloc((size_t)N * 64 * 4);   // bf16-packed out1
  float* a_src1 = (float*)alloc((size_t)N * HEADS * 4);
  float* a_dst1 = (float*)alloc((size_t)N * HEADS * 4);
  float* a_src2 = (float*)alloc((size_t)N * 4);
  float* a_dst2 = (float*)alloc((size_t)N * 4);

  // D1: setup (W convert + folded dot-weights + bucket-cursor zero)
  hipLaunchKernelGGL(k_wcvt, dim3(NWC), dim3(256), 0, stream,
                     W1, W2, as1, ad1, as2, ad2, W1t, W2t, Wdt, Wd2t, bukcur, NBUK);
  // D2: scatter || gemm1 (block-range fused)
  hipLaunchKernelGGL(k_sg, dim3(NCH + NT), dim3(256), 0, stream,
                     ei, E, N, bukcur, pairs,
                     x, W1t, Wdt, hA, hB, a_src1, a_dst1, NCH);
  // D3: fine CSR
  hipLaunchKernelGGL(k_csr, dim3(NBUK), dim3(512), 0, stream,
                     pairs, bukcur, off, offe, csr, N);

  // D4/D5: layer-1 aggregate (two half-table passes)
  hipLaunchKernelGGL(k_agg1h, dim3((N + 3) / 4), dim3(256), 0, stream,
                     off, offe, csr, (const uint4*)hA, a_src1, a_dst1, b1, out1b, N, 0, 0);
  hipLaunchKernelGGL(k_agg1h, dim3((N + 3) / 4), dim3(256), 0, stream,
                     off, offe, csr, (const uint4*)hB, a_src1, a_dst1, b1, out1b, N, 4, 64);

  // D6/D7: layer 2
  hipLaunchKernelGGL(k_gemm2, dim3(NT), dim3(256), 0, stream,
                     out1b, W2t, Wd2t, h2b, a_src2, a_dst2, N);
  hipLaunchKernelGGL(k_agg2, dim3((N + 3) / 4), dim3(256), 0, stream,
                     off, offe, csr, (const uint4*)h2b, a_src2, a_dst2, b2, out, N);
}

// Round 19
// 142.565 us; speedup vs baseline: 1.4415x; 1.0246x over previous
//
#include <hip/hip_runtime.h>
#include <hip/hip_bf16.h>

#define HEADS 8
#define HID 16
#define F1 128    // HEADS*HID
#define OUTD 64
#define BWL 7          // log2(bucket width)
#define BW 128         // dst-range per bucket
#define MAXBUK 512     // >= ceil(N/BW); N=50000 -> 391
#define BCAP 3584      // fixed bucket capacity (mean 2176 + 31 sigma)
#define CHUNK 2048     // edges per block in scatter (256 thr x 8)

typedef unsigned int uint;
typedef unsigned short ushort;
typedef __attribute__((ext_vector_type(8))) short bfrag;   // 8 bf16 (4 VGPR)
typedef __attribute__((ext_vector_type(4))) float f32x4;

__device__ __forceinline__ ushort f2bf(float f) {
  __hip_bfloat16 b = __float2bfloat16(f);
  return *reinterpret_cast<ushort*>(&b);
}
__device__ __forceinline__ float bf2f_lo(uint w) {
  return __uint_as_float((w & 0xFFFFu) << 16);
}
__device__ __forceinline__ float bf2f_hi(uint w) {
  return __uint_as_float(w & 0xFFFF0000u);
}
// ELU both bf16 halves of a packed uint
__device__ __forceinline__ uint elu2(uint u) {
  float lo = bf2f_lo(u), hi = bf2f_hi(u);
  lo = lo > 0.f ? lo : __expf(lo) - 1.f;
  hi = hi > 0.f ? hi : __expf(hi) - 1.f;
  return (uint)f2bf(lo) | ((uint)f2bf(hi) << 16);
}

// ---------------- D1: setup ----------------
// W1t[c][k] bf16 128x128; W2t[c][k] bf16 64x128.
// Wdt[j][k] 16x128: cols j<8 = as1-folded W1, j>=8 = ad1-folded (head j&7).
// Wd2t[j][k] 16x128: j=0 as2-folded W2, j=1 ad2-folded, j>=2 zero.
__global__ void k_wcvt(const float* __restrict__ W1, const float* __restrict__ W2,
                       const float* __restrict__ as1, const float* __restrict__ ad1,
                       const float* __restrict__ as2, const float* __restrict__ ad2,
                       ushort* __restrict__ W1t, ushort* __restrict__ W2t,
                       ushort* __restrict__ Wdt, ushort* __restrict__ Wd2t,
                       int* __restrict__ bukcur, int NBUK) {
  int o = blockIdx.x * 256 + threadIdx.x;
  if (o < F1 * F1) {
    int c = o >> 7, k = o & 127;
    W1t[o] = f2bf(W1[k * F1 + c]);
  } else if (o < F1 * F1 + OUTD * F1) {
    int i = o - F1 * F1;
    int c = i >> 7, k = i & 127;
    W2t[i] = f2bf(W2[k * OUTD + c]);
  } else if (o < F1 * F1 + OUTD * F1 + 2048) {
    int i = o - (F1 * F1 + OUTD * F1);
    int j = i >> 7, k = i & 127;
    const float* av = j < 8 ? as1 : ad1;
    int h = j & 7;
    float s = 0.f;
#pragma unroll
    for (int t = 0; t < HID; ++t)
      s = fmaf(W1[k * F1 + h * HID + t], av[h * HID + t], s);
    Wdt[i] = f2bf(s);
  } else if (o < F1 * F1 + OUTD * F1 + 4096) {
    int i = o - (F1 * F1 + OUTD * F1 + 2048);
    int j = i >> 7, k = i & 127;
    float s = 0.f;
    if (j < 2) {
      const float* av = j == 0 ? as2 : ad2;
      for (int c = 0; c < OUTD; ++c) s = fmaf(W2[k * OUTD + c], av[c], s);
    }
    Wd2t[i] = f2bf(s);
  } else {
    int i = o - (F1 * F1 + OUTD * F1 + 4096);
    if (i < NBUK) bukcur[i] = 0;
  }
}

// ---------------- D2: fused scatter (blocks [0,NCH)) + layer-1 MFMA GEMM ----------------
__global__ __launch_bounds__(256) void k_sg(
    const int* __restrict__ ei, int E, int N, int* __restrict__ bukcur,
    int* __restrict__ pairs,
    const float* __restrict__ x, const ushort* __restrict__ W1t,
    const ushort* __restrict__ Wdt,
    uint* __restrict__ hA, uint* __restrict__ hB,
    float* __restrict__ a_src, float* __restrict__ a_dst, int NCH_) {
  __shared__ __align__(16) char smem[52224];   // 64*136*2 + 128*136*2 bytes
  int tx = threadIdx.x;

  if ((int)blockIdx.x < NCH_) {
    // ---------------- scatter ----------------
    int* hist = (int*)smem;
    hist[tx] = 0; hist[tx + 256] = 0;
    __syncthreads();
    long long e0 = (long long)blockIdx.x * CHUNK;
    int ET = E + N;
    int myP[8], myB[8];
#pragma unroll
    for (int i = 0; i < 8; ++i) {
      long long e = e0 + i * 256 + tx;
      if (e < ET) {
        int s = e < E ? ei[e] : (int)(e - E);
        int d = e < E ? ei[E + e] : (int)(e - E);
        myP[i] = s | ((d & (BW - 1)) << 20);
        myB[i] = d >> BWL;
        atomicAdd(&hist[myB[i]], 1);
      } else {
        myB[i] = -1;
      }
    }
    __syncthreads();
    for (int b = tx; b < MAXBUK; b += 256) {
      int c = hist[b];
      hist[b] = c ? (b * BCAP + atomicAdd(&bukcur[b], c)) : 0;
    }
    __syncthreads();
#pragma unroll
    for (int i = 0; i < 8; ++i) {
      if (myB[i] >= 0) {
        int pos = atomicAdd(&hist[myB[i]], 1);
        pairs[pos] = myP[i];
      }
    }
    return;
  }

  // ---------------- gemm1 ----------------
  ushort* xl = (ushort*)smem;          // [64*136]
  ushort* wl = xl + 64 * 136;          // [128*136]
  int r0 = ((int)blockIdx.x - NCH_) * 64;

  {
    int c = tx >> 1, k0 = (tx & 1) * 64;
    const uint4* g = reinterpret_cast<const uint4*>(W1t + c * F1 + k0);
#pragma unroll
    for (int j = 0; j < 8; ++j)
      *reinterpret_cast<uint4*>(&wl[c * 136 + k0 + j * 8]) = g[j];
  }
  {
    int row = tx & 63, kq = tx >> 6;
    bool act = (r0 + row) < N;
    const float4* xg = reinterpret_cast<const float4*>(x + (size_t)(r0 + row) * F1 + kq * 32);
#pragma unroll
    for (int j = 0; j < 4; ++j) {
      float4 va = act ? xg[2 * j]     : make_float4(0.f, 0.f, 0.f, 0.f);
      float4 vb = act ? xg[2 * j + 1] : make_float4(0.f, 0.f, 0.f, 0.f);
      uint4 pk;
      pk.x = (uint)f2bf(va.x) | ((uint)f2bf(va.y) << 16);
      pk.y = (uint)f2bf(va.z) | ((uint)f2bf(va.w) << 16);
      pk.z = (uint)f2bf(vb.x) | ((uint)f2bf(vb.y) << 16);
      pk.w = (uint)f2bf(vb.z) | ((uint)f2bf(vb.w) << 16);
      *reinterpret_cast<uint4*>(&xl[row * 136 + kq * 32 + j * 8]) = pk;
    }
  }
  __syncthreads();

  int w = tx >> 6, l = tx & 63;
  int lr = l & 15, lo = l >> 4;

  bfrag af[4];
#pragma unroll
  for (int ks = 0; ks < 4; ++ks)
    af[ks] = *reinterpret_cast<const bfrag*>(&xl[(w * 16 + lr) * 136 + ks * 32 + lo * 8]);

  f32x4 acc[8];
#pragma unroll
  for (int n0 = 0; n0 < 8; ++n0) {
    acc[n0] = (f32x4){0.f, 0.f, 0.f, 0.f};
#pragma unroll
    for (int ks = 0; ks < 4; ++ks) {
      bfrag bf = *reinterpret_cast<const bfrag*>(&wl[(n0 * 16 + lr) * 136 + ks * 32 + lo * 8]);
      acc[n0] = __builtin_amdgcn_mfma_f32_16x16x32_bf16(af[ks], bf, acc[n0], 0, 0, 0);
    }
  }
  // attention dots via folded-weight MFMA tile (B from global Wdt, L2-hot)
  f32x4 dacc = (f32x4){0.f, 0.f, 0.f, 0.f};
#pragma unroll
  for (int ks = 0; ks < 4; ++ks) {
    bfrag bd = *reinterpret_cast<const bfrag*>(Wdt + lr * F1 + ks * 32 + lo * 8);
    dacc = __builtin_amdgcn_mfma_f32_16x16x32_bf16(af[ks], bd, dacc, 0, 0, 0);
  }

#pragma unroll
  for (int n0 = 0; n0 < 8; ++n0) {
    ushort* tp = reinterpret_cast<ushort*>(n0 < 4 ? hA : hB);
    int cbase = (n0 & 3) * 16 + lr;
#pragma unroll
    for (int r = 0; r < 4; ++r) {
      int row = r0 + w * 16 + lo * 4 + r;
      if (row < N) tp[(size_t)row * 64 + cbase] = f2bf(acc[n0][r]);
    }
  }
#pragma unroll
  for (int r = 0; r < 4; ++r) {
    int row = r0 + w * 16 + lo * 4 + r;
    if (row < N) {
      if (lr < 8) a_src[row * HEADS + lr] = dacc[r];
      else        a_dst[row * HEADS + (lr - 8)] = dacc[r];
    }
  }
}

// ---------------- D3: per-bucket fine CSR (512 threads) ----------------
__global__ __launch_bounds__(512) void k_csr(const int* __restrict__ pairs,
                                             const int* __restrict__ bukcur,
                                             int* __restrict__ off, int* __restrict__ offe,
                                             int* __restrict__ csr, int N) {
  __shared__ int cnt[BW];
  __shared__ int cur[BW];
  int b = blockIdx.x, t = threadIdx.x;
  int beg = b * BCAP, end = beg + bukcur[b];
  if (t < BW) cnt[t] = 0;
  __syncthreads();
  for (int j = beg + t; j < end; j += 512)
    atomicAdd(&cnt[(pairs[j] >> 20) & (BW - 1)], 1);
  __syncthreads();
  int my = t < BW ? cnt[t] : 0;
  for (int o = 1; o < BW; o <<= 1) {
    int v = (t < BW && t >= o) ? cnt[t - o] : 0;
    __syncthreads();
    if (t < BW) cnt[t] += v;
    __syncthreads();
  }
  if (t < BW) {
    int start = beg + cnt[t] - my;   // exclusive within bucket
    cur[t] = start;
    int d0 = b * BW + t;
    if (d0 < N) { off[d0] = start; offe[d0] = start + my; }
  }
  __syncthreads();
  for (int j = beg + t; j < end; j += 512) {
    int pr = pairs[j];
    int pos = atomicAdd(&cur[(pr >> 20) & (BW - 1)], 1);
    csr[pos] = pr & 0xFFFFF;
  }
}

// ---------------- D4: fused layer-1 aggregate (both half-table passes) ----------------
// Blocks [0,NB) = pass A (hA, heads 0-3, out cols 0-63); [NB,2NB) = pass B.
// 8 dsts/block (512 thr); 1 wave/dst; eight 8-lane groups on alternating
// edges; lane owns 8 half-channels via uint4; combine shfl_xor(8/16/32).
__global__ __launch_bounds__(512) void k_agg1f(
    const int* __restrict__ off, const int* __restrict__ offe,
    const int* __restrict__ csr,
    const uint4* __restrict__ hA4, const uint4* __restrict__ hB4,
    const float* __restrict__ a_src, const float* __restrict__ a_dst,
    const float* __restrict__ b1, uint* __restrict__ out1b, int N, int NB) {
  int bid = blockIdx.x;
  int passB = bid >= NB;
  const uint4* htab4 = passB ? hB4 : hA4;
  int hbase = passB ? 4 : 0;
  int obase = passB ? 64 : 0;
  int w = threadIdx.x >> 6, lane = threadIdx.x & 63;
  int g = lane >> 3, c4 = lane & 7;   // half-channels 8*c4..8*c4+7
  int h = hbase + (c4 >> 1);
  int d = (passB ? bid - NB : bid) * 8 + w;
  if (d >= N) return;
  int beg = off[d], end = offe[d];
  float adl = a_dst[d * HEADS + h];
  float a[8] = {0.f, 0.f, 0.f, 0.f, 0.f, 0.f, 0.f, 0.f};
  float den = 0.f;
  for (int j = beg + g; j < end; j += 8) {
    int s = csr[j];
    float v = a_src[s * HEADS + h] + adl;
    v = v >= 0.f ? v : 0.2f * v;
    float p = __expf(v);
    uint4 wd = htab4[(size_t)s * 8 + c4];
    a[0] = fmaf(p, bf2f_lo(wd.x), a[0]);
    a[1] = fmaf(p, bf2f_hi(wd.x), a[1]);
    a[2] = fmaf(p, bf2f_lo(wd.y), a[2]);
    a[3] = fmaf(p, bf2f_hi(wd.y), a[3]);
    a[4] = fmaf(p, bf2f_lo(wd.z), a[4]);
    a[5] = fmaf(p, bf2f_hi(wd.z), a[5]);
    a[6] = fmaf(p, bf2f_lo(wd.w), a[6]);
    a[7] = fmaf(p, bf2f_hi(wd.w), a[7]);
    den += p;
  }
#pragma unroll
  for (int i = 0; i < 8; ++i) {
    a[i] += __shfl_xor(a[i], 8);
    a[i] += __shfl_xor(a[i], 16);
    a[i] += __shfl_xor(a[i], 32);
  }
  den += __shfl_xor(den, 8); den += __shfl_xor(den, 16); den += __shfl_xor(den, 32);
  if (g == 0) {
    float inv = 1.f / den;   // self-loop guarantees den > 0
    float4 b0 = *reinterpret_cast<const float4*>(&b1[obase + 8 * c4]);
    float4 b1v = *reinterpret_cast<const float4*>(&b1[obase + 8 * c4 + 4]);
    uint4 o;
    o.x = (uint)f2bf(a[0] * inv + b0.x)  | ((uint)f2bf(a[1] * inv + b0.y) << 16);
    o.y = (uint)f2bf(a[2] * inv + b0.z)  | ((uint)f2bf(a[3] * inv + b0.w) << 16);
    o.z = (uint)f2bf(a[4] * inv + b1v.x) | ((uint)f2bf(a[5] * inv + b1v.y) << 16);
    o.w = (uint)f2bf(a[6] * inv + b1v.z) | ((uint)f2bf(a[7] * inv + b1v.w) << 16);
    *reinterpret_cast<uint4*>(&out1b[(size_t)d * 64 + (obase >> 1) + 4 * c4]) = o;
  }
}

// ---------------- D5: layer 2 GEMM (MFMA bf16, ELU fused into staging) ----------------
__global__ __launch_bounds__(256) void k_gemm2(
    const uint* __restrict__ out1b, const ushort* __restrict__ W2t,
    const ushort* __restrict__ Wd2t,
    uint* __restrict__ h2b, float* __restrict__ a_src2,
    float* __restrict__ a_dst2, int N) {
  __shared__ __align__(16) ushort xl[64 * 136];   // 17.0 KB
  __shared__ __align__(16) ushort wl[64 * 136];   // 17.0 KB
  int tx = threadIdx.x;
  int r0 = blockIdx.x * 64;

  {
    int c = tx & 63, k0 = (tx >> 6) * 32;
    const uint4* g = reinterpret_cast<const uint4*>(W2t + c * F1 + k0);
#pragma unroll
    for (int j = 0; j < 4; ++j)
      *reinterpret_cast<uint4*>(&wl[c * 136 + k0 + j * 8]) = g[j];
  }
  {
    int row = tx & 63, kq = tx >> 6;
    bool act = (r0 + row) < N;
    const uint4* xg = reinterpret_cast<const uint4*>(out1b + (size_t)(r0 + row) * 64 + kq * 16);
#pragma unroll
    for (int j = 0; j < 4; ++j) {
      uint4 v = act ? xg[j] : make_uint4(0, 0, 0, 0);
      uint4 pk;
      pk.x = elu2(v.x);
      pk.y = elu2(v.y);
      pk.z = elu2(v.z);
      pk.w = elu2(v.w);
      *reinterpret_cast<uint4*>(&xl[row * 136 + kq * 32 + j * 8]) = pk;
    }
  }
  __syncthreads();

  int w = tx >> 6, l = tx & 63;
  int lr = l & 15, lo = l >> 4;

  bfrag af[4];
#pragma unroll
  for (int ks = 0; ks < 4; ++ks)
    af[ks] = *reinterpret_cast<const bfrag*>(&xl[(w * 16 + lr) * 136 + ks * 32 + lo * 8]);

  f32x4 acc[4];
#pragma unroll
  for (int n0 = 0; n0 < 4; ++n0) {
    acc[n0] = (f32x4){0.f, 0.f, 0.f, 0.f};
#pragma unroll
    for (int ks = 0; ks < 4; ++ks) {
      bfrag bf = *reinterpret_cast<const bfrag*>(&wl[(n0 * 16 + lr) * 136 + ks * 32 + lo * 8]);
      acc[n0] = __builtin_amdgcn_mfma_f32_16x16x32_bf16(af[ks], bf, acc[n0], 0, 0, 0);
    }
  }
  f32x4 dacc = (f32x4){0.f, 0.f, 0.f, 0.f};
#pragma unroll
  for (int ks = 0; ks < 4; ++ks) {
    bfrag bd = *reinterpret_cast<const bfrag*>(Wd2t + lr * F1 + ks * 32 + lo * 8);
    dacc = __builtin_amdgcn_mfma_f32_16x16x32_bf16(af[ks], bd, dacc, 0, 0, 0);
  }

  ushort* tp = reinterpret_cast<ushort*>(h2b);
#pragma unroll
  for (int r = 0; r < 4; ++r) {
    int row = r0 + w * 16 + lo * 4 + r;
    if (row < N) {
#pragma unroll
      for (int n0 = 0; n0 < 4; ++n0)
        tp[(size_t)row * 64 + n0 * 16 + lr] = f2bf(acc[n0][r]);
      if (lr == 0) a_src2[row] = dacc[r];
      if (lr == 1) a_dst2[row] = dacc[r];
    }
  }
}

// ---------------- D6: layer 2 aggregate ----------------
__global__ void k_agg2(const int* __restrict__ off, const int* __restrict__ offe,
                       const int* __restrict__ csr,
                       const uint4* __restrict__ h2b4, const float* __restrict__ a_src2,
                       const float* __restrict__ a_dst2, const float* __restrict__ b2,
                       float* __restrict__ out, int N) {
  int w = threadIdx.x >> 6, lane = threadIdx.x & 63;
  int g = lane >> 3, c4 = lane & 7;   // channels 8*c4..8*c4+7
  int d = blockIdx.x * 4 + w;
  if (d >= N) return;
  int beg = off[d], end = offe[d];
  float adl = a_dst2[d];
  float a[8] = {0.f, 0.f, 0.f, 0.f, 0.f, 0.f, 0.f, 0.f};
  float den = 0.f;
  for (int j = beg + g; j < end; j += 8) {
    int s = csr[j];
    float v = a_src2[s] + adl;
    v = v >= 0.f ? v : 0.2f * v;
    float p = __expf(v);
    uint4 wd = h2b4[(size_t)s * 8 + c4];
    a[0] = fmaf(p, bf2f_lo(wd.x), a[0]);
    a[1] = fmaf(p, bf2f_hi(wd.x), a[1]);
    a[2] = fmaf(p, bf2f_lo(wd.y), a[2]);
    a[3] = fmaf(p, bf2f_hi(wd.y), a[3]);
    a[4] = fmaf(p, bf2f_lo(wd.z), a[4]);
    a[5] = fmaf(p, bf2f_hi(wd.z), a[5]);
    a[6] = fmaf(p, bf2f_lo(wd.w), a[6]);
    a[7] = fmaf(p, bf2f_hi(wd.w), a[7]);
    den += p;
  }
#pragma unroll
  for (int i = 0; i < 8; ++i) {
    a[i] += __shfl_xor(a[i], 8);
    a[i] += __shfl_xor(a[i], 16);
    a[i] += __shfl_xor(a[i], 32);
  }
  den += __shfl_xor(den, 8); den += __shfl_xor(den, 16); den += __shfl_xor(den, 32);
  if (g == 0) {
    float inv = 1.f / den;
    float4 b0 = *reinterpret_cast<const float4*>(&b2[8 * c4]);
    float4 b1v = *reinterpret_cast<const float4*>(&b2[8 * c4 + 4]);
    float4 o0, o1;
    o0.x = a[0] * inv + b0.x;  o0.y = a[1] * inv + b0.y;
    o0.z = a[2] * inv + b0.z;  o0.w = a[3] * inv + b0.w;
    o1.x = a[4] * inv + b1v.x; o1.y = a[5] * inv + b1v.y;
    o1.z = a[6] * inv + b1v.z; o1.w = a[7] * inv + b1v.w;
    *reinterpret_cast<float4*>(&out[(size_t)d * OUTD + 8 * c4]) = o0;
    *reinterpret_cast<float4*>(&out[(size_t)d * OUTD + 8 * c4 + 4]) = o1;
  }
}

extern "C" void kernel_launch(void* const* d_in, const int* in_sizes, int n_in,
                              void* d_out, int out_size, void* d_ws, size_t ws_size,
                              hipStream_t stream) {
  const float* x   = (const float*)d_in[0];
  const int*   ei  = (const int*)d_in[1];
  const float* W1  = (const float*)d_in[2];
  const float* as1 = (const float*)d_in[3];
  const float* ad1 = (const float*)d_in[4];
  const float* b1  = (const float*)d_in[5];
  const float* W2  = (const float*)d_in[6];
  const float* as2 = (const float*)d_in[7];
  const float* ad2 = (const float*)d_in[8];
  const float* b2  = (const float*)d_in[9];
  float* out = (float*)d_out;

  int N = in_sizes[0] / F1;
  int E = in_sizes[1] / 2;
  int ET = E + N;
  int NBUK = (N + BW - 1) / BW;       // 391 for N=50000 (<= MAXBUK)
  int NCH = (ET + CHUNK - 1) / CHUNK; // scatter blocks
  int NT = (N + 63) / 64;             // GEMM tiles (64 rows)
  int NB8 = (N + 7) / 8;              // agg1f blocks per pass
  int NWC = (F1 * F1 + OUTD * F1 + 4096 + MAXBUK + 255) / 256;

  // workspace layout (16B-aligned chunks)
  char* p = (char*)d_ws;
  auto alloc = [&](size_t bytes) {
    char* q = p;
    p += (bytes + 15) & ~(size_t)15;
    return q;
  };
  int* bukcur  = (int*)alloc((size_t)NBUK * 4);
  int* off     = (int*)alloc((size_t)N * 4);
  int* offe    = (int*)alloc((size_t)N * 4);
  int* pairs   = (int*)alloc((size_t)NBUK * BCAP * 4);
  int* csr     = (int*)alloc((size_t)NBUK * BCAP * 4);
  ushort* W1t  = (ushort*)alloc((size_t)F1 * F1 * 2);
  ushort* W2t  = (ushort*)alloc((size_t)OUTD * F1 * 2);
  ushort* Wdt  = (ushort*)alloc((size_t)16 * F1 * 2);
  ushort* Wd2t = (ushort*)alloc((size_t)16 * F1 * 2);
  uint* hA     = (uint*)alloc((size_t)N * 32 * 4);   // heads 0-3
  uint* hB     = (uint*)alloc((size_t)N * 32 * 4);   // heads 4-7
  uint* h2b    = (uint*)alloc((size_t)N * 32 * 4);
  uint* out1b  = (uint*)alloc((size_t)N * 64 * 4);   // bf16-packed out1
  float* a_src1 = (float*)alloc((size_t)N * HEADS * 4);
  float* a_dst1 = (float*)alloc((size_t)N * HEADS * 4);
  float* a_src2 = (float*)alloc((size_t)N * 4);
  float* a_dst2 = (float*)alloc((size_t)N * 4);

  // D1: setup (W convert + folded dot-weights + bucket-cursor zero)
  hipLaunchKernelGGL(k_wcvt, dim3(NWC), dim3(256), 0, stream,
                     W1, W2, as1, ad1, as2, ad2, W1t, W2t, Wdt, Wd2t, bukcur, NBUK);
  // D2: scatter || gemm1 (block-range fused)
  hipLaunchKernelGGL(k_sg, dim3(NCH + NT), dim3(256), 0, stream,
                     ei, E, N, bukcur, pairs,
                     x, W1t, Wdt, hA, hB, a_src1, a_dst1, NCH);
  // D3: fine CSR
  hipLaunchKernelGGL(k_csr, dim3(NBUK), dim3(512), 0, stream,
                     pairs, bukcur, off, offe, csr, N);
  // D4: layer-1 aggregate, both half-table passes in one dispatch
  hipLaunchKernelGGL(k_agg1f, dim3(2 * NB8), dim3(512), 0, stream,
                     off, offe, csr, (const uint4*)hA, (const uint4*)hB,
                     a_src1, a_dst1, b1, out1b, N, NB8);
  // D5/D6: layer 2
  hipLaunchKernelGGL(k_gemm2, dim3(NT), dim3(256), 0, stream,
                     out1b, W2t, Wd2t, h2b, a_src2, a_dst2, N);
  hipLaunchKernelGGL(k_agg2, dim3((N + 3) / 4), dim3(256), 0, stream,
                     off, offe, csr, (const uint4*)h2b, a_src2, a_dst2, b2, out, N);
}

// Round 20
// 132.958 us; speedup vs baseline: 1.5457x; 1.0723x over previous
//
#include <hip/hip_runtime.h>
#include <hip/hip_bf16.h>

#define HEADS 8
#define HID 16
#define F1 128    // HEADS*HID
#define OUTD 64
#define BWL 7          // log2(bucket width)
#define BW 128         // dst-range per bucket
#define MAXBUK 512     // >= ceil(N/BW); N=50000 -> 391
#define BCAP 3584      // fixed bucket capacity (mean 2176 + 31 sigma)
#define CHUNK 2048     // edges per block in scatter (256 thr x 8)

typedef unsigned int uint;
typedef unsigned short ushort;
typedef __attribute__((ext_vector_type(8))) short bfrag;   // 8 bf16 (4 VGPR)
typedef __attribute__((ext_vector_type(4))) float f32x4;

__device__ __forceinline__ ushort f2bf(float f) {
  __hip_bfloat16 b = __float2bfloat16(f);
  return *reinterpret_cast<ushort*>(&b);
}
__device__ __forceinline__ float bf2f_lo(uint w) {
  return __uint_as_float((w & 0xFFFFu) << 16);
}
__device__ __forceinline__ float bf2f_hi(uint w) {
  return __uint_as_float(w & 0xFFFF0000u);
}
// ELU both bf16 halves of a packed uint
__device__ __forceinline__ uint elu2(uint u) {
  float lo = bf2f_lo(u), hi = bf2f_hi(u);
  lo = lo > 0.f ? lo : __expf(lo) - 1.f;
  hi = hi > 0.f ? hi : __expf(hi) - 1.f;
  return (uint)f2bf(lo) | ((uint)f2bf(hi) << 16);
}

// ---------------- D1: setup ----------------
// W1t[c][k] bf16 128x128; W2t[c][k] bf16 64x128.
// Wdt[j][k] 16x128: cols j<8 = as1-folded W1, j>=8 = ad1-folded (head j&7).
// Wd2t[j][k] 16x128: j=0 as2-folded W2, j=1 ad2-folded, j>=2 zero.
__global__ void k_wcvt(const float* __restrict__ W1, const float* __restrict__ W2,
                       const float* __restrict__ as1, const float* __restrict__ ad1,
                       const float* __restrict__ as2, const float* __restrict__ ad2,
                       ushort* __restrict__ W1t, ushort* __restrict__ W2t,
                       ushort* __restrict__ Wdt, ushort* __restrict__ Wd2t,
                       int* __restrict__ bukcur, int NBUK) {
  int o = blockIdx.x * 256 + threadIdx.x;
  if (o < F1 * F1) {
    int c = o >> 7, k = o & 127;
    W1t[o] = f2bf(W1[k * F1 + c]);
  } else if (o < F1 * F1 + OUTD * F1) {
    int i = o - F1 * F1;
    int c = i >> 7, k = i & 127;
    W2t[i] = f2bf(W2[k * OUTD + c]);
  } else if (o < F1 * F1 + OUTD * F1 + 2048) {
    int i = o - (F1 * F1 + OUTD * F1);
    int j = i >> 7, k = i & 127;
    const float* av = j < 8 ? as1 : ad1;
    int h = j & 7;
    float s = 0.f;
#pragma unroll
    for (int t = 0; t < HID; ++t)
      s = fmaf(W1[k * F1 + h * HID + t], av[h * HID + t], s);
    Wdt[i] = f2bf(s);
  } else if (o < F1 * F1 + OUTD * F1 + 4096) {
    int i = o - (F1 * F1 + OUTD * F1 + 2048);
    int j = i >> 7, k = i & 127;
    float s = 0.f;
    if (j < 2) {
      const float* av = j == 0 ? as2 : ad2;
      for (int c = 0; c < OUTD; ++c) s = fmaf(W2[k * OUTD + c], av[c], s);
    }
    Wd2t[i] = f2bf(s);
  } else {
    int i = o - (F1 * F1 + OUTD * F1 + 4096);
    if (i < NBUK) bukcur[i] = 0;
  }
}

// ---------------- D2: fused scatter (blocks [0,NCH)) + layer-1 MFMA GEMM ----------------
// gemm1 writes a single h1b table (row = 128 bf16 = 256 B).
__global__ __launch_bounds__(256) void k_sg(
    const int* __restrict__ ei, int E, int N, int* __restrict__ bukcur,
    int* __restrict__ pairs,
    const float* __restrict__ x, const ushort* __restrict__ W1t,
    const ushort* __restrict__ Wdt,
    uint* __restrict__ h1b,
    float* __restrict__ a_src, float* __restrict__ a_dst, int NCH_) {
  __shared__ __align__(16) char smem[52224];   // 64*136*2 + 128*136*2 bytes
  int tx = threadIdx.x;

  if ((int)blockIdx.x < NCH_) {
    // ---------------- scatter ----------------
    int* hist = (int*)smem;
    hist[tx] = 0; hist[tx + 256] = 0;
    __syncthreads();
    long long e0 = (long long)blockIdx.x * CHUNK;
    int ET = E + N;
    int myP[8], myB[8];
#pragma unroll
    for (int i = 0; i < 8; ++i) {
      long long e = e0 + i * 256 + tx;
      if (e < ET) {
        int s = e < E ? ei[e] : (int)(e - E);
        int d = e < E ? ei[E + e] : (int)(e - E);
        myP[i] = s | ((d & (BW - 1)) << 20);
        myB[i] = d >> BWL;
        atomicAdd(&hist[myB[i]], 1);
      } else {
        myB[i] = -1;
      }
    }
    __syncthreads();
    for (int b = tx; b < MAXBUK; b += 256) {
      int c = hist[b];
      hist[b] = c ? (b * BCAP + atomicAdd(&bukcur[b], c)) : 0;
    }
    __syncthreads();
#pragma unroll
    for (int i = 0; i < 8; ++i) {
      if (myB[i] >= 0) {
        int pos = atomicAdd(&hist[myB[i]], 1);
        pairs[pos] = myP[i];
      }
    }
    return;
  }

  // ---------------- gemm1 ----------------
  ushort* xl = (ushort*)smem;          // [64*136]
  ushort* wl = xl + 64 * 136;          // [128*136]
  int r0 = ((int)blockIdx.x - NCH_) * 64;

  {
    int c = tx >> 1, k0 = (tx & 1) * 64;
    const uint4* g = reinterpret_cast<const uint4*>(W1t + c * F1 + k0);
#pragma unroll
    for (int j = 0; j < 8; ++j)
      *reinterpret_cast<uint4*>(&wl[c * 136 + k0 + j * 8]) = g[j];
  }
  {
    int row = tx & 63, kq = tx >> 6;
    bool act = (r0 + row) < N;
    const float4* xg = reinterpret_cast<const float4*>(x + (size_t)(r0 + row) * F1 + kq * 32);
#pragma unroll
    for (int j = 0; j < 4; ++j) {
      float4 va = act ? xg[2 * j]     : make_float4(0.f, 0.f, 0.f, 0.f);
      float4 vb = act ? xg[2 * j + 1] : make_float4(0.f, 0.f, 0.f, 0.f);
      uint4 pk;
      pk.x = (uint)f2bf(va.x) | ((uint)f2bf(va.y) << 16);
      pk.y = (uint)f2bf(va.z) | ((uint)f2bf(va.w) << 16);
      pk.z = (uint)f2bf(vb.x) | ((uint)f2bf(vb.y) << 16);
      pk.w = (uint)f2bf(vb.z) | ((uint)f2bf(vb.w) << 16);
      *reinterpret_cast<uint4*>(&xl[row * 136 + kq * 32 + j * 8]) = pk;
    }
  }
  __syncthreads();

  int w = tx >> 6, l = tx & 63;
  int lr = l & 15, lo = l >> 4;

  bfrag af[4];
#pragma unroll
  for (int ks = 0; ks < 4; ++ks)
    af[ks] = *reinterpret_cast<const bfrag*>(&xl[(w * 16 + lr) * 136 + ks * 32 + lo * 8]);

  f32x4 acc[8];
#pragma unroll
  for (int n0 = 0; n0 < 8; ++n0) {
    acc[n0] = (f32x4){0.f, 0.f, 0.f, 0.f};
#pragma unroll
    for (int ks = 0; ks < 4; ++ks) {
      bfrag bf = *reinterpret_cast<const bfrag*>(&wl[(n0 * 16 + lr) * 136 + ks * 32 + lo * 8]);
      acc[n0] = __builtin_amdgcn_mfma_f32_16x16x32_bf16(af[ks], bf, acc[n0], 0, 0, 0);
    }
  }
  // attention dots via folded-weight MFMA tile (B from global Wdt, L2-hot)
  f32x4 dacc = (f32x4){0.f, 0.f, 0.f, 0.f};
#pragma unroll
  for (int ks = 0; ks < 4; ++ks) {
    bfrag bd = *reinterpret_cast<const bfrag*>(Wdt + lr * F1 + ks * 32 + lo * 8);
    dacc = __builtin_amdgcn_mfma_f32_16x16x32_bf16(af[ks], bd, dacc, 0, 0, 0);
  }

  ushort* tp = reinterpret_cast<ushort*>(h1b);
#pragma unroll
  for (int n0 = 0; n0 < 8; ++n0) {
    int cbase = n0 * 16 + lr;
#pragma unroll
    for (int r = 0; r < 4; ++r) {
      int row = r0 + w * 16 + lo * 4 + r;
      if (row < N) tp[(size_t)row * 128 + cbase] = f2bf(acc[n0][r]);
    }
  }
#pragma unroll
  for (int r = 0; r < 4; ++r) {
    int row = r0 + w * 16 + lo * 4 + r;
    if (row < N) {
      if (lr < 8) a_src[row * HEADS + lr] = dacc[r];
      else        a_dst[row * HEADS + (lr - 8)] = dacc[r];
    }
  }
}

// ---------------- D3: per-bucket fine CSR (512 threads) ----------------
__global__ __launch_bounds__(512) void k_csr(const int* __restrict__ pairs,
                                             const int* __restrict__ bukcur,
                                             int* __restrict__ off, int* __restrict__ offe,
                                             int* __restrict__ csr, int N) {
  __shared__ int cnt[BW];
  __shared__ int cur[BW];
  int b = blockIdx.x, t = threadIdx.x;
  int beg = b * BCAP, end = beg + bukcur[b];
  if (t < BW) cnt[t] = 0;
  __syncthreads();
  for (int j = beg + t; j < end; j += 512)
    atomicAdd(&cnt[(pairs[j] >> 20) & (BW - 1)], 1);
  __syncthreads();
  int my = t < BW ? cnt[t] : 0;
  for (int o = 1; o < BW; o <<= 1) {
    int v = (t < BW && t >= o) ? cnt[t - o] : 0;
    __syncthreads();
    if (t < BW) cnt[t] += v;
    __syncthreads();
  }
  if (t < BW) {
    int start = beg + cnt[t] - my;   // exclusive within bucket
    cur[t] = start;
    int d0 = b * BW + t;
    if (d0 < N) { off[d0] = start; offe[d0] = start + my; }
  }
  __syncthreads();
  for (int j = beg + t; j < end; j += 512) {
    int pr = pairs[j];
    int pos = atomicAdd(&cur[(pr >> 20) & (BW - 1)], 1);
    csr[pos] = pr & 0xFFFFF;
  }
}

// ---------------- D4: layer-1 aggregate (single full-row pass) ----------------
// 8 dsts/block (512 thr); 1 wave/dst; four 16-lane groups on alternating
// edges (4 rows in flight); lane owns 8 channels via uint4 (16x16B = 256B
// row); head = c4>>1; one exp per edge per group; combine shfl_xor(16/32).
__global__ __launch_bounds__(512) void k_agg1(
    const int* __restrict__ off, const int* __restrict__ offe,
    const int* __restrict__ csr, const uint4* __restrict__ h1b4,
    const float* __restrict__ a_src, const float* __restrict__ a_dst,
    const float* __restrict__ b1, uint* __restrict__ out1b, int N) {
  int w = threadIdx.x >> 6, lane = threadIdx.x & 63;
  int g = lane >> 4, c4 = lane & 15;   // channels 8*c4..8*c4+7
  int h = c4 >> 1;
  int d = blockIdx.x * 8 + w;
  if (d >= N) return;
  int beg = off[d], end = offe[d];
  float adl = a_dst[d * HEADS + h];
  float a[8] = {0.f, 0.f, 0.f, 0.f, 0.f, 0.f, 0.f, 0.f};
  float den = 0.f;
  for (int j = beg + g; j < end; j += 4) {
    int s = csr[j];
    float v = a_src[s * HEADS + h] + adl;
    v = v >= 0.f ? v : 0.2f * v;
    float p = __expf(v);
    uint4 wd = h1b4[(size_t)s * 16 + c4];
    a[0] = fmaf(p, bf2f_lo(wd.x), a[0]);
    a[1] = fmaf(p, bf2f_hi(wd.x), a[1]);
    a[2] = fmaf(p, bf2f_lo(wd.y), a[2]);
    a[3] = fmaf(p, bf2f_hi(wd.y), a[3]);
    a[4] = fmaf(p, bf2f_lo(wd.z), a[4]);
    a[5] = fmaf(p, bf2f_hi(wd.z), a[5]);
    a[6] = fmaf(p, bf2f_lo(wd.w), a[6]);
    a[7] = fmaf(p, bf2f_hi(wd.w), a[7]);
    den += p;
  }
#pragma unroll
  for (int i = 0; i < 8; ++i) {
    a[i] += __shfl_xor(a[i], 16);
    a[i] += __shfl_xor(a[i], 32);
  }
  den += __shfl_xor(den, 16); den += __shfl_xor(den, 32);
  if (g == 0) {
    float inv = 1.f / den;   // self-loop guarantees den > 0
    float4 b0 = *reinterpret_cast<const float4*>(&b1[8 * c4]);
    float4 b1v = *reinterpret_cast<const float4*>(&b1[8 * c4 + 4]);
    uint4 o;
    o.x = (uint)f2bf(a[0] * inv + b0.x)  | ((uint)f2bf(a[1] * inv + b0.y) << 16);
    o.y = (uint)f2bf(a[2] * inv + b0.z)  | ((uint)f2bf(a[3] * inv + b0.w) << 16);
    o.z = (uint)f2bf(a[4] * inv + b1v.x) | ((uint)f2bf(a[5] * inv + b1v.y) << 16);
    o.w = (uint)f2bf(a[6] * inv + b1v.z) | ((uint)f2bf(a[7] * inv + b1v.w) << 16);
    *reinterpret_cast<uint4*>(&out1b[(size_t)d * 64 + 4 * c4]) = o;
  }
}

// ---------------- D5: layer 2 GEMM (MFMA bf16, ELU fused into staging) ----------------
__global__ __launch_bounds__(256) void k_gemm2(
    const uint* __restrict__ out1b, const ushort* __restrict__ W2t,
    const ushort* __restrict__ Wd2t,
    uint* __restrict__ h2b, float* __restrict__ a_src2,
    float* __restrict__ a_dst2, int N) {
  __shared__ __align__(16) ushort xl[64 * 136];   // 17.0 KB
  __shared__ __align__(16) ushort wl[64 * 136];   // 17.0 KB
  int tx = threadIdx.x;
  int r0 = blockIdx.x * 64;

  {
    int c = tx & 63, k0 = (tx >> 6) * 32;
    const uint4* g = reinterpret_cast<const uint4*>(W2t + c * F1 + k0);
#pragma unroll
    for (int j = 0; j < 4; ++j)
      *reinterpret_cast<uint4*>(&wl[c * 136 + k0 + j * 8]) = g[j];
  }
  {
    int row = tx & 63, kq = tx >> 6;
    bool act = (r0 + row) < N;
    const uint4* xg = reinterpret_cast<const uint4*>(out1b + (size_t)(r0 + row) * 64 + kq * 16);
#pragma unroll
    for (int j = 0; j < 4; ++j) {
      uint4 v = act ? xg[j] : make_uint4(0, 0, 0, 0);
      uint4 pk;
      pk.x = elu2(v.x);
      pk.y = elu2(v.y);
      pk.z = elu2(v.z);
      pk.w = elu2(v.w);
      *reinterpret_cast<uint4*>(&xl[row * 136 + kq * 32 + j * 8]) = pk;
    }
  }
  __syncthreads();

  int w = tx >> 6, l = tx & 63;
  int lr = l & 15, lo = l >> 4;

  bfrag af[4];
#pragma unroll
  for (int ks = 0; ks < 4; ++ks)
    af[ks] = *reinterpret_cast<const bfrag*>(&xl[(w * 16 + lr) * 136 + ks * 32 + lo * 8]);

  f32x4 acc[4];
#pragma unroll
  for (int n0 = 0; n0 < 4; ++n0) {
    acc[n0] = (f32x4){0.f, 0.f, 0.f, 0.f};
#pragma unroll
    for (int ks = 0; ks < 4; ++ks) {
      bfrag bf = *reinterpret_cast<const bfrag*>(&wl[(n0 * 16 + lr) * 136 + ks * 32 + lo * 8]);
      acc[n0] = __builtin_amdgcn_mfma_f32_16x16x32_bf16(af[ks], bf, acc[n0], 0, 0, 0);
    }
  }
  f32x4 dacc = (f32x4){0.f, 0.f, 0.f, 0.f};
#pragma unroll
  for (int ks = 0; ks < 4; ++ks) {
    bfrag bd = *reinterpret_cast<const bfrag*>(Wd2t + lr * F1 + ks * 32 + lo * 8);
    dacc = __builtin_amdgcn_mfma_f32_16x16x32_bf16(af[ks], bd, dacc, 0, 0, 0);
  }

  ushort* tp = reinterpret_cast<ushort*>(h2b);
#pragma unroll
  for (int r = 0; r < 4; ++r) {
    int row = r0 + w * 16 + lo * 4 + r;
    if (row < N) {
#pragma unroll
      for (int n0 = 0; n0 < 4; ++n0)
        tp[(size_t)row * 64 + n0 * 16 + lr] = f2bf(acc[n0][r]);
      if (lr == 0) a_src2[row] = dacc[r];
      if (lr == 1) a_dst2[row] = dacc[r];
    }
  }
}

// ---------------- D6: layer 2 aggregate ----------------
__global__ void k_agg2(const int* __restrict__ off, const int* __restrict__ offe,
                       const int* __restrict__ csr,
                       const uint4* __restrict__ h2b4, const float* __restrict__ a_src2,
                       const float* __restrict__ a_dst2, const float* __restrict__ b2,
                       float* __restrict__ out, int N) {
  int w = threadIdx.x >> 6, lane = threadIdx.x & 63;
  int g = lane >> 3, c4 = lane & 7;   // channels 8*c4..8*c4+7
  int d = blockIdx.x * 4 + w;
  if (d >= N) return;
  int beg = off[d], end = offe[d];
  float adl = a_dst2[d];
  float a[8] = {0.f, 0.f, 0.f, 0.f, 0.f, 0.f, 0.f, 0.f};
  float den = 0.f;
  for (int j = beg + g; j < end; j += 8) {
    int s = csr[j];
    float v = a_src2[s] + adl;
    v = v >= 0.f ? v : 0.2f * v;
    float p = __expf(v);
    uint4 wd = h2b4[(size_t)s * 8 + c4];
    a[0] = fmaf(p, bf2f_lo(wd.x), a[0]);
    a[1] = fmaf(p, bf2f_hi(wd.x), a[1]);
    a[2] = fmaf(p, bf2f_lo(wd.y), a[2]);
    a[3] = fmaf(p, bf2f_hi(wd.y), a[3]);
    a[4] = fmaf(p, bf2f_lo(wd.z), a[4]);
    a[5] = fmaf(p, bf2f_hi(wd.z), a[5]);
    a[6] = fmaf(p, bf2f_lo(wd.w), a[6]);
    a[7] = fmaf(p, bf2f_hi(wd.w), a[7]);
    den += p;
  }
#pragma unroll
  for (int i = 0; i < 8; ++i) {
    a[i] += __shfl_xor(a[i], 8);
    a[i] += __shfl_xor(a[i], 16);
    a[i] += __shfl_xor(a[i], 32);
  }
  den += __shfl_xor(den, 8); den += __shfl_xor(den, 16); den += __shfl_xor(den, 32);
  if (g == 0) {
    float inv = 1.f / den;
    float4 b0 = *reinterpret_cast<const float4*>(&b2[8 * c4]);
    float4 b1v = *reinterpret_cast<const float4*>(&b2[8 * c4 + 4]);
    float4 o0, o1;
    o0.x = a[0] * inv + b0.x;  o0.y = a[1] * inv + b0.y;
    o0.z = a[2] * inv + b0.z;  o0.w = a[3] * inv + b0.w;
    o1.x = a[4] * inv + b1v.x; o1.y = a[5] * inv + b1v.y;
    o1.z = a[6] * inv + b1v.z; o1.w = a[7] * inv + b1v.w;
    *reinterpret_cast<float4*>(&out[(size_t)d * OUTD + 8 * c4]) = o0;
    *reinterpret_cast<float4*>(&out[(size_t)d * OUTD + 8 * c4 + 4]) = o1;
  }
}

extern "C" void kernel_launch(void* const* d_in, const int* in_sizes, int n_in,
                              void* d_out, int out_size, void* d_ws, size_t ws_size,
                              hipStream_t stream) {
  const float* x   = (const float*)d_in[0];
  const int*   ei  = (const int*)d_in[1];
  const float* W1  = (const float*)d_in[2];
  const float* as1 = (const float*)d_in[3];
  const float* ad1 = (const float*)d_in[4];
  const float* b1  = (const float*)d_in[5];
  const float* W2  = (const float*)d_in[6];
  const float* as2 = (const float*)d_in[7];
  const float* ad2 = (const float*)d_in[8];
  const float* b2  = (const float*)d_in[9];
  float* out = (float*)d_out;

  int N = in_sizes[0] / F1;
  int E = in_sizes[1] / 2;
  int ET = E + N;
  int NBUK = (N + BW - 1) / BW;       // 391 for N=50000 (<= MAXBUK)
  int NCH = (ET + CHUNK - 1) / CHUNK; // scatter blocks
  int NT = (N + 63) / 64;             // GEMM tiles (64 rows)
  int NB8 = (N + 7) / 8;              // agg1 blocks
  int NWC = (F1 * F1 + OUTD * F1 + 4096 + MAXBUK + 255) / 256;

  // workspace layout (16B-aligned chunks)
  char* p = (char*)d_ws;
  auto alloc = [&](size_t bytes) {
    char* q = p;
    p += (bytes + 15) & ~(size_t)15;
    return q;
  };
  int* bukcur  = (int*)alloc((size_t)NBUK * 4);
  int* off     = (int*)alloc((size_t)N * 4);
  int* offe    = (int*)alloc((size_t)N * 4);
  int* pairs   = (int*)alloc((size_t)NBUK * BCAP * 4);
  int* csr     = (int*)alloc((size_t)NBUK * BCAP * 4);
  ushort* W1t  = (ushort*)alloc((size_t)F1 * F1 * 2);
  ushort* W2t  = (ushort*)alloc((size_t)OUTD * F1 * 2);
  ushort* Wdt  = (ushort*)alloc((size_t)16 * F1 * 2);
  ushort* Wd2t = (ushort*)alloc((size_t)16 * F1 * 2);
  uint* h1b    = (uint*)alloc((size_t)N * 64 * 4);   // full 128-ch bf16 rows
  uint* h2b    = (uint*)alloc((size_t)N * 32 * 4);
  uint* out1b  = (uint*)alloc((size_t)N * 64 * 4);   // bf16-packed out1
  float* a_src1 = (float*)alloc((size_t)N * HEADS * 4);
  float* a_dst1 = (float*)alloc((size_t)N * HEADS * 4);
  float* a_src2 = (float*)alloc((size_t)N * 4);
  float* a_dst2 = (float*)alloc((size_t)N * 4);

  // D1: setup (W convert + folded dot-weights + bucket-cursor zero)
  hipLaunchKernelGGL(k_wcvt, dim3(NWC), dim3(256), 0, stream,
                     W1, W2, as1, ad1, as2, ad2, W1t, W2t, Wdt, Wd2t, bukcur, NBUK);
  // D2: scatter || gemm1 (block-range fused)
  hipLaunchKernelGGL(k_sg, dim3(NCH + NT), dim3(256), 0, stream,
                     ei, E, N, bukcur, pairs,
                     x, W1t, Wdt, h1b, a_src1, a_dst1, NCH);
  // D3: fine CSR
  hipLaunchKernelGGL(k_csr, dim3(NBUK), dim3(512), 0, stream,
                     pairs, bukcur, off, offe, csr, N);
  // D4: layer-1 aggregate (single full-row pass)
  hipLaunchKernelGGL(k_agg1, dim3(NB8), dim3(512), 0, stream,
                     off, offe, csr, (const uint4*)h1b,
                     a_src1, a_dst1, b1, out1b, N);
  // D5/D6: layer 2
  hipLaunchKernelGGL(k_gemm2, dim3(NT), dim3(256), 0, stream,
                     out1b, W2t, Wd2t, h2b, a_src2, a_dst2, N);
  hipLaunchKernelGGL(k_agg2, dim3((N + 3) / 4), dim3(256), 0, stream,
                     off, offe, csr, (const uint4*)h2b, a_src2, a_dst2, b2, out, N);
}